// Round 7
// baseline (969.792 us; speedup 1.0000x reference)
//
#include <hip/hip_runtime.h>
#include <math.h>

// ClassificationBackbone: conv/attn pipeline, fp32 throughout.
// R7: k_attn7 = R6's no-LDS split-m attention + explicit 1-deep software
// pipeline (prefetch next K/V rows into a second reg buffer, unroll-2 to
// ping-pong buffers), K/Q consumed as float4+float2 (D<=6), lb(128,3).

#define DEVINL __device__ __forceinline__

DEVINL float selu_f(float x) {
  const float scale = 1.0507009873554805f;
  const float alpha = 1.6732632423543772f;
  return scale * (x > 0.f ? x : alpha * (__expf(x) - 1.f));
}

// ---------------- prep: h = concat([x^0.25/255^0.25, x], batch) -------------
__global__ __launch_bounds__(256) void k_prep(const float* __restrict__ x,
                                              float* __restrict__ h, int n) {
  const float invScale = 0.250244727f;  // 255^-0.25
  for (int i = blockIdx.x * blockDim.x + threadIdx.x; i < n;
       i += gridDim.x * blockDim.x) {
    float v = x[i];
    h[i] = sqrtf(sqrtf(v)) * invScale;
    h[n + i] = v;
  }
}

// ---------------- LDS-tiled conv3x3 (+bias)(+selu)(+avgpool2) ---------------
template <bool POOL, bool DO_SELU, bool DO_BIAS>
__global__ __launch_bounds__(256) void k_conv3x3t(
    const float* __restrict__ in, const float* __restrict__ w,
    const float* __restrict__ bias, float* __restrict__ outA,
    float* __restrict__ outB, int splitB, int Bn, int Cin, int Cout, int IH,
    int IW, int tilesX, int tilesY) {
  constexpr int CI_CHUNK = 5;
  constexpr int ROWF = 36;  // padded LDS row (floats)
  __shared__ __align__(16) float lds[CI_CHUNK * 34 * ROWF];

  const int CH = IH - 2, CW = IW - 2;
  const int OH = POOL ? (CH >> 1) : CH;
  const int OW = POOL ? (CW >> 1) : CW;

  int bid = blockIdx.x;
  const int tX = bid % tilesX; bid /= tilesX;
  const int tY = bid % tilesY; bid /= tilesY;
  const int occ = bid % (Cout >> 1);
  const int b = bid / (Cout >> 1);
  const int oc0 = occ * 2;

  const int tid = threadIdx.x;
  const int ty = tid >> 4, tx = tid & 15;
  const int cy = 2 * ty, cx = 2 * tx;

  const int cy0 = tY * 32, cx0 = tX * 32;
  const long inb = (long)b * Cin * IH * IW;

  float a0[2][2] = {{0.f, 0.f}, {0.f, 0.f}};
  float a1[2][2] = {{0.f, 0.f}, {0.f, 0.f}};

  for (int ci0 = 0; ci0 < Cin; ci0 += CI_CHUNK) {
    const int nch = min(CI_CHUNK, Cin - ci0);
    const int nstage = nch * 34 * 34;
    __syncthreads();
    for (int i = tid; i < nstage; i += 256) {
      const int c = i % 34;
      const int t = i / 34;
      const int r = t % 34;
      const int cl = t / 34;
      const int gy = cy0 + r, gx = cx0 + c;
      float v = 0.f;
      if (gy < IH && gx < IW)
        v = in[inb + ((long)(ci0 + cl) * IH + gy) * IW + gx];
      lds[(cl * 34 + r) * ROWF + c] = v;
    }
    __syncthreads();

    for (int cl = 0; cl < CI_CHUNK; ++cl) {
      const int ci = ci0 + cl;
      if (ci >= Cin) break;
      float pr[4][4];
      const float* base = &lds[(cl * 34 + cy) * ROWF + cx];
#pragma unroll
      for (int r = 0; r < 4; ++r) {
        float2 u0 = *(const float2*)(base + r * ROWF);
        float2 u1 = *(const float2*)(base + r * ROWF + 2);
        pr[r][0] = u0.x; pr[r][1] = u0.y; pr[r][2] = u1.x; pr[r][3] = u1.y;
      }
      const float* wp0 = w + ((long)oc0 * Cin + ci) * 9;
      const float* wp1 = wp0 + (long)Cin * 9;
#pragma unroll
      for (int ky = 0; ky < 3; ++ky)
#pragma unroll
        for (int kx = 0; kx < 3; ++kx) {
          const float w0 = wp0[ky * 3 + kx];
          const float w1 = wp1[ky * 3 + kx];
#pragma unroll
          for (int r = 0; r < 2; ++r)
#pragma unroll
            for (int c = 0; c < 2; ++c) {
              const float v = pr[r + ky][c + kx];
              a0[r][c] = fmaf(w0, v, a0[r][c]);
              a1[r][c] = fmaf(w1, v, a1[r][c]);
            }
        }
    }
  }

  const float b0 = DO_BIAS ? bias[oc0] : 0.f;
  const float b1 = DO_BIAS ? bias[oc0 + 1] : 0.f;

  if (POOL) {
    const int py = tY * 16 + ty, px = tX * 16 + tx;
    if (py < OH && px < OW) {
#pragma unroll
      for (int o = 0; o < 2; ++o) {
        const float bb = o ? b1 : b0;
        float s = 0.f;
#pragma unroll
        for (int r = 0; r < 2; ++r)
#pragma unroll
          for (int c = 0; c < 2; ++c) {
            float v = (o ? a1[r][c] : a0[r][c]) + bb;
            if (DO_SELU) v = selu_f(v);
            s += v;
          }
        const float rv = 0.25f * s;
        const int oc = oc0 + o;
        if (outB != nullptr && b >= splitB)
          outB[(((long)(b - splitB) * Cout + oc) * OH + py) * OW + px] = rv;
        else
          outA[(((long)b * Cout + oc) * OH + py) * OW + px] = rv;
      }
    }
  } else {
#pragma unroll
    for (int o = 0; o < 2; ++o) {
      const float bb = o ? b1 : b0;
      const int oc = oc0 + o;
#pragma unroll
      for (int r = 0; r < 2; ++r)
#pragma unroll
        for (int c = 0; c < 2; ++c) {
          const int oy = cy0 + cy + r, ox = cx0 + cx + c;
          if (oy < OH && ox < OW) {
            float v = (o ? a1[r][c] : a0[r][c]) + bb;
            if (DO_SELU) v = selu_f(v);
            float* dst = (outB != nullptr && b >= splitB)
                             ? &outB[(((long)(b - splitB) * Cout + oc) * OH + oy) * OW + ox]
                             : &outA[(((long)b * Cout + oc) * OH + oy) * OW + ox];
            *dst = v;
          }
        }
    }
  }
}

// ---------------- q/k/v projections -> padded transposed layouts ------------
// qt,kt: [Np][8] (cols d>=D zero; rows n>=N zero); vt: [Np][Cp].
template <int Cp>
__global__ __launch_bounds__(256) void k_qkv3(
    const float* __restrict__ x, const float* __restrict__ wq,
    const float* __restrict__ bq, const float* __restrict__ wk,
    const float* __restrict__ bk, const float* __restrict__ wv,
    const float* __restrict__ bv, float* __restrict__ qt,
    float* __restrict__ kt, float* __restrict__ vt, int Bn, int C, int D,
    int N, int Np) {
  constexpr int KP = 8;
  const int S = Np * (2 * KP + Cp);
  const int total = Bn * S;
  for (int idx = blockIdx.x * blockDim.x + threadIdx.x; idx < total;
       idx += gridDim.x * blockDim.x) {
    const int b = idx / S;
    const int rr = idx % S;
    const float* xb = x + (long)b * C * N;
    const float* w = nullptr;
    const float* bp = nullptr;
    float* dst;
    int n, co, lim;
    if (rr < Np * KP) {
      n = rr / KP; co = rr % KP; lim = D;
      w = wq + co * C; bp = bq;
      dst = qt + ((long)b * Np + n) * KP + co;
    } else if (rr < 2 * Np * KP) {
      const int t = rr - Np * KP;
      n = t / KP; co = t % KP; lim = D;
      w = wk + co * C; bp = bk;
      dst = kt + ((long)b * Np + n) * KP + co;
    } else {
      const int t = rr - 2 * Np * KP;
      n = t / Cp; co = t % Cp; lim = C;
      w = wv + co * C; bp = bv;
      dst = vt + ((long)b * Np + n) * Cp + co;
    }
    if (co < lim && n < N) {
      float a = bp[co];
      for (int ci = 0; ci < C; ++ci) a = fmaf(w[ci], xb[(long)ci * N + n], a);
      *dst = a;
    } else {
      *dst = 0.f;
    }
  }
}

// ---------------- flash attention partials (no LDS, split-m, pipelined) -----
// 128 thr = 2 waves (cg = channel half). lane: g=lane>>4 m-subgroup (0..3),
// r=lane&15; rows n = brow + r + 16k, k=0..1 (32 rows/block). Block handles
// m-slice [s*msz, min(+msz,N)). K/V read from global (L2-resident, 16-lane
// broadcast) with explicit 1-deep prefetch double-buffer (unroll-2 renames).
// K/Q consumed as float4+float2 (D<=6). No __syncthreads. Softmax without
// max-subtraction is exact here (tiny energies). N multiple of 4.
template <int C, int Chp>
__global__ __launch_bounds__(128, 3) void k_attn7(
    const float* __restrict__ qt, const float* __restrict__ kt,
    const float* __restrict__ vt, float* __restrict__ num,
    float* __restrict__ den, int N, int nbr, int S, int msz, int Np, int Nr) {
  constexpr int KP = 8;
  constexpr int Cp = 2 * Chp;
  constexpr int NV = Chp / 4;
  int bid = blockIdx.x;
  const int s = bid % S; bid /= S;
  const int rb = bid % nbr;
  const int b = bid / nbr;
  const int brow = rb * 32;
  const int tid = threadIdx.x;
  const int lane = tid & 63;
  const int cg = tid >> 6;  // channel half 0/1
  const int g = lane >> 4;  // m subgroup 0..3
  const int r = lane & 15;  // row base

  const float* qb = qt + (long)b * Np * KP;
  const float* kb = kt + (long)b * Np * KP;
  const float* vb = vt + (long)b * Np * Cp;

  float4 q0[2];
  float2 q1[2];
#pragma unroll
  for (int k = 0; k < 2; ++k) {
    const int n = brow + r + 16 * k;  // n < Nr <= Np always
    q0[k] = *(const float4*)(qb + (long)n * KP);
    q1[k] = *(const float2*)(qb + (long)n * KP + 4);
  }

  float acc[2][Chp];
#pragma unroll
  for (int k = 0; k < 2; ++k)
#pragma unroll
    for (int c = 0; c < Chp; ++c) acc[k][c] = 0.f;
  float sm[2] = {0.f, 0.f};

  const int mstart = s * msz;
  const int mlimit = min(mstart + msz, N);

  // prime the pipeline
  float4 ka = *(const float4*)(kb + (long)(mstart + g) * KP);
  float2 k2 = *(const float2*)(kb + (long)(mstart + g) * KP + 4);
  float4 vv[NV];
  {
    const float4* vp = (const float4*)(vb + (long)(mstart + g) * Cp + cg * Chp);
#pragma unroll
    for (int j = 0; j < NV; ++j) vv[j] = vp[j];
  }

#pragma unroll 2
  for (int m0 = mstart; m0 < mlimit; m0 += 4) {
    // issue next iteration's loads (wrap to mstart on last; always valid)
    const int mn = (m0 + 4 < mlimit) ? (m0 + 4) : mstart;
    const float4 nka = *(const float4*)(kb + (long)(mn + g) * KP);
    const float2 nk2 = *(const float2*)(kb + (long)(mn + g) * KP + 4);
    float4 nvv[NV];
    {
      const float4* vp = (const float4*)(vb + (long)(mn + g) * Cp + cg * Chp);
#pragma unroll
      for (int j = 0; j < NV; ++j) nvv[j] = vp[j];
    }
    // compute with current buffers
#pragma unroll
    for (int k = 0; k < 2; ++k) {
      float e = q0[k].x * ka.x;
      e = fmaf(q0[k].y, ka.y, e);
      e = fmaf(q0[k].z, ka.z, e);
      e = fmaf(q0[k].w, ka.w, e);
      e = fmaf(q1[k].x, k2.x, e);
      e = fmaf(q1[k].y, k2.y, e);
      const float p = __expf(e);
      sm[k] += p;
#pragma unroll
      for (int j = 0; j < NV; ++j) {
        acc[k][4 * j + 0] = fmaf(p, vv[j].x, acc[k][4 * j + 0]);
        acc[k][4 * j + 1] = fmaf(p, vv[j].y, acc[k][4 * j + 1]);
        acc[k][4 * j + 2] = fmaf(p, vv[j].z, acc[k][4 * j + 2]);
        acc[k][4 * j + 3] = fmaf(p, vv[j].w, acc[k][4 * j + 3]);
      }
    }
    // rotate buffers (unroll-2 lets the allocator rename instead of move)
    ka = nka;
    k2 = nk2;
#pragma unroll
    for (int j = 0; j < NV; ++j) vv[j] = nvv[j];
  }

  // reduce the 4 m-subgroups (lane bits 4,5)
#pragma unroll
  for (int k = 0; k < 2; ++k) {
    sm[k] += __shfl_xor(sm[k], 16, 64);
    sm[k] += __shfl_xor(sm[k], 32, 64);
#pragma unroll
    for (int c = 0; c < Chp; ++c) {
      acc[k][c] += __shfl_xor(acc[k][c], 16, 64);
      acc[k][c] += __shfl_xor(acc[k][c], 32, 64);
    }
  }

  if (g == 0) {
    float* np_ = num + ((long)(s * 8 + b) * Cp + cg * Chp) * Nr;
    float* dp_ = den + (long)(s * 8 + b) * Nr;
#pragma unroll
    for (int k = 0; k < 2; ++k) {
      const int n = brow + r + 16 * k;
      if (n < N) {
#pragma unroll
        for (int c = 0; c < Chp; ++c) np_[(long)c * Nr + n] = acc[k][c];
        if (cg == 0) dp_[n] = sm[k];
      }
    }
  }
}

// ---------------- attention merge: out = x + g * (sum num)/(sum den) --------
__global__ __launch_bounds__(256) void k_attnmerge(
    const float* __restrict__ x, const float* __restrict__ num,
    const float* __restrict__ den, const float* __restrict__ gamma_p,
    float* __restrict__ out, int C, int Cp, int N, int Nr, int S) {
  const float g = gamma_p[0];
  const int total = 8 * C * N;
  for (int idx = blockIdx.x * blockDim.x + threadIdx.x; idx < total;
       idx += gridDim.x * blockDim.x) {
    const int n = idx % N;
    const int t = idx / N;
    const int c = t % C;
    const int b = t / C;
    float a = 0.f, d = 0.f;
    for (int s = 0; s < S; ++s) {
      a += num[((long)(s * 8 + b) * Cp + c) * Nr + n];
      d += den[(long)(s * 8 + b) * Nr + n];
    }
    out[((long)b * C + c) * N + n] =
        fmaf(g, a / d, x[((long)b * C + c) * N + n]);
  }
}

// ---------------- batchnorm stats: mean + rsqrt(var+eps) per channel --------
__global__ __launch_bounds__(256) void k_bnstats(const float* __restrict__ x,
                                                 float* __restrict__ stats,
                                                 int Bn, int C, int HW,
                                                 float eps) {
  int c = blockIdx.x;
  int tid = threadIdx.x;
  int cnt = Bn * HW;
  float s = 0.f, s2 = 0.f;
  for (int i = tid; i < cnt; i += blockDim.x) {
    int b = i / HW, r = i % HW;
    float v = x[((long)b * C + c) * HW + r];
    s += v;
    s2 += v * v;
  }
#pragma unroll
  for (int off = 32; off > 0; off >>= 1) {
    s += __shfl_down(s, off);
    s2 += __shfl_down(s2, off);
  }
  __shared__ float as_[4], as2_[4];
  int wid = tid >> 6;
  if ((tid & 63) == 0) { as_[wid] = s; as2_[wid] = s2; }
  __syncthreads();
  if (tid == 0) {
    float S = 0.f, S2 = 0.f;
#pragma unroll
    for (int ww = 0; ww < 4; ++ww) { S += as_[ww]; S2 += as2_[ww]; }
    float mean = S / (float)cnt;
    float var = S2 / (float)cnt - mean * mean;
    stats[c] = mean;
    stats[C + c] = rsqrtf(var + eps);
  }
}

// ---------------- BN apply + selu (+pool) ----------------
template <bool POOL>
__global__ __launch_bounds__(256) void k_bn_selu(
    const float* __restrict__ x, const float* __restrict__ stats,
    const float* __restrict__ g, const float* __restrict__ beta,
    float* __restrict__ out, int Bn, int C, int IH, int IW) {
  int OH = POOL ? (IH >> 1) : IH;
  int OW = POOL ? (IW >> 1) : IW;
  int total = Bn * C * OH * OW;
  for (int idx = blockIdx.x * blockDim.x + threadIdx.x; idx < total;
       idx += gridDim.x * blockDim.x) {
    int px = idx % OW;
    int t = idx / OW;
    int py = t % OH;
    t /= OH;
    int c = t % C;
    int b = t / C;
    float mean = stats[c], istd = stats[C + c];
    float gg = g[c], bb = beta[c];
    const float* ip = x + ((long)b * C + c) * IH * IW;
    float r;
    if (POOL) {
      int iy = py * 2, ix = px * 2;
      float v00 = selu_f((ip[iy * IW + ix] - mean) * istd * gg + bb);
      float v01 = selu_f((ip[iy * IW + ix + 1] - mean) * istd * gg + bb);
      float v10 = selu_f((ip[(iy + 1) * IW + ix] - mean) * istd * gg + bb);
      float v11 = selu_f((ip[(iy + 1) * IW + ix + 1] - mean) * istd * gg + bb);
      r = 0.25f * (v00 + v01 + v10 + v11);
    } else {
      r = selu_f((ip[py * IW + px] - mean) * istd * gg + bb);
    }
    out[((b * C + c) * OH + py) * OW + px] = r;
  }
}

static inline int gs(int total) { return (total + 255) / 256; }
static inline int cdiv(int a, int b) { return (a + b - 1) / b; }

extern "C" void kernel_launch(void* const* d_in, const int* in_sizes, int n_in,
                              void* d_out, int out_size, void* d_ws,
                              size_t ws_size, hipStream_t stream) {
  const float* x      = (const float*)d_in[0];
  const float* enc_w1 = (const float*)d_in[1];
  const float* enc_b1 = (const float*)d_in[2];
  const float* enc_w2 = (const float*)d_in[3];
  const float* enc_b2 = (const float*)d_in[4];
  const float* a1_wq  = (const float*)d_in[5];
  const float* a1_bq  = (const float*)d_in[6];
  const float* a1_wk  = (const float*)d_in[7];
  const float* a1_bk  = (const float*)d_in[8];
  const float* a1_wv  = (const float*)d_in[9];
  const float* a1_bv  = (const float*)d_in[10];
  const float* a1_g   = (const float*)d_in[11];
  const float* c1_w   = (const float*)d_in[12];
  const float* c1_b   = (const float*)d_in[13];
  const float* a2_wq  = (const float*)d_in[14];
  const float* a2_bq  = (const float*)d_in[15];
  const float* a2_wk  = (const float*)d_in[16];
  const float* a2_bk  = (const float*)d_in[17];
  const float* a2_wv  = (const float*)d_in[18];
  const float* a2_bv  = (const float*)d_in[19];
  const float* a2_g   = (const float*)d_in[20];
  const float* c2_w   = (const float*)d_in[21];
  const float* c2_b   = (const float*)d_in[22];
  const float* c3_w   = (const float*)d_in[23];
  const float* c3_g   = (const float*)d_in[24];
  const float* c3_be  = (const float*)d_in[25];
  const float* c4_w   = (const float*)d_in[26];
  const float* c4_g   = (const float*)d_in[27];
  const float* c4_be  = (const float*)d_in[28];
  const float* a3_wq  = (const float*)d_in[29];
  const float* a3_bq  = (const float*)d_in[30];
  const float* a3_wk  = (const float*)d_in[31];
  const float* a3_bk  = (const float*)d_in[32];
  const float* a3_wv  = (const float*)d_in[33];
  const float* a3_bv  = (const float*)d_in[34];
  const float* a3_g   = (const float*)d_in[35];

  float* out = (float*)d_out;
  float* W = (float*)d_ws;

  // ---- workspace plan (floats, liveness-checked; peak 5,056,320) ----
  float* h    = W;                 // [0, 1920000)
  float* h1   = W + 1920000;       // [1920000, 5056320)
  float* h2   = W;                 // [0, 737280)
  float* xenc = out + 5120;        // (8,40,48,48) direct

  // attn1: Np=Nr=2304, S=4
  float* q1   = W + 737280;        // [737280, 884736)
  float* k1   = W + 884736;        // [884736, 1032192)
  float* v1   = W + 1032192;       // [1032192, 1769472)
  float* num1 = W + 1920000;       // [1920000, 4869120)  4*8*40*2304
  float* den1 = W + 4869120;       // [4869120, 4942848)
  float* at1  = W + 737280;        // [737280, 1474560)   (q/k/v1 dead)
  float* c1o  = W + 4209920;       // [4209920, 5056320)  (num1/den1 dead)

  // attn2: Np=2176, Nr=2116, S=3
  float* q2   = W;                 // [0, 139264)
  float* k2   = W + 139264;        // [139264, 278528)
  float* v2   = W + 278528;        // [278528, 1253376)
  float* num2 = W + 1253376;       // [1253376, 4097280)  3*8*56*2116
  float* den2 = W + 4097280;       // [4097280, 4148064)
  float* at2  = W;                 // [0, 846400)         (q/k/v2 dead)

  float* c2o  = W + 846400;        // [846400, 1001280)
  float* c3o  = W + 1001280;       // [1001280, 1097280)
  float* st3  = W + 1097280;       // 60
  float* c3p  = W + 1098240;       // [1098240, 1122240)
  float* c4o  = W + 1122304;       // [1122304, 1127424)
  float* st4  = W + 1127488;       // 20
  float* c4b  = W + 1127552;       // [1127552, 1132672)
  // attn3: Np=128, Nr=64, S=1
  float* q3   = W + 1132672;       // 8192
  float* k3   = W + 1140864;       // 8192
  float* v3   = W + 1149056;       // 16384
  float* num3 = W + 1165440;       // 8192
  float* den3 = W + 1173632;       // 512

  const int NOSPLIT = 1 << 30;

  // 1. prep
  {
    int n = 8 * 3 * 200 * 200;
    k_prep<<<gs(n), 256, 0, stream>>>(x, h, n);
  }
  // 2. enc conv1 + selu + pool : (16,3,200,200)->(16,20,99,99)
  {
    int tXY = cdiv(99, 16);
    int blocks = 16 * (20 / 2) * tXY * tXY;
    k_conv3x3t<true, true, true><<<blocks, 256, 0, stream>>>(
        h, enc_w1, enc_b1, h1, nullptr, NOSPLIT, 16, 3, 20, 200, 200, tXY, tXY);
  }
  // 3. enc conv2 + selu + pool : (16,20,99,99)->(16,40,48,48); b>=8 -> x_enc
  {
    int tXY = cdiv(48, 16);
    int blocks = 16 * (40 / 2) * tXY * tXY;
    k_conv3x3t<true, true, true><<<blocks, 256, 0, stream>>>(
        h1, enc_w2, enc_b2, h2, xenc, 8, 16, 20, 40, 99, 99, tXY, tXY);
  }
  // 4. attn1 qkv : Cp=40, Np=2304
  {
    int total = 8 * 2304 * (16 + 40);
    k_qkv3<40><<<gs(total), 256, 0, stream>>>(h2, a1_wq, a1_bq, a1_wk, a1_bk,
                                              a1_wv, a1_bv, q1, k1, v1, 8, 40,
                                              5, 2304, 2304);
  }
  // 5. attn1 partials + merge : C=40, Chp=20, S=4
  {
    int nbr = 72, S = 4, msz = 576;
    k_attn7<40, 20><<<8 * nbr * S, 128, 0, stream>>>(q1, k1, v1, num1, den1,
                                                     2304, nbr, S, msz, 2304,
                                                     2304);
    k_attnmerge<<<gs(8 * 40 * 2304), 256, 0, stream>>>(h2, num1, den1, a1_g,
                                                       at1, 40, 40, 2304, 2304,
                                                       S);
  }
  // 6. c1 conv + selu : (8,40,48,48)->(8,50,46,46)
  {
    int tXY = cdiv(46, 32);
    int blocks = 8 * (50 / 2) * tXY * tXY;
    k_conv3x3t<false, true, true><<<blocks, 256, 0, stream>>>(
        at1, c1_w, c1_b, c1o, nullptr, NOSPLIT, 8, 40, 50, 48, 48, tXY, tXY);
  }
  // 7. attn2 qkv : Cp=56, Np=2176
  {
    int total = 8 * 2176 * (16 + 56);
    k_qkv3<56><<<gs(total), 256, 0, stream>>>(c1o, a2_wq, a2_bq, a2_wk, a2_bk,
                                              a2_wv, a2_bv, q2, k2, v2, 8, 50,
                                              6, 2116, 2176);
  }
  // 8. attn2 partials + merge : C=50, Chp=28, S=3
  {
    int nbr = 67, S = 3, msz = 708;
    k_attn7<50, 28><<<8 * nbr * S, 128, 0, stream>>>(q2, k2, v2, num2, den2,
                                                     2116, nbr, S, msz, 2176,
                                                     2116);
    k_attnmerge<<<gs(8 * 50 * 2116), 256, 0, stream>>>(c1o, num2, den2, a2_g,
                                                       at2, 50, 56, 2116, 2116,
                                                       S);
  }
  // 9. c2 conv + selu + pool : (8,50,46,46)->(8,40,22,22)
  {
    int tXY = cdiv(22, 16);
    int blocks = 8 * (40 / 2) * tXY * tXY;
    k_conv3x3t<true, true, true><<<blocks, 256, 0, stream>>>(
        at2, c2_w, c2_b, c2o, nullptr, NOSPLIT, 8, 50, 40, 46, 46, tXY, tXY);
  }
  // 10. c3 conv (no bias, no act) : (8,40,22,22)->(8,30,20,20)
  {
    int tXY = cdiv(20, 32);
    int blocks = 8 * (30 / 2) * tXY * tXY;
    k_conv3x3t<false, false, false><<<blocks, 256, 0, stream>>>(
        c2o, c3_w, nullptr, c3o, nullptr, NOSPLIT, 8, 40, 30, 22, 22, tXY,
        tXY);
  }
  // 11-12. BN(c3) + selu + pool -> (8,30,10,10)
  k_bnstats<<<30, 256, 0, stream>>>(c3o, st3, 8, 30, 400, 1e-5f);
  {
    int total = 8 * 30 * 10 * 10;
    k_bn_selu<true><<<gs(total), 256, 0, stream>>>(c3o, st3, c3_g, c3_be, c3p,
                                                   8, 30, 20, 20);
  }
  // 13. c4 conv : (8,30,10,10)->(8,10,8,8)
  {
    int tXY = cdiv(8, 32);
    int blocks = 8 * (10 / 2) * tXY * tXY;
    k_conv3x3t<false, false, false><<<blocks, 256, 0, stream>>>(
        c3p, c4_w, nullptr, c4o, nullptr, NOSPLIT, 8, 30, 10, 10, 10, tXY,
        tXY);
  }
  // 14-15. BN(c4) + selu
  k_bnstats<<<10, 256, 0, stream>>>(c4o, st4, 8, 10, 64, 1e-5f);
  {
    int total = 8 * 10 * 8 * 8;
    k_bn_selu<false><<<gs(total), 256, 0, stream>>>(c4o, st4, c4_g, c4_be, c4b,
                                                    8, 10, 8, 8);
  }
  // 16. attn3 qkv : Cp=16, Np=128
  {
    int total = 8 * 128 * (16 + 16);
    k_qkv3<16><<<gs(total), 256, 0, stream>>>(c4b, a3_wq, a3_bq, a3_wk, a3_bk,
                                              a3_wv, a3_bv, q3, k3, v3, 8, 10,
                                              1, 64, 128);
  }
  // 17. attn3 partials + merge -> out[0..5120) : C=10, Chp=8, S=1
  {
    int nbr = 2, S = 1, msz = 64;
    k_attn7<10, 8><<<8 * nbr * S, 128, 0, stream>>>(q3, k3, v3, num3, den3, 64,
                                                    nbr, S, msz, 128, 64);
    k_attnmerge<<<gs(8 * 10 * 64), 256, 0, stream>>>(c4b, num3, den3, a3_g,
                                                     out, 10, 16, 64, 64, S);
  }
}

// Round 8
// 697.502 us; speedup vs baseline: 1.3904x; 1.3904x over previous
//
#include <hip/hip_runtime.h>
#include <math.h>

// ClassificationBackbone: conv/attn pipeline.
// R8: MFMA attention. P (=exp(QK^T), fp32-exact, bf16-cast) built scalar
// per-lane directly in the B-fragment k-map (k = 8*(lane>>4)+i); V stored
// bf16 [Cpad][Np] so the A-fragment is one 16B load with the SAME k-map.
// Since A and B use one consistent k-map, mfma's k-contraction is correct
// for ANY true hardware k-layout (permutation invariance). C/D layout
// (col=lane&15, row=4*(lane>>4)+reg) is the HW-verified fact we rely on.

#define DEVINL __device__ __forceinline__

using bf16x8 = __attribute__((ext_vector_type(8))) short;  // 8 bf16 (4 VGPRs)
using f32x4 = __attribute__((ext_vector_type(4))) float;   // 4 fp32

DEVINL float selu_f(float x) {
  const float scale = 1.0507009873554805f;
  const float alpha = 1.6732632423543772f;
  return scale * (x > 0.f ? x : alpha * (__expf(x) - 1.f));
}

DEVINL short f2bf(float f) {  // RNE fp32 -> bf16
  unsigned int u = __float_as_uint(f);
  u = (u + 0x7FFFu + ((u >> 16) & 1u)) >> 16;
  return (short)u;
}

// ---------------- prep: h = concat([x^0.25/255^0.25, x], batch) -------------
__global__ __launch_bounds__(256) void k_prep(const float* __restrict__ x,
                                              float* __restrict__ h, int n) {
  const float invScale = 0.250244727f;  // 255^-0.25
  for (int i = blockIdx.x * blockDim.x + threadIdx.x; i < n;
       i += gridDim.x * blockDim.x) {
    float v = x[i];
    h[i] = sqrtf(sqrtf(v)) * invScale;
    h[n + i] = v;
  }
}

// ---------------- LDS-tiled conv3x3 (+bias)(+selu)(+avgpool2) ---------------
template <bool POOL, bool DO_SELU, bool DO_BIAS>
__global__ __launch_bounds__(256) void k_conv3x3t(
    const float* __restrict__ in, const float* __restrict__ w,
    const float* __restrict__ bias, float* __restrict__ outA,
    float* __restrict__ outB, int splitB, int Bn, int Cin, int Cout, int IH,
    int IW, int tilesX, int tilesY) {
  constexpr int CI_CHUNK = 5;
  constexpr int ROWF = 36;  // padded LDS row (floats)
  __shared__ __align__(16) float lds[CI_CHUNK * 34 * ROWF];

  const int CH = IH - 2, CW = IW - 2;
  const int OH = POOL ? (CH >> 1) : CH;
  const int OW = POOL ? (CW >> 1) : CW;

  int bid = blockIdx.x;
  const int tX = bid % tilesX; bid /= tilesX;
  const int tY = bid % tilesY; bid /= tilesY;
  const int occ = bid % (Cout >> 1);
  const int b = bid / (Cout >> 1);
  const int oc0 = occ * 2;

  const int tid = threadIdx.x;
  const int ty = tid >> 4, tx = tid & 15;
  const int cy = 2 * ty, cx = 2 * tx;

  const int cy0 = tY * 32, cx0 = tX * 32;
  const long inb = (long)b * Cin * IH * IW;

  float a0[2][2] = {{0.f, 0.f}, {0.f, 0.f}};
  float a1[2][2] = {{0.f, 0.f}, {0.f, 0.f}};

  for (int ci0 = 0; ci0 < Cin; ci0 += CI_CHUNK) {
    const int nch = min(CI_CHUNK, Cin - ci0);
    const int nstage = nch * 34 * 34;
    __syncthreads();
    for (int i = tid; i < nstage; i += 256) {
      const int c = i % 34;
      const int t = i / 34;
      const int r = t % 34;
      const int cl = t / 34;
      const int gy = cy0 + r, gx = cx0 + c;
      float v = 0.f;
      if (gy < IH && gx < IW)
        v = in[inb + ((long)(ci0 + cl) * IH + gy) * IW + gx];
      lds[(cl * 34 + r) * ROWF + c] = v;
    }
    __syncthreads();

    for (int cl = 0; cl < CI_CHUNK; ++cl) {
      const int ci = ci0 + cl;
      if (ci >= Cin) break;
      float pr[4][4];
      const float* base = &lds[(cl * 34 + cy) * ROWF + cx];
#pragma unroll
      for (int r = 0; r < 4; ++r) {
        float2 u0 = *(const float2*)(base + r * ROWF);
        float2 u1 = *(const float2*)(base + r * ROWF + 2);
        pr[r][0] = u0.x; pr[r][1] = u0.y; pr[r][2] = u1.x; pr[r][3] = u1.y;
      }
      const float* wp0 = w + ((long)oc0 * Cin + ci) * 9;
      const float* wp1 = wp0 + (long)Cin * 9;
#pragma unroll
      for (int ky = 0; ky < 3; ++ky)
#pragma unroll
        for (int kx = 0; kx < 3; ++kx) {
          const float w0 = wp0[ky * 3 + kx];
          const float w1 = wp1[ky * 3 + kx];
#pragma unroll
          for (int r = 0; r < 2; ++r)
#pragma unroll
            for (int c = 0; c < 2; ++c) {
              const float v = pr[r + ky][c + kx];
              a0[r][c] = fmaf(w0, v, a0[r][c]);
              a1[r][c] = fmaf(w1, v, a1[r][c]);
            }
        }
    }
  }

  const float b0 = DO_BIAS ? bias[oc0] : 0.f;
  const float b1 = DO_BIAS ? bias[oc0 + 1] : 0.f;

  if (POOL) {
    const int py = tY * 16 + ty, px = tX * 16 + tx;
    if (py < OH && px < OW) {
#pragma unroll
      for (int o = 0; o < 2; ++o) {
        const float bb = o ? b1 : b0;
        float s = 0.f;
#pragma unroll
        for (int r = 0; r < 2; ++r)
#pragma unroll
          for (int c = 0; c < 2; ++c) {
            float v = (o ? a1[r][c] : a0[r][c]) + bb;
            if (DO_SELU) v = selu_f(v);
            s += v;
          }
        const float rv = 0.25f * s;
        const int oc = oc0 + o;
        if (outB != nullptr && b >= splitB)
          outB[(((long)(b - splitB) * Cout + oc) * OH + py) * OW + px] = rv;
        else
          outA[(((long)b * Cout + oc) * OH + py) * OW + px] = rv;
      }
    }
  } else {
#pragma unroll
    for (int o = 0; o < 2; ++o) {
      const float bb = o ? b1 : b0;
      const int oc = oc0 + o;
#pragma unroll
      for (int r = 0; r < 2; ++r)
#pragma unroll
        for (int c = 0; c < 2; ++c) {
          const int oy = cy0 + cy + r, ox = cx0 + cx + c;
          if (oy < OH && ox < OW) {
            float v = (o ? a1[r][c] : a0[r][c]) + bb;
            if (DO_SELU) v = selu_f(v);
            float* dst = (outB != nullptr && b >= splitB)
                             ? &outB[(((long)(b - splitB) * Cout + oc) * OH + oy) * OW + ox]
                             : &outA[(((long)b * Cout + oc) * OH + oy) * OW + ox];
            *dst = v;
          }
        }
    }
  }
}

// -------- qkv for MFMA attention: qt,kt fp32 [Np][8]; vtb bf16 [Cpad][Np] ---
template <int Cpad>
__global__ __launch_bounds__(256) void k_qkvA(
    const float* __restrict__ x, const float* __restrict__ wq,
    const float* __restrict__ bq, const float* __restrict__ wk,
    const float* __restrict__ bk, const float* __restrict__ wv,
    const float* __restrict__ bv, float* __restrict__ qt,
    float* __restrict__ kt, unsigned short* __restrict__ vtb, int Bn, int C,
    int D, int N, int Np) {
  const int seg1 = Np * 8;
  const int S = 2 * seg1 + Cpad * Np;
  const int total = Bn * S;
  for (int idx = blockIdx.x * blockDim.x + threadIdx.x; idx < total;
       idx += gridDim.x * blockDim.x) {
    const int b = idx / S;
    const int rr = idx % S;
    const float* xb = x + (long)b * C * N;
    if (rr < 2 * seg1) {
      const bool isq = rr < seg1;
      const int t = isq ? rr : rr - seg1;
      const int n = t >> 3, co = t & 7;
      float val = 0.f;
      if (co < D && n < N) {
        const float* w = (isq ? wq : wk) + co * C;
        float a = (isq ? bq : bk)[co];
        for (int ci = 0; ci < C; ++ci) a = fmaf(w[ci], xb[(long)ci * N + n], a);
        val = a;
      }
      (isq ? qt : kt)[((long)b * Np + n) * 8 + co] = val;
    } else {
      const int t = rr - 2 * seg1;
      const int c = t / Np, n = t % Np;
      unsigned short v = 0;
      if (c < C && n < N) {
        const float* w = wv + c * C;
        float a = bv[c];
        for (int ci = 0; ci < C; ++ci) a = fmaf(w[ci], xb[(long)ci * N + n], a);
        v = (unsigned short)f2bf(a);
      }
      vtb[((long)b * Cpad + c) * Np + n] = v;
    }
  }
}

// ---------------- MFMA flash attention + residual ----------------
// Block = (batch, 16-q tile). 256 thr = 4 waves; wave w handles m-tiles
// t = w, w+4, ... (32 m per tile). Lane: qi=lane&15 (its q column),
// g=lane>>4. P built scalar in B-frag positions (elem i -> m = mt+8g+i);
// V^T A-frag = one 16B bf16 load at the SAME positions. O^T accumulates
// in C-layout (col=q, row=4g+reg). LDS merge of 4 waves + residual.
// Softmax without max-subtraction is exact here (tiny energies).
template <int C, int CB>
__global__ __launch_bounds__(256) void k_attnM(
    const float* __restrict__ x, const float* __restrict__ qt,
    const float* __restrict__ kt, const unsigned short* __restrict__ vtb,
    const float* __restrict__ gamma_p, float* __restrict__ out, int N, int Np,
    int nqt) {
  constexpr int Cpad = CB * 16;
  __shared__ float pO[4][CB * 256];
  __shared__ float pD[4][16];

  const int bid = blockIdx.x;
  const int b = bid / nqt;
  const int n0 = (bid % nqt) * 16;
  const int tid = threadIdx.x;
  const int wv_ = tid >> 6;
  const int lane = tid & 63;
  const int g = lane >> 4;
  const int qi = lane & 15;
  const int nq = n0 + qi;  // < Np always

  const float* qrow = qt + ((long)b * Np + nq) * 8;
  const float4 q0 = *(const float4*)qrow;
  const float2 q1 = *(const float2*)(qrow + 4);
  const float* kb_ = kt + (long)b * Np * 8;
  const unsigned short* vb_ = vtb + (long)b * Cpad * Np;

  f32x4 acc[CB];
#pragma unroll
  for (int cb = 0; cb < CB; ++cb) {
    f32x4 z = {0.f, 0.f, 0.f, 0.f};
    acc[cb] = z;
  }
  float den = 0.f;

  const int ntile = Np >> 5;
  for (int t = wv_; t < ntile; t += 4) {
    const int mb = t * 32 + g * 8;
    float4 ka[8];
    float2 kc[8];
#pragma unroll
    for (int i = 0; i < 8; ++i) {
      const float* kr = kb_ + (long)(mb + i) * 8;
      ka[i] = *(const float4*)kr;
      kc[i] = *(const float2*)(kr + 4);
    }
    float p[8];
#pragma unroll
    for (int i = 0; i < 8; ++i) {
      float e = q0.x * ka[i].x;
      e = fmaf(q0.y, ka[i].y, e);
      e = fmaf(q0.z, ka[i].z, e);
      e = fmaf(q0.w, ka[i].w, e);
      e = fmaf(q1.x, kc[i].x, e);
      e = fmaf(q1.y, kc[i].y, e);
      const float pv = __expf(e);
      p[i] = (mb + i < N) ? pv : 0.f;
      den += p[i];
    }
    bf16x8 pb;
#pragma unroll
    for (int i = 0; i < 8; ++i) pb[i] = f2bf(p[i]);
#pragma unroll
    for (int cb = 0; cb < CB; ++cb) {
      const bf16x8 va =
          *(const bf16x8*)(vb_ + (long)(cb * 16 + qi) * Np + mb);
      acc[cb] = __builtin_amdgcn_mfma_f32_16x16x32_bf16(va, pb, acc[cb], 0, 0, 0);
    }
  }

  // den: sum the 4 lane-groups (each held different m's)
  den += __shfl_xor(den, 16, 64);
  den += __shfl_xor(den, 32, 64);

#pragma unroll
  for (int cb = 0; cb < CB; ++cb)
#pragma unroll
    for (int r = 0; r < 4; ++r)
      pO[wv_][cb * 256 + (4 * g + r) * 16 + qi] = acc[cb][r];
  if (g == 0) pD[wv_][qi] = den;
  __syncthreads();

  const float gma = gamma_p[0];
#pragma unroll
  for (int cb = 0; cb < CB; ++cb) {
    const int cell = cb * 256 + tid;
    const int c = cb * 16 + (tid >> 4);
    const int q = tid & 15;
    const int n = n0 + q;
    if (c < C && n < N) {
      const float s = pO[0][cell] + pO[1][cell] + pO[2][cell] + pO[3][cell];
      const float Dn = pD[0][q] + pD[1][q] + pD[2][q] + pD[3][q];
      const long o = ((long)b * C + c) * N + n;
      out[o] = fmaf(gma, s / Dn, x[o]);
    }
  }
}

// ---------------- q/k/v projections (attn3 small path) ----------------
template <int Cp>
__global__ __launch_bounds__(256) void k_qkv3(
    const float* __restrict__ x, const float* __restrict__ wq,
    const float* __restrict__ bq, const float* __restrict__ wk,
    const float* __restrict__ bk, const float* __restrict__ wv,
    const float* __restrict__ bv, float* __restrict__ qt,
    float* __restrict__ kt, float* __restrict__ vt, int Bn, int C, int D,
    int N, int Np) {
  constexpr int KP = 8;
  const int S = Np * (2 * KP + Cp);
  const int total = Bn * S;
  for (int idx = blockIdx.x * blockDim.x + threadIdx.x; idx < total;
       idx += gridDim.x * blockDim.x) {
    const int b = idx / S;
    const int rr = idx % S;
    const float* xb = x + (long)b * C * N;
    const float* w = nullptr;
    const float* bp = nullptr;
    float* dst;
    int n, co, lim;
    if (rr < Np * KP) {
      n = rr / KP; co = rr % KP; lim = D;
      w = wq + co * C; bp = bq;
      dst = qt + ((long)b * Np + n) * KP + co;
    } else if (rr < 2 * Np * KP) {
      const int t = rr - Np * KP;
      n = t / KP; co = t % KP; lim = D;
      w = wk + co * C; bp = bk;
      dst = kt + ((long)b * Np + n) * KP + co;
    } else {
      const int t = rr - 2 * Np * KP;
      n = t / Cp; co = t % Cp; lim = C;
      w = wv + co * C; bp = bv;
      dst = vt + ((long)b * Np + n) * Cp + co;
    }
    if (co < lim && n < N) {
      float a = bp[co];
      for (int ci = 0; ci < C; ++ci) a = fmaf(w[ci], xb[(long)ci * N + n], a);
      *dst = a;
    } else {
      *dst = 0.f;
    }
  }
}

// ---------------- flash attention partials (attn3 small path) ---------------
template <int C, int Chp>
__global__ __launch_bounds__(128) void k_attn7(
    const float* __restrict__ qt, const float* __restrict__ kt,
    const float* __restrict__ vt, float* __restrict__ num,
    float* __restrict__ den, int N, int nbr, int S, int msz, int Np, int Nr) {
  constexpr int KP = 8;
  constexpr int Cp = 2 * Chp;
  constexpr int NV = Chp / 4;
  int bid = blockIdx.x;
  const int s = bid % S; bid /= S;
  const int rb = bid % nbr;
  const int b = bid / nbr;
  const int brow = rb * 32;
  const int tid = threadIdx.x;
  const int lane = tid & 63;
  const int cg = tid >> 6;
  const int g = lane >> 4;
  const int r = lane & 15;

  const float* qb = qt + (long)b * Np * KP;
  const float* kb = kt + (long)b * Np * KP;
  const float* vb = vt + (long)b * Np * Cp;

  float4 q0[2];
  float2 q1[2];
#pragma unroll
  for (int k = 0; k < 2; ++k) {
    const int n = brow + r + 16 * k;
    q0[k] = *(const float4*)(qb + (long)n * KP);
    q1[k] = *(const float2*)(qb + (long)n * KP + 4);
  }

  float acc[2][Chp];
#pragma unroll
  for (int k = 0; k < 2; ++k)
#pragma unroll
    for (int c = 0; c < Chp; ++c) acc[k][c] = 0.f;
  float sm[2] = {0.f, 0.f};

  const int mstart = s * msz;
  const int mlimit = min(mstart + msz, N);
  for (int m0 = mstart; m0 < mlimit; m0 += 4) {
    const int m = m0 + g;
    const float4 ka = *(const float4*)(kb + (long)m * KP);
    const float2 kc = *(const float2*)(kb + (long)m * KP + 4);
    float4 vv[NV];
    const float4* vp = (const float4*)(vb + (long)m * Cp + cg * Chp);
#pragma unroll
    for (int j = 0; j < NV; ++j) vv[j] = vp[j];
#pragma unroll
    for (int k = 0; k < 2; ++k) {
      float e = q0[k].x * ka.x;
      e = fmaf(q0[k].y, ka.y, e);
      e = fmaf(q0[k].z, ka.z, e);
      e = fmaf(q0[k].w, ka.w, e);
      e = fmaf(q1[k].x, kc.x, e);
      e = fmaf(q1[k].y, kc.y, e);
      const float p = __expf(e);
      sm[k] += p;
#pragma unroll
      for (int j = 0; j < NV; ++j) {
        acc[k][4 * j + 0] = fmaf(p, vv[j].x, acc[k][4 * j + 0]);
        acc[k][4 * j + 1] = fmaf(p, vv[j].y, acc[k][4 * j + 1]);
        acc[k][4 * j + 2] = fmaf(p, vv[j].z, acc[k][4 * j + 2]);
        acc[k][4 * j + 3] = fmaf(p, vv[j].w, acc[k][4 * j + 3]);
      }
    }
  }

#pragma unroll
  for (int k = 0; k < 2; ++k) {
    sm[k] += __shfl_xor(sm[k], 16, 64);
    sm[k] += __shfl_xor(sm[k], 32, 64);
#pragma unroll
    for (int c = 0; c < Chp; ++c) {
      acc[k][c] += __shfl_xor(acc[k][c], 16, 64);
      acc[k][c] += __shfl_xor(acc[k][c], 32, 64);
    }
  }

  if (g == 0) {
    float* np_ = num + ((long)(s * 8 + b) * Cp + cg * Chp) * Nr;
    float* dp_ = den + (long)(s * 8 + b) * Nr;
#pragma unroll
    for (int k = 0; k < 2; ++k) {
      const int n = brow + r + 16 * k;
      if (n < N) {
#pragma unroll
        for (int c = 0; c < Chp; ++c) np_[(long)c * Nr + n] = acc[k][c];
        if (cg == 0) dp_[n] = sm[k];
      }
    }
  }
}

// ---------------- attention merge (attn3 small path) ----------------
__global__ __launch_bounds__(256) void k_attnmerge(
    const float* __restrict__ x, const float* __restrict__ num,
    const float* __restrict__ den, const float* __restrict__ gamma_p,
    float* __restrict__ out, int C, int Cp, int N, int Nr, int S) {
  const float g = gamma_p[0];
  const int total = 8 * C * N;
  for (int idx = blockIdx.x * blockDim.x + threadIdx.x; idx < total;
       idx += gridDim.x * blockDim.x) {
    const int n = idx % N;
    const int t = idx / N;
    const int c = t % C;
    const int b = t / C;
    float a = 0.f, d = 0.f;
    for (int s = 0; s < S; ++s) {
      a += num[((long)(s * 8 + b) * Cp + c) * Nr + n];
      d += den[(long)(s * 8 + b) * Nr + n];
    }
    out[((long)b * C + c) * N + n] =
        fmaf(g, a / d, x[((long)b * C + c) * N + n]);
  }
}

// ---------------- batchnorm stats: mean + rsqrt(var+eps) per channel --------
__global__ __launch_bounds__(256) void k_bnstats(const float* __restrict__ x,
                                                 float* __restrict__ stats,
                                                 int Bn, int C, int HW,
                                                 float eps) {
  int c = blockIdx.x;
  int tid = threadIdx.x;
  int cnt = Bn * HW;
  float s = 0.f, s2 = 0.f;
  for (int i = tid; i < cnt; i += blockDim.x) {
    int b = i / HW, r = i % HW;
    float v = x[((long)b * C + c) * HW + r];
    s += v;
    s2 += v * v;
  }
#pragma unroll
  for (int off = 32; off > 0; off >>= 1) {
    s += __shfl_down(s, off);
    s2 += __shfl_down(s2, off);
  }
  __shared__ float as_[4], as2_[4];
  int wid = tid >> 6;
  if ((tid & 63) == 0) { as_[wid] = s; as2_[wid] = s2; }
  __syncthreads();
  if (tid == 0) {
    float S = 0.f, S2 = 0.f;
#pragma unroll
    for (int ww = 0; ww < 4; ++ww) { S += as_[ww]; S2 += as2_[ww]; }
    float mean = S / (float)cnt;
    float var = S2 / (float)cnt - mean * mean;
    stats[c] = mean;
    stats[C + c] = rsqrtf(var + eps);
  }
}

// ---------------- BN apply + selu (+pool) ----------------
template <bool POOL>
__global__ __launch_bounds__(256) void k_bn_selu(
    const float* __restrict__ x, const float* __restrict__ stats,
    const float* __restrict__ g, const float* __restrict__ beta,
    float* __restrict__ out, int Bn, int C, int IH, int IW) {
  int OH = POOL ? (IH >> 1) : IH;
  int OW = POOL ? (IW >> 1) : IW;
  int total = Bn * C * OH * OW;
  for (int idx = blockIdx.x * blockDim.x + threadIdx.x; idx < total;
       idx += gridDim.x * blockDim.x) {
    int px = idx % OW;
    int t = idx / OW;
    int py = t % OH;
    t /= OH;
    int c = t % C;
    int b = t / C;
    float mean = stats[c], istd = stats[C + c];
    float gg = g[c], bb = beta[c];
    const float* ip = x + ((long)b * C + c) * IH * IW;
    float r;
    if (POOL) {
      int iy = py * 2, ix = px * 2;
      float v00 = selu_f((ip[iy * IW + ix] - mean) * istd * gg + bb);
      float v01 = selu_f((ip[iy * IW + ix + 1] - mean) * istd * gg + bb);
      float v10 = selu_f((ip[(iy + 1) * IW + ix] - mean) * istd * gg + bb);
      float v11 = selu_f((ip[(iy + 1) * IW + ix + 1] - mean) * istd * gg + bb);
      r = 0.25f * (v00 + v01 + v10 + v11);
    } else {
      r = selu_f((ip[py * IW + px] - mean) * istd * gg + bb);
    }
    out[((b * C + c) * OH + py) * OW + px] = r;
  }
}

static inline int gs(int total) { return (total + 255) / 256; }
static inline int cdiv(int a, int b) { return (a + b - 1) / b; }

extern "C" void kernel_launch(void* const* d_in, const int* in_sizes, int n_in,
                              void* d_out, int out_size, void* d_ws,
                              size_t ws_size, hipStream_t stream) {
  const float* x      = (const float*)d_in[0];
  const float* enc_w1 = (const float*)d_in[1];
  const float* enc_b1 = (const float*)d_in[2];
  const float* enc_w2 = (const float*)d_in[3];
  const float* enc_b2 = (const float*)d_in[4];
  const float* a1_wq  = (const float*)d_in[5];
  const float* a1_bq  = (const float*)d_in[6];
  const float* a1_wk  = (const float*)d_in[7];
  const float* a1_bk  = (const float*)d_in[8];
  const float* a1_wv  = (const float*)d_in[9];
  const float* a1_bv  = (const float*)d_in[10];
  const float* a1_g   = (const float*)d_in[11];
  const float* c1_w   = (const float*)d_in[12];
  const float* c1_b   = (const float*)d_in[13];
  const float* a2_wq  = (const float*)d_in[14];
  const float* a2_bq  = (const float*)d_in[15];
  const float* a2_wk  = (const float*)d_in[16];
  const float* a2_bk  = (const float*)d_in[17];
  const float* a2_wv  = (const float*)d_in[18];
  const float* a2_bv  = (const float*)d_in[19];
  const float* a2_g   = (const float*)d_in[20];
  const float* c2_w   = (const float*)d_in[21];
  const float* c2_b   = (const float*)d_in[22];
  const float* c3_w   = (const float*)d_in[23];
  const float* c3_g   = (const float*)d_in[24];
  const float* c3_be  = (const float*)d_in[25];
  const float* c4_w   = (const float*)d_in[26];
  const float* c4_g   = (const float*)d_in[27];
  const float* c4_be  = (const float*)d_in[28];
  const float* a3_wq  = (const float*)d_in[29];
  const float* a3_bq  = (const float*)d_in[30];
  const float* a3_wk  = (const float*)d_in[31];
  const float* a3_bk  = (const float*)d_in[32];
  const float* a3_wv  = (const float*)d_in[33];
  const float* a3_bv  = (const float*)d_in[34];
  const float* a3_g   = (const float*)d_in[35];

  float* out = (float*)d_out;
  float* W = (float*)d_ws;

  // ---- workspace plan (float slots; peak 5,056,320 = 20.2 MB, proven) ----
  float* h    = W;                         // [0, 1,920,000)
  float* h1   = W + 1920000;               // [1,920,000, 5,056,320)
  float* h2   = W;                         // [0, 737,280)
  float* xenc = out + 5120;                // (8,40,48,48) direct

  // attn1: Np1=2304, Cpad=48
  float* qt1 = W + 737280;                 // 147,456
  float* kt1 = W + 884736;                 // 147,456
  unsigned short* vtb1 = (unsigned short*)(W + 1032192);  // 884,736 bf16
  float* at1 = W + 1474560;                // 737,280 -> ends 2,211,840
  float* c1o = W + 2211840;                // 846,400 -> ends 3,058,240

  // attn2: Np2=2144, Cpad=64
  float* qt2 = W + 3058240;                // 137,216
  float* kt2 = W + 3195456;                // 137,216
  unsigned short* vtb2 = (unsigned short*)(W + 3332672);  // 1,097,728 bf16
  float* at2 = W + 3881536;                // 846,400 -> ends 4,727,936

  float* c2o  = W;                         // 154,880
  float* c3o  = W + 200000;                // 96,000
  float* st3  = W + 300000;                // 60
  float* c3p  = W + 310000;                // 24,000
  float* c4o  = W + 340000;                // 5,120
  float* st4  = W + 350000;                // 20
  float* c4b  = W + 360000;                // 5,120
  float* q3   = W + 370000;                // 8,192
  float* k3   = W + 380000;                // 8,192
  float* v3   = W + 390000;                // 16,384
  float* num3 = W + 410000;                // 8,192
  float* den3 = W + 420000;                // 512

  const int NOSPLIT = 1 << 30;

  // 1. prep
  {
    int n = 8 * 3 * 200 * 200;
    k_prep<<<gs(n), 256, 0, stream>>>(x, h, n);
  }
  // 2. enc conv1 + selu + pool : (16,3,200,200)->(16,20,99,99)
  {
    int tXY = cdiv(99, 16);
    int blocks = 16 * (20 / 2) * tXY * tXY;
    k_conv3x3t<true, true, true><<<blocks, 256, 0, stream>>>(
        h, enc_w1, enc_b1, h1, nullptr, NOSPLIT, 16, 3, 20, 200, 200, tXY, tXY);
  }
  // 3. enc conv2 + selu + pool : (16,20,99,99)->(16,40,48,48); b>=8 -> x_enc
  {
    int tXY = cdiv(48, 16);
    int blocks = 16 * (40 / 2) * tXY * tXY;
    k_conv3x3t<true, true, true><<<blocks, 256, 0, stream>>>(
        h1, enc_w2, enc_b2, h2, xenc, 8, 16, 20, 40, 99, 99, tXY, tXY);
  }
  // 4. attn1 qkv : Cpad=48, Np=2304
  {
    int total = 8 * 2304 * (16 + 48);
    k_qkvA<48><<<gs(total), 256, 0, stream>>>(h2, a1_wq, a1_bq, a1_wk, a1_bk,
                                              a1_wv, a1_bv, qt1, kt1, vtb1, 8,
                                              40, 5, 2304, 2304);
  }
  // 5. attn1 (MFMA) : C=40, CB=3, nqt=144
  {
    k_attnM<40, 3><<<8 * 144, 256, 0, stream>>>(h2, qt1, kt1, vtb1, a1_g, at1,
                                                2304, 2304, 144);
  }
  // 6. c1 conv + selu : (8,40,48,48)->(8,50,46,46)
  {
    int tXY = cdiv(46, 32);
    int blocks = 8 * (50 / 2) * tXY * tXY;
    k_conv3x3t<false, true, true><<<blocks, 256, 0, stream>>>(
        at1, c1_w, c1_b, c1o, nullptr, NOSPLIT, 8, 40, 50, 48, 48, tXY, tXY);
  }
  // 7. attn2 qkv : Cpad=64, Np=2144
  {
    int total = 8 * 2144 * (16 + 64);
    k_qkvA<64><<<gs(total), 256, 0, stream>>>(c1o, a2_wq, a2_bq, a2_wk, a2_bk,
                                              a2_wv, a2_bv, qt2, kt2, vtb2, 8,
                                              50, 6, 2116, 2144);
  }
  // 8. attn2 (MFMA) : C=50, CB=4, nqt=133
  {
    k_attnM<50, 4><<<8 * 133, 256, 0, stream>>>(c1o, qt2, kt2, vtb2, a2_g, at2,
                                                2116, 2144, 133);
  }
  // 9. c2 conv + selu + pool : (8,50,46,46)->(8,40,22,22)
  {
    int tXY = cdiv(22, 16);
    int blocks = 8 * (40 / 2) * tXY * tXY;
    k_conv3x3t<true, true, true><<<blocks, 256, 0, stream>>>(
        at2, c2_w, c2_b, c2o, nullptr, NOSPLIT, 8, 50, 40, 46, 46, tXY, tXY);
  }
  // 10. c3 conv (no bias, no act) : (8,40,22,22)->(8,30,20,20)
  {
    int tXY = cdiv(20, 32);
    int blocks = 8 * (30 / 2) * tXY * tXY;
    k_conv3x3t<false, false, false><<<blocks, 256, 0, stream>>>(
        c2o, c3_w, nullptr, c3o, nullptr, NOSPLIT, 8, 40, 30, 22, 22, tXY,
        tXY);
  }
  // 11-12. BN(c3) + selu + pool -> (8,30,10,10)
  k_bnstats<<<30, 256, 0, stream>>>(c3o, st3, 8, 30, 400, 1e-5f);
  {
    int total = 8 * 30 * 10 * 10;
    k_bn_selu<true><<<gs(total), 256, 0, stream>>>(c3o, st3, c3_g, c3_be, c3p,
                                                   8, 30, 20, 20);
  }
  // 13. c4 conv : (8,30,10,10)->(8,10,8,8)
  {
    int tXY = cdiv(8, 32);
    int blocks = 8 * (10 / 2) * tXY * tXY;
    k_conv3x3t<false, false, false><<<blocks, 256, 0, stream>>>(
        c3p, c4_w, nullptr, c4o, nullptr, NOSPLIT, 8, 30, 10, 10, 10, tXY,
        tXY);
  }
  // 14-15. BN(c4) + selu
  k_bnstats<<<10, 256, 0, stream>>>(c4o, st4, 8, 10, 64, 1e-5f);
  {
    int total = 8 * 10 * 8 * 8;
    k_bn_selu<false><<<gs(total), 256, 0, stream>>>(c4o, st4, c4_g, c4_be, c4b,
                                                    8, 10, 8, 8);
  }
  // 16. attn3 qkv : Cp=16, Np=128
  {
    int total = 8 * 128 * (16 + 16);
    k_qkv3<16><<<gs(total), 256, 0, stream>>>(c4b, a3_wq, a3_bq, a3_wk, a3_bk,
                                              a3_wv, a3_bv, q3, k3, v3, 8, 10,
                                              1, 64, 128);
  }
  // 17. attn3 partials + merge -> out[0..5120)
  {
    int nbr = 2, S = 1, msz = 64;
    k_attn7<10, 8><<<8 * nbr * S, 128, 0, stream>>>(q3, k3, v3, num3, den3, 64,
                                                    nbr, S, msz, 128, 64);
    k_attnmerge<<<gs(8 * 10 * 64), 256, 0, stream>>>(c4b, num3, den3, a3_g,
                                                     out, 10, 16, 64, 64, S);
  }
}

// Round 9
// 550.168 us; speedup vs baseline: 1.7627x; 1.2678x over previous
//
#include <hip/hip_runtime.h>
#include <math.h>

// ClassificationBackbone: conv/attn pipeline.
// R9: conv rewrite k_conv3x3o — OCB output channels per block (patch reused
// OCB times), div/mod-free float4 staging (row-slot x f4-slot thread map),
// weights staged in LDS per ci-chunk (broadcast reads). MFMA attention (R8)
// unchanged.

#define DEVINL __device__ __forceinline__

using bf16x8 = __attribute__((ext_vector_type(8))) short;  // 8 bf16 (4 VGPRs)
using f32x4 = __attribute__((ext_vector_type(4))) float;   // 4 fp32

DEVINL float selu_f(float x) {
  const float scale = 1.0507009873554805f;
  const float alpha = 1.6732632423543772f;
  return scale * (x > 0.f ? x : alpha * (__expf(x) - 1.f));
}

DEVINL short f2bf(float f) {  // RNE fp32 -> bf16
  unsigned int u = __float_as_uint(f);
  u = (u + 0x7FFFu + ((u >> 16) & 1u)) >> 16;
  return (short)u;
}

// ---------------- prep: h = concat([x^0.25/255^0.25, x], batch) -------------
__global__ __launch_bounds__(256) void k_prep(const float* __restrict__ x,
                                              float* __restrict__ h, int n) {
  const float invScale = 0.250244727f;  // 255^-0.25
  for (int i = blockIdx.x * blockDim.x + threadIdx.x; i < n;
       i += gridDim.x * blockDim.x) {
    float v = x[i];
    h[i] = sqrtf(sqrtf(v)) * invScale;
    h[n + i] = v;
  }
}

// ------------- conv3x3, OCB ocs/block (+bias)(+selu)(+avgpool2) -------------
// 256 thr = 16x16; thread owns a 2x2 conv quad (1 pooled output when POOL)
// for OCB consecutive ocs. Input staged per 5-channel chunk as [cl][34][36]
// via float4 (cx0 % 32 == 0 -> 16B aligned); weights staged [o][cl][12].
// Rows/cols beyond the input feed only bounds-masked dead outputs.
template <bool POOL, bool DO_SELU, bool DO_BIAS, int OCB>
__global__ __launch_bounds__(256) void k_conv3x3o(
    const float* __restrict__ in, const float* __restrict__ w,
    const float* __restrict__ bias, float* __restrict__ outA,
    float* __restrict__ outB, int splitB, int Bn, int Cin, int Cout, int IH,
    int IW, int tilesX, int tilesY) {
  constexpr int CI_CHUNK = 5;
  constexpr int ROWF = 36;
  __shared__ __align__(16) float lds[CI_CHUNK * 34 * ROWF];
  __shared__ __align__(16) float wlds[OCB * CI_CHUNK * 12];

  const int CH = IH - 2, CW = IW - 2;
  const int OH = POOL ? (CH >> 1) : CH;
  const int OW = POOL ? (CW >> 1) : CW;

  int bid = blockIdx.x;
  const int tX = bid % tilesX; bid /= tilesX;
  const int tY = bid % tilesY; bid /= tilesY;
  const int nOcg = Cout / OCB;
  const int ocg = bid % nOcg;
  const int b = bid / nOcg;
  const int oc0 = ocg * OCB;

  const int tid = threadIdx.x;
  const int ty = tid >> 4, tx = tid & 15;
  const int cy = 2 * ty, cx = 2 * tx;
  const int cy0 = tY * 32, cx0 = tX * 32;
  const long inb = (long)b * Cin * IH * IW;

  const bool live = (cy0 + cy < CH) && (cx0 + cx < CW);

  float acc[OCB][2][2];
#pragma unroll
  for (int o = 0; o < OCB; ++o)
#pragma unroll
    for (int r = 0; r < 2; ++r)
#pragma unroll
      for (int c = 0; c < 2; ++c) acc[o][r][c] = 0.f;

  const int f4 = tid & 15;
  const int gx0 = cx0 + 4 * f4;

  for (int ci0 = 0; ci0 < Cin; ci0 += CI_CHUNK) {
    const int nch = min(CI_CHUNK, Cin - ci0);
    __syncthreads();
    // stage weights for this (oc-group, ci-chunk)
#pragma unroll
    for (int o = 0; o < OCB; ++o) {
      for (int j = tid; j < nch * 9; j += 256) {
        const int cl = j / 9;
        const int kk = j - 9 * cl;
        wlds[(o * CI_CHUNK + cl) * 12 + kk] =
            w[((long)(oc0 + o) * Cin + ci0 + cl) * 9 + kk];
      }
    }
    // stage input: nch*34 rows x 9 float4 slots (slots 9..15 idle)
    for (int ra = tid >> 4; ra < nch * 34; ra += 16) {
      const int cl = ra / 34;
      const int r = ra - 34 * cl;
      if (f4 < 9) {
        const int gy = cy0 + r;
        if (gy < IH) {
          const float* gp = in + inb + ((long)(ci0 + cl) * IH + gy) * IW + gx0;
          float4 v;
          if (gx0 + 3 < IW) {
            v = *(const float4*)gp;
          } else {
            v.x = (gx0 < IW) ? gp[0] : 0.f;
            v.y = (gx0 + 1 < IW) ? gp[1] : 0.f;
            v.z = (gx0 + 2 < IW) ? gp[2] : 0.f;
            v.w = 0.f;
          }
          *(float4*)&lds[(cl * 34 + r) * ROWF + 4 * f4] = v;
        }
      }
    }
    __syncthreads();

    if (live) {
      for (int cl = 0; cl < nch; ++cl) {
        float pr[4][4];
        const float* base = &lds[(cl * 34 + cy) * ROWF + cx];
#pragma unroll
        for (int r = 0; r < 4; ++r) {
          float2 u0 = *(const float2*)(base + r * ROWF);
          float2 u1 = *(const float2*)(base + r * ROWF + 2);
          pr[r][0] = u0.x; pr[r][1] = u0.y; pr[r][2] = u1.x; pr[r][3] = u1.y;
        }
#pragma unroll
        for (int o = 0; o < OCB; ++o) {
          const float* wp = &wlds[(o * CI_CHUNK + cl) * 12];
          const float4 wA = *(const float4*)wp;
          const float4 wB = *(const float4*)(wp + 4);
          const float w8 = wp[8];
          const float wv[9] = {wA.x, wA.y, wA.z, wA.w, wB.x, wB.y, wB.z, wB.w,
                               w8};
#pragma unroll
          for (int ky = 0; ky < 3; ++ky)
#pragma unroll
            for (int kx = 0; kx < 3; ++kx) {
              const float ww = wv[ky * 3 + kx];
#pragma unroll
              for (int r = 0; r < 2; ++r)
#pragma unroll
                for (int c = 0; c < 2; ++c)
                  acc[o][r][c] = fmaf(ww, pr[r + ky][c + kx], acc[o][r][c]);
            }
        }
      }
    }
  }

  if (POOL) {
    const int py = tY * 16 + ty, px = tX * 16 + tx;
    if (py < OH && px < OW) {
#pragma unroll
      for (int o = 0; o < OCB; ++o) {
        const float bb = DO_BIAS ? bias[oc0 + o] : 0.f;
        float s = 0.f;
#pragma unroll
        for (int r = 0; r < 2; ++r)
#pragma unroll
          for (int c = 0; c < 2; ++c) {
            float v = acc[o][r][c] + bb;
            if (DO_SELU) v = selu_f(v);
            s += v;
          }
        const float rv = 0.25f * s;
        const int oc = oc0 + o;
        if (outB != nullptr && b >= splitB)
          outB[(((long)(b - splitB) * Cout + oc) * OH + py) * OW + px] = rv;
        else
          outA[(((long)b * Cout + oc) * OH + py) * OW + px] = rv;
      }
    }
  } else {
#pragma unroll
    for (int o = 0; o < OCB; ++o) {
      const float bb = DO_BIAS ? bias[oc0 + o] : 0.f;
      const int oc = oc0 + o;
#pragma unroll
      for (int r = 0; r < 2; ++r)
#pragma unroll
        for (int c = 0; c < 2; ++c) {
          const int oy = cy0 + cy + r, ox = cx0 + cx + c;
          if (oy < OH && ox < OW) {
            float v = acc[o][r][c] + bb;
            if (DO_SELU) v = selu_f(v);
            float* dst =
                (outB != nullptr && b >= splitB)
                    ? &outB[(((long)(b - splitB) * Cout + oc) * OH + oy) * OW + ox]
                    : &outA[(((long)b * Cout + oc) * OH + oy) * OW + ox];
            *dst = v;
          }
        }
    }
  }
}

// -------- qkv for MFMA attention: qt,kt fp32 [Np][8]; vtb bf16 [Cpad][Np] ---
template <int Cpad>
__global__ __launch_bounds__(256) void k_qkvA(
    const float* __restrict__ x, const float* __restrict__ wq,
    const float* __restrict__ bq, const float* __restrict__ wk,
    const float* __restrict__ bk, const float* __restrict__ wv,
    const float* __restrict__ bv, float* __restrict__ qt,
    float* __restrict__ kt, unsigned short* __restrict__ vtb, int Bn, int C,
    int D, int N, int Np) {
  const int seg1 = Np * 8;
  const int S = 2 * seg1 + Cpad * Np;
  const int total = Bn * S;
  for (int idx = blockIdx.x * blockDim.x + threadIdx.x; idx < total;
       idx += gridDim.x * blockDim.x) {
    const int b = idx / S;
    const int rr = idx % S;
    const float* xb = x + (long)b * C * N;
    if (rr < 2 * seg1) {
      const bool isq = rr < seg1;
      const int t = isq ? rr : rr - seg1;
      const int n = t >> 3, co = t & 7;
      float val = 0.f;
      if (co < D && n < N) {
        const float* w = (isq ? wq : wk) + co * C;
        float a = (isq ? bq : bk)[co];
        for (int ci = 0; ci < C; ++ci) a = fmaf(w[ci], xb[(long)ci * N + n], a);
        val = a;
      }
      (isq ? qt : kt)[((long)b * Np + n) * 8 + co] = val;
    } else {
      const int t = rr - 2 * seg1;
      const int c = t / Np, n = t % Np;
      unsigned short v = 0;
      if (c < C && n < N) {
        const float* w = wv + c * C;
        float a = bv[c];
        for (int ci = 0; ci < C; ++ci) a = fmaf(w[ci], xb[(long)ci * N + n], a);
        v = (unsigned short)f2bf(a);
      }
      vtb[((long)b * Cpad + c) * Np + n] = v;
    }
  }
}

// ---------------- MFMA flash attention + residual ----------------
template <int C, int CB>
__global__ __launch_bounds__(256) void k_attnM(
    const float* __restrict__ x, const float* __restrict__ qt,
    const float* __restrict__ kt, const unsigned short* __restrict__ vtb,
    const float* __restrict__ gamma_p, float* __restrict__ out, int N, int Np,
    int nqt) {
  constexpr int Cpad = CB * 16;
  __shared__ float pO[4][CB * 256];
  __shared__ float pD[4][16];

  const int bid = blockIdx.x;
  const int b = bid / nqt;
  const int n0 = (bid % nqt) * 16;
  const int tid = threadIdx.x;
  const int wv_ = tid >> 6;
  const int lane = tid & 63;
  const int g = lane >> 4;
  const int qi = lane & 15;
  const int nq = n0 + qi;

  const float* qrow = qt + ((long)b * Np + nq) * 8;
  const float4 q0 = *(const float4*)qrow;
  const float2 q1 = *(const float2*)(qrow + 4);
  const float* kb_ = kt + (long)b * Np * 8;
  const unsigned short* vb_ = vtb + (long)b * Cpad * Np;

  f32x4 acc[CB];
#pragma unroll
  for (int cb = 0; cb < CB; ++cb) {
    f32x4 z = {0.f, 0.f, 0.f, 0.f};
    acc[cb] = z;
  }
  float den = 0.f;

  const int ntile = Np >> 5;
  for (int t = wv_; t < ntile; t += 4) {
    const int mb = t * 32 + g * 8;
    float4 ka[8];
    float2 kc[8];
#pragma unroll
    for (int i = 0; i < 8; ++i) {
      const float* kr = kb_ + (long)(mb + i) * 8;
      ka[i] = *(const float4*)kr;
      kc[i] = *(const float2*)(kr + 4);
    }
    float p[8];
#pragma unroll
    for (int i = 0; i < 8; ++i) {
      float e = q0.x * ka[i].x;
      e = fmaf(q0.y, ka[i].y, e);
      e = fmaf(q0.z, ka[i].z, e);
      e = fmaf(q0.w, ka[i].w, e);
      e = fmaf(q1.x, kc[i].x, e);
      e = fmaf(q1.y, kc[i].y, e);
      const float pv = __expf(e);
      p[i] = (mb + i < N) ? pv : 0.f;
      den += p[i];
    }
    bf16x8 pb;
#pragma unroll
    for (int i = 0; i < 8; ++i) pb[i] = f2bf(p[i]);
#pragma unroll
    for (int cb = 0; cb < CB; ++cb) {
      const bf16x8 va = *(const bf16x8*)(vb_ + (long)(cb * 16 + qi) * Np + mb);
      acc[cb] =
          __builtin_amdgcn_mfma_f32_16x16x32_bf16(va, pb, acc[cb], 0, 0, 0);
    }
  }

  den += __shfl_xor(den, 16, 64);
  den += __shfl_xor(den, 32, 64);

#pragma unroll
  for (int cb = 0; cb < CB; ++cb)
#pragma unroll
    for (int r = 0; r < 4; ++r)
      pO[wv_][cb * 256 + (4 * g + r) * 16 + qi] = acc[cb][r];
  if (g == 0) pD[wv_][qi] = den;
  __syncthreads();

  const float gma = gamma_p[0];
#pragma unroll
  for (int cb = 0; cb < CB; ++cb) {
    const int cell = cb * 256 + tid;
    const int c = cb * 16 + (tid >> 4);
    const int q = tid & 15;
    const int n = n0 + q;
    if (c < C && n < N) {
      const float s = pO[0][cell] + pO[1][cell] + pO[2][cell] + pO[3][cell];
      const float Dn = pD[0][q] + pD[1][q] + pD[2][q] + pD[3][q];
      const long o = ((long)b * C + c) * N + n;
      out[o] = fmaf(gma, s / Dn, x[o]);
    }
  }
}

// ---------------- q/k/v projections (attn3 small path) ----------------
template <int Cp>
__global__ __launch_bounds__(256) void k_qkv3(
    const float* __restrict__ x, const float* __restrict__ wq,
    const float* __restrict__ bq, const float* __restrict__ wk,
    const float* __restrict__ bk, const float* __restrict__ wv,
    const float* __restrict__ bv, float* __restrict__ qt,
    float* __restrict__ kt, float* __restrict__ vt, int Bn, int C, int D,
    int N, int Np) {
  constexpr int KP = 8;
  const int S = Np * (2 * KP + Cp);
  const int total = Bn * S;
  for (int idx = blockIdx.x * blockDim.x + threadIdx.x; idx < total;
       idx += gridDim.x * blockDim.x) {
    const int b = idx / S;
    const int rr = idx % S;
    const float* xb = x + (long)b * C * N;
    const float* w = nullptr;
    const float* bp = nullptr;
    float* dst;
    int n, co, lim;
    if (rr < Np * KP) {
      n = rr / KP; co = rr % KP; lim = D;
      w = wq + co * C; bp = bq;
      dst = qt + ((long)b * Np + n) * KP + co;
    } else if (rr < 2 * Np * KP) {
      const int t = rr - Np * KP;
      n = t / KP; co = t % KP; lim = D;
      w = wk + co * C; bp = bk;
      dst = kt + ((long)b * Np + n) * KP + co;
    } else {
      const int t = rr - 2 * Np * KP;
      n = t / Cp; co = t % Cp; lim = C;
      w = wv + co * C; bp = bv;
      dst = vt + ((long)b * Np + n) * Cp + co;
    }
    if (co < lim && n < N) {
      float a = bp[co];
      for (int ci = 0; ci < C; ++ci) a = fmaf(w[ci], xb[(long)ci * N + n], a);
      *dst = a;
    } else {
      *dst = 0.f;
    }
  }
}

// ---------------- flash attention partials (attn3 small path) ---------------
template <int C, int Chp>
__global__ __launch_bounds__(128) void k_attn7(
    const float* __restrict__ qt, const float* __restrict__ kt,
    const float* __restrict__ vt, float* __restrict__ num,
    float* __restrict__ den, int N, int nbr, int S, int msz, int Np, int Nr) {
  constexpr int KP = 8;
  constexpr int Cp = 2 * Chp;
  constexpr int NV = Chp / 4;
  int bid = blockIdx.x;
  const int s = bid % S; bid /= S;
  const int rb = bid % nbr;
  const int b = bid / nbr;
  const int brow = rb * 32;
  const int tid = threadIdx.x;
  const int lane = tid & 63;
  const int cg = tid >> 6;
  const int g = lane >> 4;
  const int r = lane & 15;

  const float* qb = qt + (long)b * Np * KP;
  const float* kb = kt + (long)b * Np * KP;
  const float* vb = vt + (long)b * Np * Cp;

  float4 q0[2];
  float2 q1[2];
#pragma unroll
  for (int k = 0; k < 2; ++k) {
    const int n = brow + r + 16 * k;
    q0[k] = *(const float4*)(qb + (long)n * KP);
    q1[k] = *(const float2*)(qb + (long)n * KP + 4);
  }

  float acc[2][Chp];
#pragma unroll
  for (int k = 0; k < 2; ++k)
#pragma unroll
    for (int c = 0; c < Chp; ++c) acc[k][c] = 0.f;
  float sm[2] = {0.f, 0.f};

  const int mstart = s * msz;
  const int mlimit = min(mstart + msz, N);
  for (int m0 = mstart; m0 < mlimit; m0 += 4) {
    const int m = m0 + g;
    const float4 ka = *(const float4*)(kb + (long)m * KP);
    const float2 kc = *(const float2*)(kb + (long)m * KP + 4);
    float4 vv[NV];
    const float4* vp = (const float4*)(vb + (long)m * Cp + cg * Chp);
#pragma unroll
    for (int j = 0; j < NV; ++j) vv[j] = vp[j];
#pragma unroll
    for (int k = 0; k < 2; ++k) {
      float e = q0[k].x * ka.x;
      e = fmaf(q0[k].y, ka.y, e);
      e = fmaf(q0[k].z, ka.z, e);
      e = fmaf(q0[k].w, ka.w, e);
      e = fmaf(q1[k].x, kc.x, e);
      e = fmaf(q1[k].y, kc.y, e);
      const float p = __expf(e);
      sm[k] += p;
#pragma unroll
      for (int j = 0; j < NV; ++j) {
        acc[k][4 * j + 0] = fmaf(p, vv[j].x, acc[k][4 * j + 0]);
        acc[k][4 * j + 1] = fmaf(p, vv[j].y, acc[k][4 * j + 1]);
        acc[k][4 * j + 2] = fmaf(p, vv[j].z, acc[k][4 * j + 2]);
        acc[k][4 * j + 3] = fmaf(p, vv[j].w, acc[k][4 * j + 3]);
      }
    }
  }

#pragma unroll
  for (int k = 0; k < 2; ++k) {
    sm[k] += __shfl_xor(sm[k], 16, 64);
    sm[k] += __shfl_xor(sm[k], 32, 64);
#pragma unroll
    for (int c = 0; c < Chp; ++c) {
      acc[k][c] += __shfl_xor(acc[k][c], 16, 64);
      acc[k][c] += __shfl_xor(acc[k][c], 32, 64);
    }
  }

  if (g == 0) {
    float* np_ = num + ((long)(s * 8 + b) * Cp + cg * Chp) * Nr;
    float* dp_ = den + (long)(s * 8 + b) * Nr;
#pragma unroll
    for (int k = 0; k < 2; ++k) {
      const int n = brow + r + 16 * k;
      if (n < N) {
#pragma unroll
        for (int c = 0; c < Chp; ++c) np_[(long)c * Nr + n] = acc[k][c];
        if (cg == 0) dp_[n] = sm[k];
      }
    }
  }
}

// ---------------- attention merge (attn3 small path) ----------------
__global__ __launch_bounds__(256) void k_attnmerge(
    const float* __restrict__ x, const float* __restrict__ num,
    const float* __restrict__ den, const float* __restrict__ gamma_p,
    float* __restrict__ out, int C, int Cp, int N, int Nr, int S) {
  const float g = gamma_p[0];
  const int total = 8 * C * N;
  for (int idx = blockIdx.x * blockDim.x + threadIdx.x; idx < total;
       idx += gridDim.x * blockDim.x) {
    const int n = idx % N;
    const int t = idx / N;
    const int c = t % C;
    const int b = t / C;
    float a = 0.f, d = 0.f;
    for (int s = 0; s < S; ++s) {
      a += num[((long)(s * 8 + b) * Cp + c) * Nr + n];
      d += den[(long)(s * 8 + b) * Nr + n];
    }
    out[((long)b * C + c) * N + n] =
        fmaf(g, a / d, x[((long)b * C + c) * N + n]);
  }
}

// ---------------- batchnorm stats: mean + rsqrt(var+eps) per channel --------
__global__ __launch_bounds__(256) void k_bnstats(const float* __restrict__ x,
                                                 float* __restrict__ stats,
                                                 int Bn, int C, int HW,
                                                 float eps) {
  int c = blockIdx.x;
  int tid = threadIdx.x;
  int cnt = Bn * HW;
  float s = 0.f, s2 = 0.f;
  for (int i = tid; i < cnt; i += blockDim.x) {
    int b = i / HW, r = i % HW;
    float v = x[((long)b * C + c) * HW + r];
    s += v;
    s2 += v * v;
  }
#pragma unroll
  for (int off = 32; off > 0; off >>= 1) {
    s += __shfl_down(s, off);
    s2 += __shfl_down(s2, off);
  }
  __shared__ float as_[4], as2_[4];
  int wid = tid >> 6;
  if ((tid & 63) == 0) { as_[wid] = s; as2_[wid] = s2; }
  __syncthreads();
  if (tid == 0) {
    float S = 0.f, S2 = 0.f;
#pragma unroll
    for (int ww = 0; ww < 4; ++ww) { S += as_[ww]; S2 += as2_[ww]; }
    float mean = S / (float)cnt;
    float var = S2 / (float)cnt - mean * mean;
    stats[c] = mean;
    stats[C + c] = rsqrtf(var + eps);
  }
}

// ---------------- BN apply + selu (+pool) ----------------
template <bool POOL>
__global__ __launch_bounds__(256) void k_bn_selu(
    const float* __restrict__ x, const float* __restrict__ stats,
    const float* __restrict__ g, const float* __restrict__ beta,
    float* __restrict__ out, int Bn, int C, int IH, int IW) {
  int OH = POOL ? (IH >> 1) : IH;
  int OW = POOL ? (IW >> 1) : IW;
  int total = Bn * C * OH * OW;
  for (int idx = blockIdx.x * blockDim.x + threadIdx.x; idx < total;
       idx += gridDim.x * blockDim.x) {
    int px = idx % OW;
    int t = idx / OW;
    int py = t % OH;
    t /= OH;
    int c = t % C;
    int b = t / C;
    float mean = stats[c], istd = stats[C + c];
    float gg = g[c], bb = beta[c];
    const float* ip = x + ((long)b * C + c) * IH * IW;
    float r;
    if (POOL) {
      int iy = py * 2, ix = px * 2;
      float v00 = selu_f((ip[iy * IW + ix] - mean) * istd * gg + bb);
      float v01 = selu_f((ip[iy * IW + ix + 1] - mean) * istd * gg + bb);
      float v10 = selu_f((ip[(iy + 1) * IW + ix] - mean) * istd * gg + bb);
      float v11 = selu_f((ip[(iy + 1) * IW + ix + 1] - mean) * istd * gg + bb);
      r = 0.25f * (v00 + v01 + v10 + v11);
    } else {
      r = selu_f((ip[py * IW + px] - mean) * istd * gg + bb);
    }
    out[((b * C + c) * OH + py) * OW + px] = r;
  }
}

static inline int gs(int total) { return (total + 255) / 256; }
static inline int cdiv(int a, int b) { return (a + b - 1) / b; }

extern "C" void kernel_launch(void* const* d_in, const int* in_sizes, int n_in,
                              void* d_out, int out_size, void* d_ws,
                              size_t ws_size, hipStream_t stream) {
  const float* x      = (const float*)d_in[0];
  const float* enc_w1 = (const float*)d_in[1];
  const float* enc_b1 = (const float*)d_in[2];
  const float* enc_w2 = (const float*)d_in[3];
  const float* enc_b2 = (const float*)d_in[4];
  const float* a1_wq  = (const float*)d_in[5];
  const float* a1_bq  = (const float*)d_in[6];
  const float* a1_wk  = (const float*)d_in[7];
  const float* a1_bk  = (const float*)d_in[8];
  const float* a1_wv  = (const float*)d_in[9];
  const float* a1_bv  = (const float*)d_in[10];
  const float* a1_g   = (const float*)d_in[11];
  const float* c1_w   = (const float*)d_in[12];
  const float* c1_b   = (const float*)d_in[13];
  const float* a2_wq  = (const float*)d_in[14];
  const float* a2_bq  = (const float*)d_in[15];
  const float* a2_wk  = (const float*)d_in[16];
  const float* a2_bk  = (const float*)d_in[17];
  const float* a2_wv  = (const float*)d_in[18];
  const float* a2_bv  = (const float*)d_in[19];
  const float* a2_g   = (const float*)d_in[20];
  const float* c2_w   = (const float*)d_in[21];
  const float* c2_b   = (const float*)d_in[22];
  const float* c3_w   = (const float*)d_in[23];
  const float* c3_g   = (const float*)d_in[24];
  const float* c3_be  = (const float*)d_in[25];
  const float* c4_w   = (const float*)d_in[26];
  const float* c4_g   = (const float*)d_in[27];
  const float* c4_be  = (const float*)d_in[28];
  const float* a3_wq  = (const float*)d_in[29];
  const float* a3_bq  = (const float*)d_in[30];
  const float* a3_wk  = (const float*)d_in[31];
  const float* a3_bk  = (const float*)d_in[32];
  const float* a3_wv  = (const float*)d_in[33];
  const float* a3_bv  = (const float*)d_in[34];
  const float* a3_g   = (const float*)d_in[35];

  float* out = (float*)d_out;
  float* W = (float*)d_ws;

  // ---- workspace plan (float slots; peak 5,056,320 = 20.2 MB, proven) ----
  float* h    = W;                         // [0, 1,920,000)
  float* h1   = W + 1920000;               // [1,920,000, 5,056,320)
  float* h2   = W;                         // [0, 737,280)
  float* xenc = out + 5120;                // (8,40,48,48) direct

  // attn1: Np1=2304, Cpad=48
  float* qt1 = W + 737280;                 // 147,456
  float* kt1 = W + 884736;                 // 147,456
  unsigned short* vtb1 = (unsigned short*)(W + 1032192);  // 884,736 bf16
  float* at1 = W + 1474560;                // 737,280 -> ends 2,211,840
  float* c1o = W + 2211840;                // 846,400 -> ends 3,058,240

  // attn2: Np2=2144, Cpad=64
  float* qt2 = W + 3058240;                // 137,216
  float* kt2 = W + 3195456;                // 137,216
  unsigned short* vtb2 = (unsigned short*)(W + 3332672);  // 1,097,728 bf16
  float* at2 = W + 3881536;                // 846,400 -> ends 4,727,936

  float* c2o  = W;                         // 154,880
  float* c3o  = W + 200000;                // 96,000
  float* st3  = W + 300000;                // 60
  float* c3p  = W + 310000;                // 24,000
  float* c4o  = W + 340000;                // 5,120
  float* st4  = W + 350000;                // 20
  float* c4b  = W + 360000;                // 5,120
  float* q3   = W + 370000;                // 8,192
  float* k3   = W + 380000;                // 8,192
  float* v3   = W + 390000;                // 16,384
  float* num3 = W + 410000;                // 8,192
  float* den3 = W + 420000;                // 512

  const int NOSPLIT = 1 << 30;

  // 1. prep
  {
    int n = 8 * 3 * 200 * 200;
    k_prep<<<gs(n), 256, 0, stream>>>(x, h, n);
  }
  // 2. enc conv1 + selu + pool : (16,3,200,200)->(16,20,99,99), OCB=10
  {
    int tXY = cdiv(99, 16);  // 7
    int blocks = 16 * (20 / 10) * tXY * tXY;  // 1568
    k_conv3x3o<true, true, true, 10><<<blocks, 256, 0, stream>>>(
        h, enc_w1, enc_b1, h1, nullptr, NOSPLIT, 16, 3, 20, 200, 200, tXY,
        tXY);
  }
  // 3. enc conv2 + selu + pool : (16,20,99,99)->(16,40,48,48), OCB=10
  {
    int tXY = cdiv(48, 16);  // 3
    int blocks = 16 * (40 / 10) * tXY * tXY;  // 576
    k_conv3x3o<true, true, true, 10><<<blocks, 256, 0, stream>>>(
        h1, enc_w2, enc_b2, h2, xenc, 8, 16, 20, 40, 99, 99, tXY, tXY);
  }
  // 4. attn1 qkv : Cpad=48, Np=2304
  {
    int total = 8 * 2304 * (16 + 48);
    k_qkvA<48><<<gs(total), 256, 0, stream>>>(h2, a1_wq, a1_bq, a1_wk, a1_bk,
                                              a1_wv, a1_bv, qt1, kt1, vtb1, 8,
                                              40, 5, 2304, 2304);
  }
  // 5. attn1 (MFMA) : C=40, CB=3, nqt=144
  {
    k_attnM<40, 3><<<8 * 144, 256, 0, stream>>>(h2, qt1, kt1, vtb1, a1_g, at1,
                                                2304, 2304, 144);
  }
  // 6. c1 conv + selu : (8,40,48,48)->(8,50,46,46), OCB=5
  {
    int tXY = cdiv(46, 32);  // 2
    int blocks = 8 * (50 / 5) * tXY * tXY;  // 320
    k_conv3x3o<false, true, true, 5><<<blocks, 256, 0, stream>>>(
        at1, c1_w, c1_b, c1o, nullptr, NOSPLIT, 8, 40, 50, 48, 48, tXY, tXY);
  }
  // 7. attn2 qkv : Cpad=64, Np=2144
  {
    int total = 8 * 2144 * (16 + 64);
    k_qkvA<64><<<gs(total), 256, 0, stream>>>(c1o, a2_wq, a2_bq, a2_wk, a2_bk,
                                              a2_wv, a2_bv, qt2, kt2, vtb2, 8,
                                              50, 6, 2116, 2144);
  }
  // 8. attn2 (MFMA) : C=50, CB=4, nqt=133
  {
    k_attnM<50, 4><<<8 * 133, 256, 0, stream>>>(c1o, qt2, kt2, vtb2, a2_g, at2,
                                                2116, 2144, 133);
  }
  // 9. c2 conv + selu + pool : (8,50,46,46)->(8,40,22,22), OCB=5
  {
    int tXY = cdiv(22, 16);  // 2
    int blocks = 8 * (40 / 5) * tXY * tXY;  // 256
    k_conv3x3o<true, true, true, 5><<<blocks, 256, 0, stream>>>(
        at2, c2_w, c2_b, c2o, nullptr, NOSPLIT, 8, 50, 40, 46, 46, tXY, tXY);
  }
  // 10. c3 conv : (8,40,22,22)->(8,30,20,20), OCB=2
  {
    int tXY = cdiv(20, 32);  // 1
    int blocks = 8 * (30 / 2) * tXY * tXY;  // 120
    k_conv3x3o<false, false, false, 2><<<blocks, 256, 0, stream>>>(
        c2o, c3_w, nullptr, c3o, nullptr, NOSPLIT, 8, 40, 30, 22, 22, tXY,
        tXY);
  }
  // 11-12. BN(c3) + selu + pool -> (8,30,10,10)
  k_bnstats<<<30, 256, 0, stream>>>(c3o, st3, 8, 30, 400, 1e-5f);
  {
    int total = 8 * 30 * 10 * 10;
    k_bn_selu<true><<<gs(total), 256, 0, stream>>>(c3o, st3, c3_g, c3_be, c3p,
                                                   8, 30, 20, 20);
  }
  // 13. c4 conv : (8,30,10,10)->(8,10,8,8), OCB=2
  {
    int tXY = cdiv(8, 32);  // 1
    int blocks = 8 * (10 / 2) * tXY * tXY;  // 40
    k_conv3x3o<false, false, false, 2><<<blocks, 256, 0, stream>>>(
        c3p, c4_w, nullptr, c4o, nullptr, NOSPLIT, 8, 30, 10, 10, 10, tXY,
        tXY);
  }
  // 14-15. BN(c4) + selu
  k_bnstats<<<10, 256, 0, stream>>>(c4o, st4, 8, 10, 64, 1e-5f);
  {
    int total = 8 * 10 * 8 * 8;
    k_bn_selu<false><<<gs(total), 256, 0, stream>>>(c4o, st4, c4_g, c4_be, c4b,
                                                    8, 10, 8, 8);
  }
  // 16. attn3 qkv : Cp=16, Np=128
  {
    int total = 8 * 128 * (16 + 16);
    k_qkv3<16><<<gs(total), 256, 0, stream>>>(c4b, a3_wq, a3_bq, a3_wk, a3_bk,
                                              a3_wv, a3_bv, q3, k3, v3, 8, 10,
                                              1, 64, 128);
  }
  // 17. attn3 partials + merge -> out[0..5120)
  {
    int nbr = 2, S = 1, msz = 64;
    k_attn7<10, 8><<<8 * nbr * S, 128, 0, stream>>>(q3, k3, v3, num3, den3, 64,
                                                    nbr, S, msz, 128, 64);
    k_attnmerge<<<gs(8 * 10 * 64), 256, 0, stream>>>(c4b, num3, den3, a3_g,
                                                     out, 10, 16, 64, 64, S);
  }
}

// Round 10
// 521.426 us; speedup vs baseline: 1.8599x; 1.0551x over previous
//
#include <hip/hip_runtime.h>
#include <math.h>

// ClassificationBackbone: conv/attn pipeline.
// R10: conv occupancy fix — OCB halved (conv1/2: 5, c1/c2: 2) so the grid
// provides 4.5-12 blocks/CU (was 1-2.25); __launch_bounds__(256,4) keeps
// VGPR <= 128 so 4 blocks/CU stay resident. Flat weight-staging loop.
// MFMA attention (R8) unchanged.

#define DEVINL __device__ __forceinline__

using bf16x8 = __attribute__((ext_vector_type(8))) short;  // 8 bf16 (4 VGPRs)
using f32x4 = __attribute__((ext_vector_type(4))) float;   // 4 fp32

DEVINL float selu_f(float x) {
  const float scale = 1.0507009873554805f;
  const float alpha = 1.6732632423543772f;
  return scale * (x > 0.f ? x : alpha * (__expf(x) - 1.f));
}

DEVINL short f2bf(float f) {  // RNE fp32 -> bf16
  unsigned int u = __float_as_uint(f);
  u = (u + 0x7FFFu + ((u >> 16) & 1u)) >> 16;
  return (short)u;
}

// ---------------- prep: h = concat([x^0.25/255^0.25, x], batch) -------------
__global__ __launch_bounds__(256) void k_prep(const float* __restrict__ x,
                                              float* __restrict__ h, int n) {
  const float invScale = 0.250244727f;  // 255^-0.25
  for (int i = blockIdx.x * blockDim.x + threadIdx.x; i < n;
       i += gridDim.x * blockDim.x) {
    float v = x[i];
    h[i] = sqrtf(sqrtf(v)) * invScale;
    h[n + i] = v;
  }
}

// ------------- conv3x3, OCB ocs/block (+bias)(+selu)(+avgpool2) -------------
// 256 thr = 16x16; thread owns a 2x2 conv quad (1 pooled output when POOL)
// for OCB consecutive ocs. Input staged per 5-channel chunk as [cl][34][36]
// via float4 (cx0 % 32 == 0 -> 16B aligned); weights staged [o][cl][12].
template <bool POOL, bool DO_SELU, bool DO_BIAS, int OCB>
__global__ __launch_bounds__(256, 4) void k_conv3x3o(
    const float* __restrict__ in, const float* __restrict__ w,
    const float* __restrict__ bias, float* __restrict__ outA,
    float* __restrict__ outB, int splitB, int Bn, int Cin, int Cout, int IH,
    int IW, int tilesX, int tilesY) {
  constexpr int CI_CHUNK = 5;
  constexpr int ROWF = 36;
  __shared__ __align__(16) float lds[CI_CHUNK * 34 * ROWF];
  __shared__ __align__(16) float wlds[OCB * CI_CHUNK * 12];

  const int CH = IH - 2, CW = IW - 2;
  const int OH = POOL ? (CH >> 1) : CH;
  const int OW = POOL ? (CW >> 1) : CW;

  int bid = blockIdx.x;
  const int tX = bid % tilesX; bid /= tilesX;
  const int tY = bid % tilesY; bid /= tilesY;
  const int nOcg = Cout / OCB;
  const int ocg = bid % nOcg;
  const int b = bid / nOcg;
  const int oc0 = ocg * OCB;

  const int tid = threadIdx.x;
  const int ty = tid >> 4, tx = tid & 15;
  const int cy = 2 * ty, cx = 2 * tx;
  const int cy0 = tY * 32, cx0 = tX * 32;
  const long inb = (long)b * Cin * IH * IW;

  const bool live = (cy0 + cy < CH) && (cx0 + cx < CW);

  float acc[OCB][2][2];
#pragma unroll
  for (int o = 0; o < OCB; ++o)
#pragma unroll
    for (int r = 0; r < 2; ++r)
#pragma unroll
      for (int c = 0; c < 2; ++c) acc[o][r][c] = 0.f;

  const int f4 = tid & 15;
  const int gx0 = cx0 + 4 * f4;

  for (int ci0 = 0; ci0 < Cin; ci0 += CI_CHUNK) {
    const int nch = min(CI_CHUNK, Cin - ci0);
    __syncthreads();
    // stage weights for this (oc-group, ci-chunk): flat loop, const divisors
    for (int j = tid; j < OCB * CI_CHUNK * 9; j += 256) {
      const int o = j / (CI_CHUNK * 9);
      const int rem = j - o * (CI_CHUNK * 9);
      const int cl = rem / 9;
      const int kk = rem - 9 * cl;
      if (cl < nch)
        wlds[(o * CI_CHUNK + cl) * 12 + kk] =
            w[((long)(oc0 + o) * Cin + ci0 + cl) * 9 + kk];
    }
    // stage input: nch*34 rows x 9 float4 slots (slots 9..15 idle)
    for (int ra = tid >> 4; ra < nch * 34; ra += 16) {
      const int cl = ra / 34;
      const int r = ra - 34 * cl;
      if (f4 < 9) {
        const int gy = cy0 + r;
        if (gy < IH) {
          const float* gp = in + inb + ((long)(ci0 + cl) * IH + gy) * IW + gx0;
          float4 v;
          if (gx0 + 3 < IW) {
            v = *(const float4*)gp;
          } else {
            v.x = (gx0 < IW) ? gp[0] : 0.f;
            v.y = (gx0 + 1 < IW) ? gp[1] : 0.f;
            v.z = (gx0 + 2 < IW) ? gp[2] : 0.f;
            v.w = 0.f;
          }
          *(float4*)&lds[(cl * 34 + r) * ROWF + 4 * f4] = v;
        }
      }
    }
    __syncthreads();

    if (live) {
      for (int cl = 0; cl < nch; ++cl) {
        float pr[4][4];
        const float* base = &lds[(cl * 34 + cy) * ROWF + cx];
#pragma unroll
        for (int r = 0; r < 4; ++r) {
          float2 u0 = *(const float2*)(base + r * ROWF);
          float2 u1 = *(const float2*)(base + r * ROWF + 2);
          pr[r][0] = u0.x; pr[r][1] = u0.y; pr[r][2] = u1.x; pr[r][3] = u1.y;
        }
#pragma unroll
        for (int o = 0; o < OCB; ++o) {
          const float* wp = &wlds[(o * CI_CHUNK + cl) * 12];
          const float4 wA = *(const float4*)wp;
          const float4 wB = *(const float4*)(wp + 4);
          const float w8 = wp[8];
          const float wv[9] = {wA.x, wA.y, wA.z, wA.w, wB.x, wB.y, wB.z, wB.w,
                               w8};
#pragma unroll
          for (int ky = 0; ky < 3; ++ky)
#pragma unroll
            for (int kx = 0; kx < 3; ++kx) {
              const float ww = wv[ky * 3 + kx];
#pragma unroll
              for (int r = 0; r < 2; ++r)
#pragma unroll
                for (int c = 0; c < 2; ++c)
                  acc[o][r][c] = fmaf(ww, pr[r + ky][c + kx], acc[o][r][c]);
            }
        }
      }
    }
  }

  if (POOL) {
    const int py = tY * 16 + ty, px = tX * 16 + tx;
    if (py < OH && px < OW) {
#pragma unroll
      for (int o = 0; o < OCB; ++o) {
        const float bb = DO_BIAS ? bias[oc0 + o] : 0.f;
        float s = 0.f;
#pragma unroll
        for (int r = 0; r < 2; ++r)
#pragma unroll
          for (int c = 0; c < 2; ++c) {
            float v = acc[o][r][c] + bb;
            if (DO_SELU) v = selu_f(v);
            s += v;
          }
        const float rv = 0.25f * s;
        const int oc = oc0 + o;
        if (outB != nullptr && b >= splitB)
          outB[(((long)(b - splitB) * Cout + oc) * OH + py) * OW + px] = rv;
        else
          outA[(((long)b * Cout + oc) * OH + py) * OW + px] = rv;
      }
    }
  } else {
#pragma unroll
    for (int o = 0; o < OCB; ++o) {
      const float bb = DO_BIAS ? bias[oc0 + o] : 0.f;
      const int oc = oc0 + o;
#pragma unroll
      for (int r = 0; r < 2; ++r)
#pragma unroll
        for (int c = 0; c < 2; ++c) {
          const int oy = cy0 + cy + r, ox = cx0 + cx + c;
          if (oy < OH && ox < OW) {
            float v = acc[o][r][c] + bb;
            if (DO_SELU) v = selu_f(v);
            float* dst =
                (outB != nullptr && b >= splitB)
                    ? &outB[(((long)(b - splitB) * Cout + oc) * OH + oy) * OW + ox]
                    : &outA[(((long)b * Cout + oc) * OH + oy) * OW + ox];
            *dst = v;
          }
        }
    }
  }
}

// -------- qkv for MFMA attention: qt,kt fp32 [Np][8]; vtb bf16 [Cpad][Np] ---
template <int Cpad>
__global__ __launch_bounds__(256) void k_qkvA(
    const float* __restrict__ x, const float* __restrict__ wq,
    const float* __restrict__ bq, const float* __restrict__ wk,
    const float* __restrict__ bk, const float* __restrict__ wv,
    const float* __restrict__ bv, float* __restrict__ qt,
    float* __restrict__ kt, unsigned short* __restrict__ vtb, int Bn, int C,
    int D, int N, int Np) {
  const int seg1 = Np * 8;
  const int S = 2 * seg1 + Cpad * Np;
  const int total = Bn * S;
  for (int idx = blockIdx.x * blockDim.x + threadIdx.x; idx < total;
       idx += gridDim.x * blockDim.x) {
    const int b = idx / S;
    const int rr = idx % S;
    const float* xb = x + (long)b * C * N;
    if (rr < 2 * seg1) {
      const bool isq = rr < seg1;
      const int t = isq ? rr : rr - seg1;
      const int n = t >> 3, co = t & 7;
      float val = 0.f;
      if (co < D && n < N) {
        const float* w = (isq ? wq : wk) + co * C;
        float a = (isq ? bq : bk)[co];
        for (int ci = 0; ci < C; ++ci) a = fmaf(w[ci], xb[(long)ci * N + n], a);
        val = a;
      }
      (isq ? qt : kt)[((long)b * Np + n) * 8 + co] = val;
    } else {
      const int t = rr - 2 * seg1;
      const int c = t / Np, n = t % Np;
      unsigned short v = 0;
      if (c < C && n < N) {
        const float* w = wv + c * C;
        float a = bv[c];
        for (int ci = 0; ci < C; ++ci) a = fmaf(w[ci], xb[(long)ci * N + n], a);
        v = (unsigned short)f2bf(a);
      }
      vtb[((long)b * Cpad + c) * Np + n] = v;
    }
  }
}

// ---------------- MFMA flash attention + residual ----------------
template <int C, int CB>
__global__ __launch_bounds__(256) void k_attnM(
    const float* __restrict__ x, const float* __restrict__ qt,
    const float* __restrict__ kt, const unsigned short* __restrict__ vtb,
    const float* __restrict__ gamma_p, float* __restrict__ out, int N, int Np,
    int nqt) {
  constexpr int Cpad = CB * 16;
  __shared__ float pO[4][CB * 256];
  __shared__ float pD[4][16];

  const int bid = blockIdx.x;
  const int b = bid / nqt;
  const int n0 = (bid % nqt) * 16;
  const int tid = threadIdx.x;
  const int wv_ = tid >> 6;
  const int lane = tid & 63;
  const int g = lane >> 4;
  const int qi = lane & 15;
  const int nq = n0 + qi;

  const float* qrow = qt + ((long)b * Np + nq) * 8;
  const float4 q0 = *(const float4*)qrow;
  const float2 q1 = *(const float2*)(qrow + 4);
  const float* kb_ = kt + (long)b * Np * 8;
  const unsigned short* vb_ = vtb + (long)b * Cpad * Np;

  f32x4 acc[CB];
#pragma unroll
  for (int cb = 0; cb < CB; ++cb) {
    f32x4 z = {0.f, 0.f, 0.f, 0.f};
    acc[cb] = z;
  }
  float den = 0.f;

  const int ntile = Np >> 5;
  for (int t = wv_; t < ntile; t += 4) {
    const int mb = t * 32 + g * 8;
    float4 ka[8];
    float2 kc[8];
#pragma unroll
    for (int i = 0; i < 8; ++i) {
      const float* kr = kb_ + (long)(mb + i) * 8;
      ka[i] = *(const float4*)kr;
      kc[i] = *(const float2*)(kr + 4);
    }
    float p[8];
#pragma unroll
    for (int i = 0; i < 8; ++i) {
      float e = q0.x * ka[i].x;
      e = fmaf(q0.y, ka[i].y, e);
      e = fmaf(q0.z, ka[i].z, e);
      e = fmaf(q0.w, ka[i].w, e);
      e = fmaf(q1.x, kc[i].x, e);
      e = fmaf(q1.y, kc[i].y, e);
      const float pv = __expf(e);
      p[i] = (mb + i < N) ? pv : 0.f;
      den += p[i];
    }
    bf16x8 pb;
#pragma unroll
    for (int i = 0; i < 8; ++i) pb[i] = f2bf(p[i]);
#pragma unroll
    for (int cb = 0; cb < CB; ++cb) {
      const bf16x8 va = *(const bf16x8*)(vb_ + (long)(cb * 16 + qi) * Np + mb);
      acc[cb] =
          __builtin_amdgcn_mfma_f32_16x16x32_bf16(va, pb, acc[cb], 0, 0, 0);
    }
  }

  den += __shfl_xor(den, 16, 64);
  den += __shfl_xor(den, 32, 64);

#pragma unroll
  for (int cb = 0; cb < CB; ++cb)
#pragma unroll
    for (int r = 0; r < 4; ++r)
      pO[wv_][cb * 256 + (4 * g + r) * 16 + qi] = acc[cb][r];
  if (g == 0) pD[wv_][qi] = den;
  __syncthreads();

  const float gma = gamma_p[0];
#pragma unroll
  for (int cb = 0; cb < CB; ++cb) {
    const int cell = cb * 256 + tid;
    const int c = cb * 16 + (tid >> 4);
    const int q = tid & 15;
    const int n = n0 + q;
    if (c < C && n < N) {
      const float s = pO[0][cell] + pO[1][cell] + pO[2][cell] + pO[3][cell];
      const float Dn = pD[0][q] + pD[1][q] + pD[2][q] + pD[3][q];
      const long o = ((long)b * C + c) * N + n;
      out[o] = fmaf(gma, s / Dn, x[o]);
    }
  }
}

// ---------------- q/k/v projections (attn3 small path) ----------------
template <int Cp>
__global__ __launch_bounds__(256) void k_qkv3(
    const float* __restrict__ x, const float* __restrict__ wq,
    const float* __restrict__ bq, const float* __restrict__ wk,
    const float* __restrict__ bk, const float* __restrict__ wv,
    const float* __restrict__ bv, float* __restrict__ qt,
    float* __restrict__ kt, float* __restrict__ vt, int Bn, int C, int D,
    int N, int Np) {
  constexpr int KP = 8;
  const int S = Np * (2 * KP + Cp);
  const int total = Bn * S;
  for (int idx = blockIdx.x * blockDim.x + threadIdx.x; idx < total;
       idx += gridDim.x * blockDim.x) {
    const int b = idx / S;
    const int rr = idx % S;
    const float* xb = x + (long)b * C * N;
    const float* w = nullptr;
    const float* bp = nullptr;
    float* dst;
    int n, co, lim;
    if (rr < Np * KP) {
      n = rr / KP; co = rr % KP; lim = D;
      w = wq + co * C; bp = bq;
      dst = qt + ((long)b * Np + n) * KP + co;
    } else if (rr < 2 * Np * KP) {
      const int t = rr - Np * KP;
      n = t / KP; co = t % KP; lim = D;
      w = wk + co * C; bp = bk;
      dst = kt + ((long)b * Np + n) * KP + co;
    } else {
      const int t = rr - 2 * Np * KP;
      n = t / Cp; co = t % Cp; lim = C;
      w = wv + co * C; bp = bv;
      dst = vt + ((long)b * Np + n) * Cp + co;
    }
    if (co < lim && n < N) {
      float a = bp[co];
      for (int ci = 0; ci < C; ++ci) a = fmaf(w[ci], xb[(long)ci * N + n], a);
      *dst = a;
    } else {
      *dst = 0.f;
    }
  }
}

// ---------------- flash attention partials (attn3 small path) ---------------
template <int C, int Chp>
__global__ __launch_bounds__(128) void k_attn7(
    const float* __restrict__ qt, const float* __restrict__ kt,
    const float* __restrict__ vt, float* __restrict__ num,
    float* __restrict__ den, int N, int nbr, int S, int msz, int Np, int Nr) {
  constexpr int KP = 8;
  constexpr int Cp = 2 * Chp;
  constexpr int NV = Chp / 4;
  int bid = blockIdx.x;
  const int s = bid % S; bid /= S;
  const int rb = bid % nbr;
  const int b = bid / nbr;
  const int brow = rb * 32;
  const int tid = threadIdx.x;
  const int lane = tid & 63;
  const int cg = tid >> 6;
  const int g = lane >> 4;
  const int r = lane & 15;

  const float* qb = qt + (long)b * Np * KP;
  const float* kb = kt + (long)b * Np * KP;
  const float* vb = vt + (long)b * Np * Cp;

  float4 q0[2];
  float2 q1[2];
#pragma unroll
  for (int k = 0; k < 2; ++k) {
    const int n = brow + r + 16 * k;
    q0[k] = *(const float4*)(qb + (long)n * KP);
    q1[k] = *(const float2*)(qb + (long)n * KP + 4);
  }

  float acc[2][Chp];
#pragma unroll
  for (int k = 0; k < 2; ++k)
#pragma unroll
    for (int c = 0; c < Chp; ++c) acc[k][c] = 0.f;
  float sm[2] = {0.f, 0.f};

  const int mstart = s * msz;
  const int mlimit = min(mstart + msz, N);
  for (int m0 = mstart; m0 < mlimit; m0 += 4) {
    const int m = m0 + g;
    const float4 ka = *(const float4*)(kb + (long)m * KP);
    const float2 kc = *(const float2*)(kb + (long)m * KP + 4);
    float4 vv[NV];
    const float4* vp = (const float4*)(vb + (long)m * Cp + cg * Chp);
#pragma unroll
    for (int j = 0; j < NV; ++j) vv[j] = vp[j];
#pragma unroll
    for (int k = 0; k < 2; ++k) {
      float e = q0[k].x * ka.x;
      e = fmaf(q0[k].y, ka.y, e);
      e = fmaf(q0[k].z, ka.z, e);
      e = fmaf(q0[k].w, ka.w, e);
      e = fmaf(q1[k].x, kc.x, e);
      e = fmaf(q1[k].y, kc.y, e);
      const float p = __expf(e);
      sm[k] += p;
#pragma unroll
      for (int j = 0; j < NV; ++j) {
        acc[k][4 * j + 0] = fmaf(p, vv[j].x, acc[k][4 * j + 0]);
        acc[k][4 * j + 1] = fmaf(p, vv[j].y, acc[k][4 * j + 1]);
        acc[k][4 * j + 2] = fmaf(p, vv[j].z, acc[k][4 * j + 2]);
        acc[k][4 * j + 3] = fmaf(p, vv[j].w, acc[k][4 * j + 3]);
      }
    }
  }

#pragma unroll
  for (int k = 0; k < 2; ++k) {
    sm[k] += __shfl_xor(sm[k], 16, 64);
    sm[k] += __shfl_xor(sm[k], 32, 64);
#pragma unroll
    for (int c = 0; c < Chp; ++c) {
      acc[k][c] += __shfl_xor(acc[k][c], 16, 64);
      acc[k][c] += __shfl_xor(acc[k][c], 32, 64);
    }
  }

  if (g == 0) {
    float* np_ = num + ((long)(s * 8 + b) * Cp + cg * Chp) * Nr;
    float* dp_ = den + (long)(s * 8 + b) * Nr;
#pragma unroll
    for (int k = 0; k < 2; ++k) {
      const int n = brow + r + 16 * k;
      if (n < N) {
#pragma unroll
        for (int c = 0; c < Chp; ++c) np_[(long)c * Nr + n] = acc[k][c];
        if (cg == 0) dp_[n] = sm[k];
      }
    }
  }
}

// ---------------- attention merge (attn3 small path) ----------------
__global__ __launch_bounds__(256) void k_attnmerge(
    const float* __restrict__ x, const float* __restrict__ num,
    const float* __restrict__ den, const float* __restrict__ gamma_p,
    float* __restrict__ out, int C, int Cp, int N, int Nr, int S) {
  const float g = gamma_p[0];
  const int total = 8 * C * N;
  for (int idx = blockIdx.x * blockDim.x + threadIdx.x; idx < total;
       idx += gridDim.x * blockDim.x) {
    const int n = idx % N;
    const int t = idx / N;
    const int c = t % C;
    const int b = t / C;
    float a = 0.f, d = 0.f;
    for (int s = 0; s < S; ++s) {
      a += num[((long)(s * 8 + b) * Cp + c) * Nr + n];
      d += den[(long)(s * 8 + b) * Nr + n];
    }
    out[((long)b * C + c) * N + n] =
        fmaf(g, a / d, x[((long)b * C + c) * N + n]);
  }
}

// ---------------- batchnorm stats: mean + rsqrt(var+eps) per channel --------
__global__ __launch_bounds__(256) void k_bnstats(const float* __restrict__ x,
                                                 float* __restrict__ stats,
                                                 int Bn, int C, int HW,
                                                 float eps) {
  int c = blockIdx.x;
  int tid = threadIdx.x;
  int cnt = Bn * HW;
  float s = 0.f, s2 = 0.f;
  for (int i = tid; i < cnt; i += blockDim.x) {
    int b = i / HW, r = i % HW;
    float v = x[((long)b * C + c) * HW + r];
    s += v;
    s2 += v * v;
  }
#pragma unroll
  for (int off = 32; off > 0; off >>= 1) {
    s += __shfl_down(s, off);
    s2 += __shfl_down(s2, off);
  }
  __shared__ float as_[4], as2_[4];
  int wid = tid >> 6;
  if ((tid & 63) == 0) { as_[wid] = s; as2_[wid] = s2; }
  __syncthreads();
  if (tid == 0) {
    float S = 0.f, S2 = 0.f;
#pragma unroll
    for (int ww = 0; ww < 4; ++ww) { S += as_[ww]; S2 += as2_[ww]; }
    float mean = S / (float)cnt;
    float var = S2 / (float)cnt - mean * mean;
    stats[c] = mean;
    stats[C + c] = rsqrtf(var + eps);
  }
}

// ---------------- BN apply + selu (+pool) ----------------
template <bool POOL>
__global__ __launch_bounds__(256) void k_bn_selu(
    const float* __restrict__ x, const float* __restrict__ stats,
    const float* __restrict__ g, const float* __restrict__ beta,
    float* __restrict__ out, int Bn, int C, int IH, int IW) {
  int OH = POOL ? (IH >> 1) : IH;
  int OW = POOL ? (IW >> 1) : IW;
  int total = Bn * C * OH * OW;
  for (int idx = blockIdx.x * blockDim.x + threadIdx.x; idx < total;
       idx += gridDim.x * blockDim.x) {
    int px = idx % OW;
    int t = idx / OW;
    int py = t % OH;
    t /= OH;
    int c = t % C;
    int b = t / C;
    float mean = stats[c], istd = stats[C + c];
    float gg = g[c], bb = beta[c];
    const float* ip = x + ((long)b * C + c) * IH * IW;
    float r;
    if (POOL) {
      int iy = py * 2, ix = px * 2;
      float v00 = selu_f((ip[iy * IW + ix] - mean) * istd * gg + bb);
      float v01 = selu_f((ip[iy * IW + ix + 1] - mean) * istd * gg + bb);
      float v10 = selu_f((ip[(iy + 1) * IW + ix] - mean) * istd * gg + bb);
      float v11 = selu_f((ip[(iy + 1) * IW + ix + 1] - mean) * istd * gg + bb);
      r = 0.25f * (v00 + v01 + v10 + v11);
    } else {
      r = selu_f((ip[py * IW + px] - mean) * istd * gg + bb);
    }
    out[((b * C + c) * OH + py) * OW + px] = r;
  }
}

static inline int gs(int total) { return (total + 255) / 256; }
static inline int cdiv(int a, int b) { return (a + b - 1) / b; }

extern "C" void kernel_launch(void* const* d_in, const int* in_sizes, int n_in,
                              void* d_out, int out_size, void* d_ws,
                              size_t ws_size, hipStream_t stream) {
  const float* x      = (const float*)d_in[0];
  const float* enc_w1 = (const float*)d_in[1];
  const float* enc_b1 = (const float*)d_in[2];
  const float* enc_w2 = (const float*)d_in[3];
  const float* enc_b2 = (const float*)d_in[4];
  const float* a1_wq  = (const float*)d_in[5];
  const float* a1_bq  = (const float*)d_in[6];
  const float* a1_wk  = (const float*)d_in[7];
  const float* a1_bk  = (const float*)d_in[8];
  const float* a1_wv  = (const float*)d_in[9];
  const float* a1_bv  = (const float*)d_in[10];
  const float* a1_g   = (const float*)d_in[11];
  const float* c1_w   = (const float*)d_in[12];
  const float* c1_b   = (const float*)d_in[13];
  const float* a2_wq  = (const float*)d_in[14];
  const float* a2_bq  = (const float*)d_in[15];
  const float* a2_wk  = (const float*)d_in[16];
  const float* a2_bk  = (const float*)d_in[17];
  const float* a2_wv  = (const float*)d_in[18];
  const float* a2_bv  = (const float*)d_in[19];
  const float* a2_g   = (const float*)d_in[20];
  const float* c2_w   = (const float*)d_in[21];
  const float* c2_b   = (const float*)d_in[22];
  const float* c3_w   = (const float*)d_in[23];
  const float* c3_g   = (const float*)d_in[24];
  const float* c3_be  = (const float*)d_in[25];
  const float* c4_w   = (const float*)d_in[26];
  const float* c4_g   = (const float*)d_in[27];
  const float* c4_be  = (const float*)d_in[28];
  const float* a3_wq  = (const float*)d_in[29];
  const float* a3_bq  = (const float*)d_in[30];
  const float* a3_wk  = (const float*)d_in[31];
  const float* a3_bk  = (const float*)d_in[32];
  const float* a3_wv  = (const float*)d_in[33];
  const float* a3_bv  = (const float*)d_in[34];
  const float* a3_g   = (const float*)d_in[35];

  float* out = (float*)d_out;
  float* W = (float*)d_ws;

  // ---- workspace plan (float slots; peak 5,056,320 = 20.2 MB, proven) ----
  float* h    = W;                         // [0, 1,920,000)
  float* h1   = W + 1920000;               // [1,920,000, 5,056,320)
  float* h2   = W;                         // [0, 737,280)
  float* xenc = out + 5120;                // (8,40,48,48) direct

  // attn1: Np1=2304, Cpad=48
  float* qt1 = W + 737280;                 // 147,456
  float* kt1 = W + 884736;                 // 147,456
  unsigned short* vtb1 = (unsigned short*)(W + 1032192);  // 884,736 bf16
  float* at1 = W + 1474560;                // 737,280 -> ends 2,211,840
  float* c1o = W + 2211840;                // 846,400 -> ends 3,058,240

  // attn2: Np2=2144, Cpad=64
  float* qt2 = W + 3058240;                // 137,216
  float* kt2 = W + 3195456;                // 137,216
  unsigned short* vtb2 = (unsigned short*)(W + 3332672);  // 1,097,728 bf16
  float* at2 = W + 3881536;                // 846,400 -> ends 4,727,936

  float* c2o  = W;                         // 154,880
  float* c3o  = W + 200000;                // 96,000
  float* st3  = W + 300000;                // 60
  float* c3p  = W + 310000;                // 24,000
  float* c4o  = W + 340000;                // 5,120
  float* st4  = W + 350000;                // 20
  float* c4b  = W + 360000;                // 5,120
  float* q3   = W + 370000;                // 8,192
  float* k3   = W + 380000;                // 8,192
  float* v3   = W + 390000;                // 16,384
  float* num3 = W + 410000;                // 8,192
  float* den3 = W + 420000;                // 512

  const int NOSPLIT = 1 << 30;

  // 1. prep
  {
    int n = 8 * 3 * 200 * 200;
    k_prep<<<gs(n), 256, 0, stream>>>(x, h, n);
  }
  // 2. enc conv1 + selu + pool : (16,3,200,200)->(16,20,99,99), OCB=5
  {
    int tXY = cdiv(99, 16);  // 7
    int blocks = 16 * (20 / 5) * tXY * tXY;  // 3136
    k_conv3x3o<true, true, true, 5><<<blocks, 256, 0, stream>>>(
        h, enc_w1, enc_b1, h1, nullptr, NOSPLIT, 16, 3, 20, 200, 200, tXY,
        tXY);
  }
  // 3. enc conv2 + selu + pool : (16,20,99,99)->(16,40,48,48), OCB=5
  {
    int tXY = cdiv(48, 16);  // 3
    int blocks = 16 * (40 / 5) * tXY * tXY;  // 1152
    k_conv3x3o<true, true, true, 5><<<blocks, 256, 0, stream>>>(
        h1, enc_w2, enc_b2, h2, xenc, 8, 16, 20, 40, 99, 99, tXY, tXY);
  }
  // 4. attn1 qkv : Cpad=48, Np=2304
  {
    int total = 8 * 2304 * (16 + 48);
    k_qkvA<48><<<gs(total), 256, 0, stream>>>(h2, a1_wq, a1_bq, a1_wk, a1_bk,
                                              a1_wv, a1_bv, qt1, kt1, vtb1, 8,
                                              40, 5, 2304, 2304);
  }
  // 5. attn1 (MFMA) : C=40, CB=3, nqt=144
  {
    k_attnM<40, 3><<<8 * 144, 256, 0, stream>>>(h2, qt1, kt1, vtb1, a1_g, at1,
                                                2304, 2304, 144);
  }
  // 6. c1 conv + selu : (8,40,48,48)->(8,50,46,46), OCB=2
  {
    int tXY = cdiv(46, 32);  // 2
    int blocks = 8 * (50 / 2) * tXY * tXY;  // 800
    k_conv3x3o<false, true, true, 2><<<blocks, 256, 0, stream>>>(
        at1, c1_w, c1_b, c1o, nullptr, NOSPLIT, 8, 40, 50, 48, 48, tXY, tXY);
  }
  // 7. attn2 qkv : Cpad=64, Np=2144
  {
    int total = 8 * 2144 * (16 + 64);
    k_qkvA<64><<<gs(total), 256, 0, stream>>>(c1o, a2_wq, a2_bq, a2_wk, a2_bk,
                                              a2_wv, a2_bv, qt2, kt2, vtb2, 8,
                                              50, 6, 2116, 2144);
  }
  // 8. attn2 (MFMA) : C=50, CB=4, nqt=133
  {
    k_attnM<50, 4><<<8 * 133, 256, 0, stream>>>(c1o, qt2, kt2, vtb2, a2_g, at2,
                                                2116, 2144, 133);
  }
  // 9. c2 conv + selu + pool : (8,50,46,46)->(8,40,22,22), OCB=2
  {
    int tXY = cdiv(22, 16);  // 2
    int blocks = 8 * (40 / 2) * tXY * tXY;  // 640
    k_conv3x3o<true, true, true, 2><<<blocks, 256, 0, stream>>>(
        at2, c2_w, c2_b, c2o, nullptr, NOSPLIT, 8, 50, 40, 46, 46, tXY, tXY);
  }
  // 10. c3 conv : (8,40,22,22)->(8,30,20,20), OCB=2
  {
    int tXY = cdiv(20, 32);  // 1
    int blocks = 8 * (30 / 2) * tXY * tXY;  // 120
    k_conv3x3o<false, false, false, 2><<<blocks, 256, 0, stream>>>(
        c2o, c3_w, nullptr, c3o, nullptr, NOSPLIT, 8, 40, 30, 22, 22, tXY,
        tXY);
  }
  // 11-12. BN(c3) + selu + pool -> (8,30,10,10)
  k_bnstats<<<30, 256, 0, stream>>>(c3o, st3, 8, 30, 400, 1e-5f);
  {
    int total = 8 * 30 * 10 * 10;
    k_bn_selu<true><<<gs(total), 256, 0, stream>>>(c3o, st3, c3_g, c3_be, c3p,
                                                   8, 30, 20, 20);
  }
  // 13. c4 conv : (8,30,10,10)->(8,10,8,8), OCB=2
  {
    int tXY = cdiv(8, 32);  // 1
    int blocks = 8 * (10 / 2) * tXY * tXY;  // 40
    k_conv3x3o<false, false, false, 2><<<blocks, 256, 0, stream>>>(
        c3p, c4_w, nullptr, c4o, nullptr, NOSPLIT, 8, 30, 10, 10, 10, tXY,
        tXY);
  }
  // 14-15. BN(c4) + selu
  k_bnstats<<<10, 256, 0, stream>>>(c4o, st4, 8, 10, 64, 1e-5f);
  {
    int total = 8 * 10 * 8 * 8;
    k_bn_selu<false><<<gs(total), 256, 0, stream>>>(c4o, st4, c4_g, c4_be, c4b,
                                                    8, 10, 8, 8);
  }
  // 16. attn3 qkv : Cp=16, Np=128
  {
    int total = 8 * 128 * (16 + 16);
    k_qkv3<16><<<gs(total), 256, 0, stream>>>(c4b, a3_wq, a3_bq, a3_wk, a3_bk,
                                              a3_wv, a3_bv, q3, k3, v3, 8, 10,
                                              1, 64, 128);
  }
  // 17. attn3 partials + merge -> out[0..5120)
  {
    int nbr = 2, S = 1, msz = 64;
    k_attn7<10, 8><<<8 * nbr * S, 128, 0, stream>>>(q3, k3, v3, num3, den3, 64,
                                                    nbr, S, msz, 128, 64);
    k_attnmerge<<<gs(8 * 10 * 64), 256, 0, stream>>>(c4b, num3, den3, a3_g,
                                                     out, 10, 16, 64, 64, S);
  }
}

// Round 11
// 502.128 us; speedup vs baseline: 1.9314x; 1.0384x over previous
//
#include <hip/hip_runtime.h>
#include <math.h>

// ClassificationBackbone: conv/attn pipeline.
// R11: full-MFMA attention. Q,K stored bf16 [Np][8]; E[m][q] per 16-m tile
// via one mfma (A=K rows, B=Q, k=8 real of 32); exp scalar on the 4 E rows
// each lane owns; P fragment built lane-locally with the bijective map
// (g,i) -> m = mb + 16*(i>>2) + 4g + (i&3), V A-frag gathered with the SAME
// map (permutation invariance => exact contraction). PV mfma as in R8.

#define DEVINL __device__ __forceinline__

using bf16x8 = __attribute__((ext_vector_type(8))) short;  // 8 bf16 (4 VGPRs)
using f32x4 = __attribute__((ext_vector_type(4))) float;   // 4 fp32

DEVINL float selu_f(float x) {
  const float scale = 1.0507009873554805f;
  const float alpha = 1.6732632423543772f;
  return scale * (x > 0.f ? x : alpha * (__expf(x) - 1.f));
}

DEVINL short f2bf(float f) {  // RNE fp32 -> bf16
  unsigned int u = __float_as_uint(f);
  u = (u + 0x7FFFu + ((u >> 16) & 1u)) >> 16;
  return (short)u;
}

// ---------------- prep: h = concat([x^0.25/255^0.25, x], batch) -------------
__global__ __launch_bounds__(256) void k_prep(const float* __restrict__ x,
                                              float* __restrict__ h, int n) {
  const float invScale = 0.250244727f;  // 255^-0.25
  for (int i = blockIdx.x * blockDim.x + threadIdx.x; i < n;
       i += gridDim.x * blockDim.x) {
    float v = x[i];
    h[i] = sqrtf(sqrtf(v)) * invScale;
    h[n + i] = v;
  }
}

// ------------- conv3x3, OCB ocs/block (+bias)(+selu)(+avgpool2) -------------
template <bool POOL, bool DO_SELU, bool DO_BIAS, int OCB>
__global__ __launch_bounds__(256, 4) void k_conv3x3o(
    const float* __restrict__ in, const float* __restrict__ w,
    const float* __restrict__ bias, float* __restrict__ outA,
    float* __restrict__ outB, int splitB, int Bn, int Cin, int Cout, int IH,
    int IW, int tilesX, int tilesY) {
  constexpr int CI_CHUNK = 5;
  constexpr int ROWF = 36;
  __shared__ __align__(16) float lds[CI_CHUNK * 34 * ROWF];
  __shared__ __align__(16) float wlds[OCB * CI_CHUNK * 12];

  const int CH = IH - 2, CW = IW - 2;
  const int OH = POOL ? (CH >> 1) : CH;
  const int OW = POOL ? (CW >> 1) : CW;

  int bid = blockIdx.x;
  const int tX = bid % tilesX; bid /= tilesX;
  const int tY = bid % tilesY; bid /= tilesY;
  const int nOcg = Cout / OCB;
  const int ocg = bid % nOcg;
  const int b = bid / nOcg;
  const int oc0 = ocg * OCB;

  const int tid = threadIdx.x;
  const int ty = tid >> 4, tx = tid & 15;
  const int cy = 2 * ty, cx = 2 * tx;
  const int cy0 = tY * 32, cx0 = tX * 32;
  const long inb = (long)b * Cin * IH * IW;

  const bool live = (cy0 + cy < CH) && (cx0 + cx < CW);

  float acc[OCB][2][2];
#pragma unroll
  for (int o = 0; o < OCB; ++o)
#pragma unroll
    for (int r = 0; r < 2; ++r)
#pragma unroll
      for (int c = 0; c < 2; ++c) acc[o][r][c] = 0.f;

  const int f4 = tid & 15;
  const int gx0 = cx0 + 4 * f4;

  for (int ci0 = 0; ci0 < Cin; ci0 += CI_CHUNK) {
    const int nch = min(CI_CHUNK, Cin - ci0);
    __syncthreads();
    for (int j = tid; j < OCB * CI_CHUNK * 9; j += 256) {
      const int o = j / (CI_CHUNK * 9);
      const int rem = j - o * (CI_CHUNK * 9);
      const int cl = rem / 9;
      const int kk = rem - 9 * cl;
      if (cl < nch)
        wlds[(o * CI_CHUNK + cl) * 12 + kk] =
            w[((long)(oc0 + o) * Cin + ci0 + cl) * 9 + kk];
    }
    for (int ra = tid >> 4; ra < nch * 34; ra += 16) {
      const int cl = ra / 34;
      const int r = ra - 34 * cl;
      if (f4 < 9) {
        const int gy = cy0 + r;
        if (gy < IH) {
          const float* gp = in + inb + ((long)(ci0 + cl) * IH + gy) * IW + gx0;
          float4 v;
          if (gx0 + 3 < IW) {
            v = *(const float4*)gp;
          } else {
            v.x = (gx0 < IW) ? gp[0] : 0.f;
            v.y = (gx0 + 1 < IW) ? gp[1] : 0.f;
            v.z = (gx0 + 2 < IW) ? gp[2] : 0.f;
            v.w = 0.f;
          }
          *(float4*)&lds[(cl * 34 + r) * ROWF + 4 * f4] = v;
        }
      }
    }
    __syncthreads();

    if (live) {
      for (int cl = 0; cl < nch; ++cl) {
        float pr[4][4];
        const float* base = &lds[(cl * 34 + cy) * ROWF + cx];
#pragma unroll
        for (int r = 0; r < 4; ++r) {
          float2 u0 = *(const float2*)(base + r * ROWF);
          float2 u1 = *(const float2*)(base + r * ROWF + 2);
          pr[r][0] = u0.x; pr[r][1] = u0.y; pr[r][2] = u1.x; pr[r][3] = u1.y;
        }
#pragma unroll
        for (int o = 0; o < OCB; ++o) {
          const float* wp = &wlds[(o * CI_CHUNK + cl) * 12];
          const float4 wA = *(const float4*)wp;
          const float4 wB = *(const float4*)(wp + 4);
          const float w8 = wp[8];
          const float wv[9] = {wA.x, wA.y, wA.z, wA.w, wB.x, wB.y, wB.z, wB.w,
                               w8};
#pragma unroll
          for (int ky = 0; ky < 3; ++ky)
#pragma unroll
            for (int kx = 0; kx < 3; ++kx) {
              const float ww = wv[ky * 3 + kx];
#pragma unroll
              for (int r = 0; r < 2; ++r)
#pragma unroll
                for (int c = 0; c < 2; ++c)
                  acc[o][r][c] = fmaf(ww, pr[r + ky][c + kx], acc[o][r][c]);
            }
        }
      }
    }
  }

  if (POOL) {
    const int py = tY * 16 + ty, px = tX * 16 + tx;
    if (py < OH && px < OW) {
#pragma unroll
      for (int o = 0; o < OCB; ++o) {
        const float bb = DO_BIAS ? bias[oc0 + o] : 0.f;
        float s = 0.f;
#pragma unroll
        for (int r = 0; r < 2; ++r)
#pragma unroll
          for (int c = 0; c < 2; ++c) {
            float v = acc[o][r][c] + bb;
            if (DO_SELU) v = selu_f(v);
            s += v;
          }
        const float rv = 0.25f * s;
        const int oc = oc0 + o;
        if (outB != nullptr && b >= splitB)
          outB[(((long)(b - splitB) * Cout + oc) * OH + py) * OW + px] = rv;
        else
          outA[(((long)b * Cout + oc) * OH + py) * OW + px] = rv;
      }
    }
  } else {
#pragma unroll
    for (int o = 0; o < OCB; ++o) {
      const float bb = DO_BIAS ? bias[oc0 + o] : 0.f;
      const int oc = oc0 + o;
#pragma unroll
      for (int r = 0; r < 2; ++r)
#pragma unroll
        for (int c = 0; c < 2; ++c) {
          const int oy = cy0 + cy + r, ox = cx0 + cx + c;
          if (oy < OH && ox < OW) {
            float v = acc[o][r][c] + bb;
            if (DO_SELU) v = selu_f(v);
            float* dst =
                (outB != nullptr && b >= splitB)
                    ? &outB[(((long)(b - splitB) * Cout + oc) * OH + oy) * OW + ox]
                    : &outA[(((long)b * Cout + oc) * OH + oy) * OW + ox];
            *dst = v;
          }
        }
    }
  }
}

// -------- qkv for MFMA attention: qtb,ktb bf16 [Np][8]; vtb bf16 [Cpad][Np] -
template <int Cpad>
__global__ __launch_bounds__(256) void k_qkvA(
    const float* __restrict__ x, const float* __restrict__ wq,
    const float* __restrict__ bq, const float* __restrict__ wk,
    const float* __restrict__ bk, const float* __restrict__ wv,
    const float* __restrict__ bv, unsigned short* __restrict__ qtb,
    unsigned short* __restrict__ ktb, unsigned short* __restrict__ vtb,
    int Bn, int C, int D, int N, int Np) {
  const int seg1 = Np * 8;
  const int S = 2 * seg1 + Cpad * Np;
  const int total = Bn * S;
  for (int idx = blockIdx.x * blockDim.x + threadIdx.x; idx < total;
       idx += gridDim.x * blockDim.x) {
    const int b = idx / S;
    const int rr = idx % S;
    const float* xb = x + (long)b * C * N;
    if (rr < 2 * seg1) {
      const bool isq = rr < seg1;
      const int t = isq ? rr : rr - seg1;
      const int n = t >> 3, co = t & 7;
      unsigned short val = 0;
      if (co < D && n < N) {
        const float* w = (isq ? wq : wk) + co * C;
        float a = (isq ? bq : bk)[co];
        for (int ci = 0; ci < C; ++ci) a = fmaf(w[ci], xb[(long)ci * N + n], a);
        val = (unsigned short)f2bf(a);
      }
      (isq ? qtb : ktb)[((long)b * Np + n) * 8 + co] = val;
    } else {
      const int t = rr - 2 * seg1;
      const int c = t / Np, n = t % Np;
      unsigned short v = 0;
      if (c < C && n < N) {
        const float* w = wv + c * C;
        float a = bv[c];
        for (int ci = 0; ci < C; ++ci) a = fmaf(w[ci], xb[(long)ci * N + n], a);
        v = (unsigned short)f2bf(a);
      }
      vtb[((long)b * Cpad + c) * Np + n] = v;
    }
  }
}

// ---------------- full-MFMA flash attention + residual ----------------
// Block = (batch, 16-q tile). 256 thr = 4 waves; wave w handles m-tiles
// t = w, w+4, ... (32 m per tile). qi = lane&15, g = lane>>4.
// E-mfma per 16-m subtile: A = K rows (lane row = m, g>0 zero-pad k>=8),
// B = Q (loaded once). E C-layout: col=q=qi, rows m = 4g+r. exp scalar.
// PV: pb slot (g, i) <-> m = mb + 16*(i>>2) + 4g + (i&3); V A-frag gathered
// with the same map (two 8B loads per cb). Softmax w/o max-sub (tiny e).
template <int C, int CB>
__global__ __launch_bounds__(256) void k_attnN(
    const float* __restrict__ x, const unsigned short* __restrict__ qtb,
    const unsigned short* __restrict__ ktb,
    const unsigned short* __restrict__ vtb,
    const float* __restrict__ gamma_p, float* __restrict__ out, int N, int Np,
    int nqt) {
  constexpr int Cpad = CB * 16;
  __shared__ float pO[4][CB * 256];
  __shared__ float pD[4][16];

  const int bid = blockIdx.x;
  const int b = bid / nqt;
  const int n0 = (bid % nqt) * 16;
  const int tid = threadIdx.x;
  const int wv_ = tid >> 6;
  const int lane = tid & 63;
  const int g = lane >> 4;
  const int qi = lane & 15;

  const unsigned short* qb_ = qtb + (long)b * Np * 8;
  const unsigned short* kb_ = ktb + (long)b * Np * 8;
  const unsigned short* vb_ = vtb + (long)b * Cpad * Np;

  // Q B-fragment: k = 8g+i; real k<8 only for g==0
  bf16x8 qf;
#pragma unroll
  for (int i = 0; i < 8; ++i) qf[i] = 0;
  if (g == 0) qf = *(const bf16x8*)(qb_ + (long)(n0 + qi) * 8);

  f32x4 acc[CB];
#pragma unroll
  for (int cb = 0; cb < CB; ++cb) {
    f32x4 z = {0.f, 0.f, 0.f, 0.f};
    acc[cb] = z;
  }
  float den = 0.f;
  const f32x4 z4 = {0.f, 0.f, 0.f, 0.f};

  const int ntile = Np >> 5;
  for (int t = wv_; t < ntile; t += 4) {
    const int mb = t * 32;
    bf16x8 kf0, kf1;
#pragma unroll
    for (int i = 0; i < 8; ++i) { kf0[i] = 0; kf1[i] = 0; }
    if (g == 0) {
      kf0 = *(const bf16x8*)(kb_ + (long)(mb + qi) * 8);
      kf1 = *(const bf16x8*)(kb_ + (long)(mb + 16 + qi) * 8);
    }
    const f32x4 e0 = __builtin_amdgcn_mfma_f32_16x16x32_bf16(kf0, qf, z4, 0, 0, 0);
    const f32x4 e1 = __builtin_amdgcn_mfma_f32_16x16x32_bf16(kf1, qf, z4, 0, 0, 0);

    bf16x8 pb;
#pragma unroll
    for (int r = 0; r < 4; ++r) {
      const int ma = mb + 4 * g + r;
      const int mc = ma + 16;
      const float p0 = (ma < N) ? __expf(e0[r]) : 0.f;
      const float p1 = (mc < N) ? __expf(e1[r]) : 0.f;
      den += p0 + p1;
      pb[r] = f2bf(p0);       // i = r   -> m = mb + 4g + r
      pb[4 + r] = f2bf(p1);   // i = 4+r -> m = mb + 16 + 4g + r
    }
#pragma unroll
    for (int cb = 0; cb < CB; ++cb) {
      const unsigned short* vrow =
          vb_ + (long)(cb * 16 + qi) * Np + mb + 4 * g;
      const ushort4 vlo = *(const ushort4*)vrow;         // i=0..3
      const ushort4 vhi = *(const ushort4*)(vrow + 16);  // i=4..7
      bf16x8 va;
      va[0] = (short)vlo.x; va[1] = (short)vlo.y;
      va[2] = (short)vlo.z; va[3] = (short)vlo.w;
      va[4] = (short)vhi.x; va[5] = (short)vhi.y;
      va[6] = (short)vhi.z; va[7] = (short)vhi.w;
      acc[cb] =
          __builtin_amdgcn_mfma_f32_16x16x32_bf16(va, pb, acc[cb], 0, 0, 0);
    }
  }

  den += __shfl_xor(den, 16, 64);
  den += __shfl_xor(den, 32, 64);

#pragma unroll
  for (int cb = 0; cb < CB; ++cb)
#pragma unroll
    for (int r = 0; r < 4; ++r)
      pO[wv_][cb * 256 + (4 * g + r) * 16 + qi] = acc[cb][r];
  if (g == 0) pD[wv_][qi] = den;
  __syncthreads();

  const float gma = gamma_p[0];
#pragma unroll
  for (int cb = 0; cb < CB; ++cb) {
    const int cell = cb * 256 + tid;
    const int c = cb * 16 + (tid >> 4);
    const int q = tid & 15;
    const int n = n0 + q;
    if (c < C && n < N) {
      const float s = pO[0][cell] + pO[1][cell] + pO[2][cell] + pO[3][cell];
      const float Dn = pD[0][q] + pD[1][q] + pD[2][q] + pD[3][q];
      const long o = ((long)b * C + c) * N + n;
      out[o] = fmaf(gma, s / Dn, x[o]);
    }
  }
}

// ---------------- q/k/v projections (attn3 small path) ----------------
template <int Cp>
__global__ __launch_bounds__(256) void k_qkv3(
    const float* __restrict__ x, const float* __restrict__ wq,
    const float* __restrict__ bq, const float* __restrict__ wk,
    const float* __restrict__ bk, const float* __restrict__ wv,
    const float* __restrict__ bv, float* __restrict__ qt,
    float* __restrict__ kt, float* __restrict__ vt, int Bn, int C, int D,
    int N, int Np) {
  constexpr int KP = 8;
  const int S = Np * (2 * KP + Cp);
  const int total = Bn * S;
  for (int idx = blockIdx.x * blockDim.x + threadIdx.x; idx < total;
       idx += gridDim.x * blockDim.x) {
    const int b = idx / S;
    const int rr = idx % S;
    const float* xb = x + (long)b * C * N;
    const float* w = nullptr;
    const float* bp = nullptr;
    float* dst;
    int n, co, lim;
    if (rr < Np * KP) {
      n = rr / KP; co = rr % KP; lim = D;
      w = wq + co * C; bp = bq;
      dst = qt + ((long)b * Np + n) * KP + co;
    } else if (rr < 2 * Np * KP) {
      const int t = rr - Np * KP;
      n = t / KP; co = t % KP; lim = D;
      w = wk + co * C; bp = bk;
      dst = kt + ((long)b * Np + n) * KP + co;
    } else {
      const int t = rr - 2 * Np * KP;
      n = t / Cp; co = t % Cp; lim = C;
      w = wv + co * C; bp = bv;
      dst = vt + ((long)b * Np + n) * Cp + co;
    }
    if (co < lim && n < N) {
      float a = bp[co];
      for (int ci = 0; ci < C; ++ci) a = fmaf(w[ci], xb[(long)ci * N + n], a);
      *dst = a;
    } else {
      *dst = 0.f;
    }
  }
}

// ---------------- flash attention partials (attn3 small path) ---------------
template <int C, int Chp>
__global__ __launch_bounds__(128) void k_attn7(
    const float* __restrict__ qt, const float* __restrict__ kt,
    const float* __restrict__ vt, float* __restrict__ num,
    float* __restrict__ den, int N, int nbr, int S, int msz, int Np, int Nr) {
  constexpr int KP = 8;
  constexpr int Cp = 2 * Chp;
  constexpr int NV = Chp / 4;
  int bid = blockIdx.x;
  const int s = bid % S; bid /= S;
  const int rb = bid % nbr;
  const int b = bid / nbr;
  const int brow = rb * 32;
  const int tid = threadIdx.x;
  const int lane = tid & 63;
  const int cg = tid >> 6;
  const int g = lane >> 4;
  const int r = lane & 15;

  const float* qb = qt + (long)b * Np * KP;
  const float* kb = kt + (long)b * Np * KP;
  const float* vb = vt + (long)b * Np * Cp;

  float4 q0[2];
  float2 q1[2];
#pragma unroll
  for (int k = 0; k < 2; ++k) {
    const int n = brow + r + 16 * k;
    q0[k] = *(const float4*)(qb + (long)n * KP);
    q1[k] = *(const float2*)(qb + (long)n * KP + 4);
  }

  float acc[2][Chp];
#pragma unroll
  for (int k = 0; k < 2; ++k)
#pragma unroll
    for (int c = 0; c < Chp; ++c) acc[k][c] = 0.f;
  float sm[2] = {0.f, 0.f};

  const int mstart = s * msz;
  const int mlimit = min(mstart + msz, N);
  for (int m0 = mstart; m0 < mlimit; m0 += 4) {
    const int m = m0 + g;
    const float4 ka = *(const float4*)(kb + (long)m * KP);
    const float2 kc = *(const float2*)(kb + (long)m * KP + 4);
    float4 vv[NV];
    const float4* vp = (const float4*)(vb + (long)m * Cp + cg * Chp);
#pragma unroll
    for (int j = 0; j < NV; ++j) vv[j] = vp[j];
#pragma unroll
    for (int k = 0; k < 2; ++k) {
      float e = q0[k].x * ka.x;
      e = fmaf(q0[k].y, ka.y, e);
      e = fmaf(q0[k].z, ka.z, e);
      e = fmaf(q0[k].w, ka.w, e);
      e = fmaf(q1[k].x, kc.x, e);
      e = fmaf(q1[k].y, kc.y, e);
      const float p = __expf(e);
      sm[k] += p;
#pragma unroll
      for (int j = 0; j < NV; ++j) {
        acc[k][4 * j + 0] = fmaf(p, vv[j].x, acc[k][4 * j + 0]);
        acc[k][4 * j + 1] = fmaf(p, vv[j].y, acc[k][4 * j + 1]);
        acc[k][4 * j + 2] = fmaf(p, vv[j].z, acc[k][4 * j + 2]);
        acc[k][4 * j + 3] = fmaf(p, vv[j].w, acc[k][4 * j + 3]);
      }
    }
  }

#pragma unroll
  for (int k = 0; k < 2; ++k) {
    sm[k] += __shfl_xor(sm[k], 16, 64);
    sm[k] += __shfl_xor(sm[k], 32, 64);
#pragma unroll
    for (int c = 0; c < Chp; ++c) {
      acc[k][c] += __shfl_xor(acc[k][c], 16, 64);
      acc[k][c] += __shfl_xor(acc[k][c], 32, 64);
    }
  }

  if (g == 0) {
    float* np_ = num + ((long)(s * 8 + b) * Cp + cg * Chp) * Nr;
    float* dp_ = den + (long)(s * 8 + b) * Nr;
#pragma unroll
    for (int k = 0; k < 2; ++k) {
      const int n = brow + r + 16 * k;
      if (n < N) {
#pragma unroll
        for (int c = 0; c < Chp; ++c) np_[(long)c * Nr + n] = acc[k][c];
        if (cg == 0) dp_[n] = sm[k];
      }
    }
  }
}

// ---------------- attention merge (attn3 small path) ----------------
__global__ __launch_bounds__(256) void k_attnmerge(
    const float* __restrict__ x, const float* __restrict__ num,
    const float* __restrict__ den, const float* __restrict__ gamma_p,
    float* __restrict__ out, int C, int Cp, int N, int Nr, int S) {
  const float g = gamma_p[0];
  const int total = 8 * C * N;
  for (int idx = blockIdx.x * blockDim.x + threadIdx.x; idx < total;
       idx += gridDim.x * blockDim.x) {
    const int n = idx % N;
    const int t = idx / N;
    const int c = t % C;
    const int b = t / C;
    float a = 0.f, d = 0.f;
    for (int s = 0; s < S; ++s) {
      a += num[((long)(s * 8 + b) * Cp + c) * Nr + n];
      d += den[(long)(s * 8 + b) * Nr + n];
    }
    out[((long)b * C + c) * N + n] =
        fmaf(g, a / d, x[((long)b * C + c) * N + n]);
  }
}

// ---------------- batchnorm stats: mean + rsqrt(var+eps) per channel --------
__global__ __launch_bounds__(256) void k_bnstats(const float* __restrict__ x,
                                                 float* __restrict__ stats,
                                                 int Bn, int C, int HW,
                                                 float eps) {
  int c = blockIdx.x;
  int tid = threadIdx.x;
  int cnt = Bn * HW;
  float s = 0.f, s2 = 0.f;
  for (int i = tid; i < cnt; i += blockDim.x) {
    int b = i / HW, r = i % HW;
    float v = x[((long)b * C + c) * HW + r];
    s += v;
    s2 += v * v;
  }
#pragma unroll
  for (int off = 32; off > 0; off >>= 1) {
    s += __shfl_down(s, off);
    s2 += __shfl_down(s2, off);
  }
  __shared__ float as_[4], as2_[4];
  int wid = tid >> 6;
  if ((tid & 63) == 0) { as_[wid] = s; as2_[wid] = s2; }
  __syncthreads();
  if (tid == 0) {
    float S = 0.f, S2 = 0.f;
#pragma unroll
    for (int ww = 0; ww < 4; ++ww) { S += as_[ww]; S2 += as2_[ww]; }
    float mean = S / (float)cnt;
    float var = S2 / (float)cnt - mean * mean;
    stats[c] = mean;
    stats[C + c] = rsqrtf(var + eps);
  }
}

// ---------------- BN apply + selu (+pool) ----------------
template <bool POOL>
__global__ __launch_bounds__(256) void k_bn_selu(
    const float* __restrict__ x, const float* __restrict__ stats,
    const float* __restrict__ g, const float* __restrict__ beta,
    float* __restrict__ out, int Bn, int C, int IH, int IW) {
  int OH = POOL ? (IH >> 1) : IH;
  int OW = POOL ? (IW >> 1) : IW;
  int total = Bn * C * OH * OW;
  for (int idx = blockIdx.x * blockDim.x + threadIdx.x; idx < total;
       idx += gridDim.x * blockDim.x) {
    int px = idx % OW;
    int t = idx / OW;
    int py = t % OH;
    t /= OH;
    int c = t % C;
    int b = t / C;
    float mean = stats[c], istd = stats[C + c];
    float gg = g[c], bb = beta[c];
    const float* ip = x + ((long)b * C + c) * IH * IW;
    float r;
    if (POOL) {
      int iy = py * 2, ix = px * 2;
      float v00 = selu_f((ip[iy * IW + ix] - mean) * istd * gg + bb);
      float v01 = selu_f((ip[iy * IW + ix + 1] - mean) * istd * gg + bb);
      float v10 = selu_f((ip[(iy + 1) * IW + ix] - mean) * istd * gg + bb);
      float v11 = selu_f((ip[(iy + 1) * IW + ix + 1] - mean) * istd * gg + bb);
      r = 0.25f * (v00 + v01 + v10 + v11);
    } else {
      r = selu_f((ip[py * IW + px] - mean) * istd * gg + bb);
    }
    out[((b * C + c) * OH + py) * OW + px] = r;
  }
}

static inline int gs(int total) { return (total + 255) / 256; }
static inline int cdiv(int a, int b) { return (a + b - 1) / b; }

extern "C" void kernel_launch(void* const* d_in, const int* in_sizes, int n_in,
                              void* d_out, int out_size, void* d_ws,
                              size_t ws_size, hipStream_t stream) {
  const float* x      = (const float*)d_in[0];
  const float* enc_w1 = (const float*)d_in[1];
  const float* enc_b1 = (const float*)d_in[2];
  const float* enc_w2 = (const float*)d_in[3];
  const float* enc_b2 = (const float*)d_in[4];
  const float* a1_wq  = (const float*)d_in[5];
  const float* a1_bq  = (const float*)d_in[6];
  const float* a1_wk  = (const float*)d_in[7];
  const float* a1_bk  = (const float*)d_in[8];
  const float* a1_wv  = (const float*)d_in[9];
  const float* a1_bv  = (const float*)d_in[10];
  const float* a1_g   = (const float*)d_in[11];
  const float* c1_w   = (const float*)d_in[12];
  const float* c1_b   = (const float*)d_in[13];
  const float* a2_wq  = (const float*)d_in[14];
  const float* a2_bq  = (const float*)d_in[15];
  const float* a2_wk  = (const float*)d_in[16];
  const float* a2_bk  = (const float*)d_in[17];
  const float* a2_wv  = (const float*)d_in[18];
  const float* a2_bv  = (const float*)d_in[19];
  const float* a2_g   = (const float*)d_in[20];
  const float* c2_w   = (const float*)d_in[21];
  const float* c2_b   = (const float*)d_in[22];
  const float* c3_w   = (const float*)d_in[23];
  const float* c3_g   = (const float*)d_in[24];
  const float* c3_be  = (const float*)d_in[25];
  const float* c4_w   = (const float*)d_in[26];
  const float* c4_g   = (const float*)d_in[27];
  const float* c4_be  = (const float*)d_in[28];
  const float* a3_wq  = (const float*)d_in[29];
  const float* a3_bq  = (const float*)d_in[30];
  const float* a3_wk  = (const float*)d_in[31];
  const float* a3_bk  = (const float*)d_in[32];
  const float* a3_wv  = (const float*)d_in[33];
  const float* a3_bv  = (const float*)d_in[34];
  const float* a3_g   = (const float*)d_in[35];

  float* out = (float*)d_out;
  float* W = (float*)d_ws;

  // ---- workspace plan (float slots; peak 5,056,320 = 20.2 MB, proven) ----
  float* h    = W;                         // [0, 1,920,000)
  float* h1   = W + 1920000;               // [1,920,000, 5,056,320)
  float* h2   = W;                         // [0, 737,280)
  float* xenc = out + 5120;                // (8,40,48,48) direct

  // attn1: Np1=2304, Cpad=48 (qtb/ktb bf16 [Np][8]; slots oversized, aligned)
  unsigned short* qtb1 = (unsigned short*)(W + 737280);   // 147,456 bf16
  unsigned short* ktb1 = (unsigned short*)(W + 884736);   // 147,456 bf16
  unsigned short* vtb1 = (unsigned short*)(W + 1032192);  // 884,736 bf16
  float* at1 = W + 1474560;                // 737,280 -> ends 2,211,840
  float* c1o = W + 2211840;                // 846,400 -> ends 3,058,240

  // attn2: Np2=2144, Cpad=64
  unsigned short* qtb2 = (unsigned short*)(W + 3058240);  // 137,216 bf16
  unsigned short* ktb2 = (unsigned short*)(W + 3195456);  // 137,216 bf16
  unsigned short* vtb2 = (unsigned short*)(W + 3332672);  // 1,097,728 bf16
  float* at2 = W + 3881536;                // 846,400 -> ends 4,727,936

  float* c2o  = W;                         // 154,880
  float* c3o  = W + 200000;                // 96,000
  float* st3  = W + 300000;                // 60
  float* c3p  = W + 310000;                // 24,000
  float* c4o  = W + 340000;                // 5,120
  float* st4  = W + 350000;                // 20
  float* c4b  = W + 360000;                // 5,120
  float* q3   = W + 370000;                // 8,192
  float* k3   = W + 380000;                // 8,192
  float* v3   = W + 390000;                // 16,384
  float* num3 = W + 410000;                // 8,192
  float* den3 = W + 420000;                // 512

  const int NOSPLIT = 1 << 30;

  // 1. prep
  {
    int n = 8 * 3 * 200 * 200;
    k_prep<<<gs(n), 256, 0, stream>>>(x, h, n);
  }
  // 2. enc conv1 + selu + pool : (16,3,200,200)->(16,20,99,99), OCB=5
  {
    int tXY = cdiv(99, 16);  // 7
    int blocks = 16 * (20 / 5) * tXY * tXY;  // 3136
    k_conv3x3o<true, true, true, 5><<<blocks, 256, 0, stream>>>(
        h, enc_w1, enc_b1, h1, nullptr, NOSPLIT, 16, 3, 20, 200, 200, tXY,
        tXY);
  }
  // 3. enc conv2 + selu + pool : (16,20,99,99)->(16,40,48,48), OCB=5
  {
    int tXY = cdiv(48, 16);  // 3
    int blocks = 16 * (40 / 5) * tXY * tXY;  // 1152
    k_conv3x3o<true, true, true, 5><<<blocks, 256, 0, stream>>>(
        h1, enc_w2, enc_b2, h2, xenc, 8, 16, 20, 40, 99, 99, tXY, tXY);
  }
  // 4. attn1 qkv : Cpad=48, Np=2304
  {
    int total = 8 * 2304 * (16 + 48);
    k_qkvA<48><<<gs(total), 256, 0, stream>>>(h2, a1_wq, a1_bq, a1_wk, a1_bk,
                                              a1_wv, a1_bv, qtb1, ktb1, vtb1,
                                              8, 40, 5, 2304, 2304);
  }
  // 5. attn1 (full MFMA) : C=40, CB=3, nqt=144
  {
    k_attnN<40, 3><<<8 * 144, 256, 0, stream>>>(h2, qtb1, ktb1, vtb1, a1_g,
                                                at1, 2304, 2304, 144);
  }
  // 6. c1 conv + selu : (8,40,48,48)->(8,50,46,46), OCB=2
  {
    int tXY = cdiv(46, 32);  // 2
    int blocks = 8 * (50 / 2) * tXY * tXY;  // 800
    k_conv3x3o<false, true, true, 2><<<blocks, 256, 0, stream>>>(
        at1, c1_w, c1_b, c1o, nullptr, NOSPLIT, 8, 40, 50, 48, 48, tXY, tXY);
  }
  // 7. attn2 qkv : Cpad=64, Np=2144
  {
    int total = 8 * 2144 * (16 + 64);
    k_qkvA<64><<<gs(total), 256, 0, stream>>>(c1o, a2_wq, a2_bq, a2_wk, a2_bk,
                                              a2_wv, a2_bv, qtb2, ktb2, vtb2,
                                              8, 50, 6, 2116, 2144);
  }
  // 8. attn2 (full MFMA) : C=50, CB=4, nqt=133
  {
    k_attnN<50, 4><<<8 * 133, 256, 0, stream>>>(c1o, qtb2, ktb2, vtb2, a2_g,
                                                at2, 2116, 2144, 133);
  }
  // 9. c2 conv + selu + pool : (8,50,46,46)->(8,40,22,22), OCB=2
  {
    int tXY = cdiv(22, 16);  // 2
    int blocks = 8 * (40 / 2) * tXY * tXY;  // 640
    k_conv3x3o<true, true, true, 2><<<blocks, 256, 0, stream>>>(
        at2, c2_w, c2_b, c2o, nullptr, NOSPLIT, 8, 50, 40, 46, 46, tXY, tXY);
  }
  // 10. c3 conv : (8,40,22,22)->(8,30,20,20), OCB=2
  {
    int tXY = cdiv(20, 32);  // 1
    int blocks = 8 * (30 / 2) * tXY * tXY;  // 120
    k_conv3x3o<false, false, false, 2><<<blocks, 256, 0, stream>>>(
        c2o, c3_w, nullptr, c3o, nullptr, NOSPLIT, 8, 40, 30, 22, 22, tXY,
        tXY);
  }
  // 11-12. BN(c3) + selu + pool -> (8,30,10,10)
  k_bnstats<<<30, 256, 0, stream>>>(c3o, st3, 8, 30, 400, 1e-5f);
  {
    int total = 8 * 30 * 10 * 10;
    k_bn_selu<true><<<gs(total), 256, 0, stream>>>(c3o, st3, c3_g, c3_be, c3p,
                                                   8, 30, 20, 20);
  }
  // 13. c4 conv : (8,30,10,10)->(8,10,8,8), OCB=2
  {
    int tXY = cdiv(8, 32);  // 1
    int blocks = 8 * (10 / 2) * tXY * tXY;  // 40
    k_conv3x3o<false, false, false, 2><<<blocks, 256, 0, stream>>>(
        c3p, c4_w, nullptr, c4o, nullptr, NOSPLIT, 8, 30, 10, 10, 10, tXY,
        tXY);
  }
  // 14-15. BN(c4) + selu
  k_bnstats<<<10, 256, 0, stream>>>(c4o, st4, 8, 10, 64, 1e-5f);
  {
    int total = 8 * 10 * 8 * 8;
    k_bn_selu<false><<<gs(total), 256, 0, stream>>>(c4o, st4, c4_g, c4_be, c4b,
                                                    8, 10, 8, 8);
  }
  // 16. attn3 qkv : Cp=16, Np=128
  {
    int total = 8 * 128 * (16 + 16);
    k_qkv3<16><<<gs(total), 256, 0, stream>>>(c4b, a3_wq, a3_bq, a3_wk, a3_bk,
                                              a3_wv, a3_bv, q3, k3, v3, 8, 10,
                                              1, 64, 128);
  }
  // 17. attn3 partials + merge -> out[0..5120)
  {
    int nbr = 2, S = 1, msz = 64;
    k_attn7<10, 8><<<8 * nbr * S, 128, 0, stream>>>(q3, k3, v3, num3, den3, 64,
                                                    nbr, S, msz, 128, 64);
    k_attnmerge<<<gs(8 * 10 * 64), 256, 0, stream>>>(c4b, num3, den3, a3_g,
                                                     out, 10, 16, 64, 64, S);
  }
}

// Round 12
// 421.822 us; speedup vs baseline: 2.2991x; 1.1904x over previous
//
#include <hip/hip_runtime.h>
#include <math.h>

// ClassificationBackbone: conv/attn pipeline.
// R12: V pre-permuted into PV-fragment order. vp[b][t][cb][lane][i] with
// (lane=g*16+qi, i) <-> (c=cb*16+qi, m = 32t + 16*(i>>2) + 4g + (i&3)).
// attnN's V load is one coalesced bf16x8 per lane (64 lanes = 1KB contig),
// replacing the 16-line row-gather that stalled R11 at 80%.

#define DEVINL __device__ __forceinline__

using bf16x8 = __attribute__((ext_vector_type(8))) short;  // 8 bf16 (4 VGPRs)
using f32x4 = __attribute__((ext_vector_type(4))) float;   // 4 fp32

DEVINL float selu_f(float x) {
  const float scale = 1.0507009873554805f;
  const float alpha = 1.6732632423543772f;
  return scale * (x > 0.f ? x : alpha * (__expf(x) - 1.f));
}

DEVINL short f2bf(float f) {  // RNE fp32 -> bf16
  unsigned int u = __float_as_uint(f);
  u = (u + 0x7FFFu + ((u >> 16) & 1u)) >> 16;
  return (short)u;
}

// ---------------- prep: h = concat([x^0.25/255^0.25, x], batch) -------------
__global__ __launch_bounds__(256) void k_prep(const float* __restrict__ x,
                                              float* __restrict__ h, int n) {
  const float invScale = 0.250244727f;  // 255^-0.25
  for (int i = blockIdx.x * blockDim.x + threadIdx.x; i < n;
       i += gridDim.x * blockDim.x) {
    float v = x[i];
    h[i] = sqrtf(sqrtf(v)) * invScale;
    h[n + i] = v;
  }
}

// ------------- conv3x3, OCB ocs/block (+bias)(+selu)(+avgpool2) -------------
template <bool POOL, bool DO_SELU, bool DO_BIAS, int OCB>
__global__ __launch_bounds__(256, 4) void k_conv3x3o(
    const float* __restrict__ in, const float* __restrict__ w,
    const float* __restrict__ bias, float* __restrict__ outA,
    float* __restrict__ outB, int splitB, int Bn, int Cin, int Cout, int IH,
    int IW, int tilesX, int tilesY) {
  constexpr int CI_CHUNK = 5;
  constexpr int ROWF = 36;
  __shared__ __align__(16) float lds[CI_CHUNK * 34 * ROWF];
  __shared__ __align__(16) float wlds[OCB * CI_CHUNK * 12];

  const int CH = IH - 2, CW = IW - 2;
  const int OH = POOL ? (CH >> 1) : CH;
  const int OW = POOL ? (CW >> 1) : CW;

  int bid = blockIdx.x;
  const int tX = bid % tilesX; bid /= tilesX;
  const int tY = bid % tilesY; bid /= tilesY;
  const int nOcg = Cout / OCB;
  const int ocg = bid % nOcg;
  const int b = bid / nOcg;
  const int oc0 = ocg * OCB;

  const int tid = threadIdx.x;
  const int ty = tid >> 4, tx = tid & 15;
  const int cy = 2 * ty, cx = 2 * tx;
  const int cy0 = tY * 32, cx0 = tX * 32;
  const long inb = (long)b * Cin * IH * IW;

  const bool live = (cy0 + cy < CH) && (cx0 + cx < CW);

  float acc[OCB][2][2];
#pragma unroll
  for (int o = 0; o < OCB; ++o)
#pragma unroll
    for (int r = 0; r < 2; ++r)
#pragma unroll
      for (int c = 0; c < 2; ++c) acc[o][r][c] = 0.f;

  const int f4 = tid & 15;
  const int gx0 = cx0 + 4 * f4;

  for (int ci0 = 0; ci0 < Cin; ci0 += CI_CHUNK) {
    const int nch = min(CI_CHUNK, Cin - ci0);
    __syncthreads();
    for (int j = tid; j < OCB * CI_CHUNK * 9; j += 256) {
      const int o = j / (CI_CHUNK * 9);
      const int rem = j - o * (CI_CHUNK * 9);
      const int cl = rem / 9;
      const int kk = rem - 9 * cl;
      if (cl < nch)
        wlds[(o * CI_CHUNK + cl) * 12 + kk] =
            w[((long)(oc0 + o) * Cin + ci0 + cl) * 9 + kk];
    }
    for (int ra = tid >> 4; ra < nch * 34; ra += 16) {
      const int cl = ra / 34;
      const int r = ra - 34 * cl;
      if (f4 < 9) {
        const int gy = cy0 + r;
        if (gy < IH) {
          const float* gp = in + inb + ((long)(ci0 + cl) * IH + gy) * IW + gx0;
          float4 v;
          if (gx0 + 3 < IW) {
            v = *(const float4*)gp;
          } else {
            v.x = (gx0 < IW) ? gp[0] : 0.f;
            v.y = (gx0 + 1 < IW) ? gp[1] : 0.f;
            v.z = (gx0 + 2 < IW) ? gp[2] : 0.f;
            v.w = 0.f;
          }
          *(float4*)&lds[(cl * 34 + r) * ROWF + 4 * f4] = v;
        }
      }
    }
    __syncthreads();

    if (live) {
      for (int cl = 0; cl < nch; ++cl) {
        float pr[4][4];
        const float* base = &lds[(cl * 34 + cy) * ROWF + cx];
#pragma unroll
        for (int r = 0; r < 4; ++r) {
          float2 u0 = *(const float2*)(base + r * ROWF);
          float2 u1 = *(const float2*)(base + r * ROWF + 2);
          pr[r][0] = u0.x; pr[r][1] = u0.y; pr[r][2] = u1.x; pr[r][3] = u1.y;
        }
#pragma unroll
        for (int o = 0; o < OCB; ++o) {
          const float* wp = &wlds[(o * CI_CHUNK + cl) * 12];
          const float4 wA = *(const float4*)wp;
          const float4 wB = *(const float4*)(wp + 4);
          const float w8 = wp[8];
          const float wv[9] = {wA.x, wA.y, wA.z, wA.w, wB.x, wB.y, wB.z, wB.w,
                               w8};
#pragma unroll
          for (int ky = 0; ky < 3; ++ky)
#pragma unroll
            for (int kx = 0; kx < 3; ++kx) {
              const float ww = wv[ky * 3 + kx];
#pragma unroll
              for (int r = 0; r < 2; ++r)
#pragma unroll
                for (int c = 0; c < 2; ++c)
                  acc[o][r][c] = fmaf(ww, pr[r + ky][c + kx], acc[o][r][c]);
            }
        }
      }
    }
  }

  if (POOL) {
    const int py = tY * 16 + ty, px = tX * 16 + tx;
    if (py < OH && px < OW) {
#pragma unroll
      for (int o = 0; o < OCB; ++o) {
        const float bb = DO_BIAS ? bias[oc0 + o] : 0.f;
        float s = 0.f;
#pragma unroll
        for (int r = 0; r < 2; ++r)
#pragma unroll
          for (int c = 0; c < 2; ++c) {
            float v = acc[o][r][c] + bb;
            if (DO_SELU) v = selu_f(v);
            s += v;
          }
        const float rv = 0.25f * s;
        const int oc = oc0 + o;
        if (outB != nullptr && b >= splitB)
          outB[(((long)(b - splitB) * Cout + oc) * OH + py) * OW + px] = rv;
        else
          outA[(((long)b * Cout + oc) * OH + py) * OW + px] = rv;
      }
    }
  } else {
#pragma unroll
    for (int o = 0; o < OCB; ++o) {
      const float bb = DO_BIAS ? bias[oc0 + o] : 0.f;
      const int oc = oc0 + o;
#pragma unroll
      for (int r = 0; r < 2; ++r)
#pragma unroll
        for (int c = 0; c < 2; ++c) {
          const int oy = cy0 + cy + r, ox = cx0 + cx + c;
          if (oy < OH && ox < OW) {
            float v = acc[o][r][c] + bb;
            if (DO_SELU) v = selu_f(v);
            float* dst =
                (outB != nullptr && b >= splitB)
                    ? &outB[(((long)(b - splitB) * Cout + oc) * OH + oy) * OW + ox]
                    : &outA[(((long)b * Cout + oc) * OH + oy) * OW + ox];
            *dst = v;
          }
        }
    }
  }
}

// -------- qkv for MFMA attention -------------------------------------------
// qtb,ktb bf16 [Np][8]. V written PRE-PERMUTED into PV-fragment order:
// vp[((b*ntile + t)*CB + cb)*512 + lane*8 + i], lane = g*16 + (c&15),
// t = n>>5, mo = n&31, g = (mo&15)>>2, i = ((mo>>4)<<2) | (mo&3), cb = c>>4.
template <int CB>
__global__ __launch_bounds__(256) void k_qkvA(
    const float* __restrict__ x, const float* __restrict__ wq,
    const float* __restrict__ bq, const float* __restrict__ wk,
    const float* __restrict__ bk, const float* __restrict__ wv,
    const float* __restrict__ bv, unsigned short* __restrict__ qtb,
    unsigned short* __restrict__ ktb, unsigned short* __restrict__ vp,
    int Bn, int C, int D, int N, int Np) {
  constexpr int Cpad = CB * 16;
  const int ntile = Np >> 5;
  const int seg1 = Np * 8;
  const int S = 2 * seg1 + Cpad * Np;
  const int total = Bn * S;
  for (int idx = blockIdx.x * blockDim.x + threadIdx.x; idx < total;
       idx += gridDim.x * blockDim.x) {
    const int b = idx / S;
    const int rr = idx % S;
    const float* xb = x + (long)b * C * N;
    if (rr < 2 * seg1) {
      const bool isq = rr < seg1;
      const int t = isq ? rr : rr - seg1;
      const int n = t >> 3, co = t & 7;
      unsigned short val = 0;
      if (co < D && n < N) {
        const float* w = (isq ? wq : wk) + co * C;
        float a = (isq ? bq : bk)[co];
        for (int ci = 0; ci < C; ++ci) a = fmaf(w[ci], xb[(long)ci * N + n], a);
        val = (unsigned short)f2bf(a);
      }
      (isq ? qtb : ktb)[((long)b * Np + n) * 8 + co] = val;
    } else {
      const int t2 = rr - 2 * seg1;
      const int c = t2 / Np, n = t2 % Np;
      unsigned short v = 0;
      if (c < C && n < N) {
        const float* w = wv + c * C;
        float a = bv[c];
        for (int ci = 0; ci < C; ++ci) a = fmaf(w[ci], xb[(long)ci * N + n], a);
        v = (unsigned short)f2bf(a);
      }
      const int tt = n >> 5, mo = n & 31;
      const int g = (mo & 15) >> 2;
      const int i = ((mo >> 4) << 2) | (mo & 3);
      const int lane = g * 16 + (c & 15);
      const int cb = c >> 4;
      vp[(((long)b * ntile + tt) * CB + cb) * 512 + lane * 8 + i] = v;
    }
  }
}

// ---------------- full-MFMA flash attention + residual ----------------
// Block = (batch, 16-q tile). 256 thr = 4 waves; wave w handles m-tiles
// t = w, w+4, ... (32 m per tile). qi = lane&15, g = lane>>4.
// E-mfma per 16-m subtile (A=K rows, B=Q, k=8 real of 32); exp scalar on
// the 4 E rows each lane owns; P fragment lane-local with map
// (g,i) -> m = 32t + 16*(i>>2) + 4g + (i&3); V A-frag = one coalesced
// bf16x8 per lane from the pre-permuted vp. Softmax w/o max-sub (tiny e).
template <int C, int CB>
__global__ __launch_bounds__(256) void k_attnN(
    const float* __restrict__ x, const unsigned short* __restrict__ qtb,
    const unsigned short* __restrict__ ktb,
    const unsigned short* __restrict__ vp,
    const float* __restrict__ gamma_p, float* __restrict__ out, int N, int Np,
    int nqt) {
  __shared__ float pO[4][CB * 256];
  __shared__ float pD[4][16];

  const int bid = blockIdx.x;
  const int b = bid / nqt;
  const int n0 = (bid % nqt) * 16;
  const int tid = threadIdx.x;
  const int wv_ = tid >> 6;
  const int lane = tid & 63;
  const int g = lane >> 4;
  const int qi = lane & 15;

  const int ntile = Np >> 5;
  const unsigned short* qb_ = qtb + (long)b * Np * 8;
  const unsigned short* kb_ = ktb + (long)b * Np * 8;
  const unsigned short* vb_ = vp + (long)b * ntile * CB * 512 + lane * 8;

  // Q B-fragment: k = 8g+i; real k<8 only for g==0
  bf16x8 qf;
#pragma unroll
  for (int i = 0; i < 8; ++i) qf[i] = 0;
  if (g == 0) qf = *(const bf16x8*)(qb_ + (long)(n0 + qi) * 8);

  f32x4 acc[CB];
#pragma unroll
  for (int cb = 0; cb < CB; ++cb) {
    f32x4 z = {0.f, 0.f, 0.f, 0.f};
    acc[cb] = z;
  }
  float den = 0.f;
  const f32x4 z4 = {0.f, 0.f, 0.f, 0.f};

  for (int t = wv_; t < ntile; t += 4) {
    const int mb = t * 32;
    bf16x8 kf0, kf1;
#pragma unroll
    for (int i = 0; i < 8; ++i) { kf0[i] = 0; kf1[i] = 0; }
    if (g == 0) {
      kf0 = *(const bf16x8*)(kb_ + (long)(mb + qi) * 8);
      kf1 = *(const bf16x8*)(kb_ + (long)(mb + 16 + qi) * 8);
    }
    const f32x4 e0 =
        __builtin_amdgcn_mfma_f32_16x16x32_bf16(kf0, qf, z4, 0, 0, 0);
    const f32x4 e1 =
        __builtin_amdgcn_mfma_f32_16x16x32_bf16(kf1, qf, z4, 0, 0, 0);

    bf16x8 pb;
#pragma unroll
    for (int r = 0; r < 4; ++r) {
      const int ma = mb + 4 * g + r;
      const int mc = ma + 16;
      const float p0 = (ma < N) ? __expf(e0[r]) : 0.f;
      const float p1 = (mc < N) ? __expf(e1[r]) : 0.f;
      den += p0 + p1;
      pb[r] = f2bf(p0);       // i = r   -> m = mb + 4g + r
      pb[4 + r] = f2bf(p1);   // i = 4+r -> m = mb + 16 + 4g + r
    }
    const unsigned short* vt_ = vb_ + (long)t * CB * 512;
#pragma unroll
    for (int cb = 0; cb < CB; ++cb) {
      const bf16x8 va = *(const bf16x8*)(vt_ + cb * 512);
      acc[cb] =
          __builtin_amdgcn_mfma_f32_16x16x32_bf16(va, pb, acc[cb], 0, 0, 0);
    }
  }

  den += __shfl_xor(den, 16, 64);
  den += __shfl_xor(den, 32, 64);

#pragma unroll
  for (int cb = 0; cb < CB; ++cb)
#pragma unroll
    for (int r = 0; r < 4; ++r)
      pO[wv_][cb * 256 + (4 * g + r) * 16 + qi] = acc[cb][r];
  if (g == 0) pD[wv_][qi] = den;
  __syncthreads();

  const float gma = gamma_p[0];
#pragma unroll
  for (int cb = 0; cb < CB; ++cb) {
    const int cell = cb * 256 + tid;
    const int c = cb * 16 + (tid >> 4);
    const int q = tid & 15;
    const int n = n0 + q;
    if (c < C && n < N) {
      const float s = pO[0][cell] + pO[1][cell] + pO[2][cell] + pO[3][cell];
      const float Dn = pD[0][q] + pD[1][q] + pD[2][q] + pD[3][q];
      const long o = ((long)b * C + c) * N + n;
      out[o] = fmaf(gma, s / Dn, x[o]);
    }
  }
}

// ---------------- q/k/v projections (attn3 small path) ----------------
template <int Cp>
__global__ __launch_bounds__(256) void k_qkv3(
    const float* __restrict__ x, const float* __restrict__ wq,
    const float* __restrict__ bq, const float* __restrict__ wk,
    const float* __restrict__ bk, const float* __restrict__ wv,
    const float* __restrict__ bv, float* __restrict__ qt,
    float* __restrict__ kt, float* __restrict__ vt, int Bn, int C, int D,
    int N, int Np) {
  constexpr int KP = 8;
  const int S = Np * (2 * KP + Cp);
  const int total = Bn * S;
  for (int idx = blockIdx.x * blockDim.x + threadIdx.x; idx < total;
       idx += gridDim.x * blockDim.x) {
    const int b = idx / S;
    const int rr = idx % S;
    const float* xb = x + (long)b * C * N;
    const float* w = nullptr;
    const float* bp = nullptr;
    float* dst;
    int n, co, lim;
    if (rr < Np * KP) {
      n = rr / KP; co = rr % KP; lim = D;
      w = wq + co * C; bp = bq;
      dst = qt + ((long)b * Np + n) * KP + co;
    } else if (rr < 2 * Np * KP) {
      const int t = rr - Np * KP;
      n = t / KP; co = t % KP; lim = D;
      w = wk + co * C; bp = bk;
      dst = kt + ((long)b * Np + n) * KP + co;
    } else {
      const int t = rr - 2 * Np * KP;
      n = t / Cp; co = t % Cp; lim = C;
      w = wv + co * C; bp = bv;
      dst = vt + ((long)b * Np + n) * Cp + co;
    }
    if (co < lim && n < N) {
      float a = bp[co];
      for (int ci = 0; ci < C; ++ci) a = fmaf(w[ci], xb[(long)ci * N + n], a);
      *dst = a;
    } else {
      *dst = 0.f;
    }
  }
}

// ---------------- flash attention partials (attn3 small path) ---------------
template <int C, int Chp>
__global__ __launch_bounds__(128) void k_attn7(
    const float* __restrict__ qt, const float* __restrict__ kt,
    const float* __restrict__ vt, float* __restrict__ num,
    float* __restrict__ den, int N, int nbr, int S, int msz, int Np, int Nr) {
  constexpr int KP = 8;
  constexpr int Cp = 2 * Chp;
  constexpr int NV = Chp / 4;
  int bid = blockIdx.x;
  const int s = bid % S; bid /= S;
  const int rb = bid % nbr;
  const int b = bid / nbr;
  const int brow = rb * 32;
  const int tid = threadIdx.x;
  const int lane = tid & 63;
  const int cg = tid >> 6;
  const int g = lane >> 4;
  const int r = lane & 15;

  const float* qb = qt + (long)b * Np * KP;
  const float* kb = kt + (long)b * Np * KP;
  const float* vb = vt + (long)b * Np * Cp;

  float4 q0[2];
  float2 q1[2];
#pragma unroll
  for (int k = 0; k < 2; ++k) {
    const int n = brow + r + 16 * k;
    q0[k] = *(const float4*)(qb + (long)n * KP);
    q1[k] = *(const float2*)(qb + (long)n * KP + 4);
  }

  float acc[2][Chp];
#pragma unroll
  for (int k = 0; k < 2; ++k)
#pragma unroll
    for (int c = 0; c < Chp; ++c) acc[k][c] = 0.f;
  float sm[2] = {0.f, 0.f};

  const int mstart = s * msz;
  const int mlimit = min(mstart + msz, N);
  for (int m0 = mstart; m0 < mlimit; m0 += 4) {
    const int m = m0 + g;
    const float4 ka = *(const float4*)(kb + (long)m * KP);
    const float2 kc = *(const float2*)(kb + (long)m * KP + 4);
    float4 vv[NV];
    const float4* vpp = (const float4*)(vb + (long)m * Cp + cg * Chp);
#pragma unroll
    for (int j = 0; j < NV; ++j) vv[j] = vpp[j];
#pragma unroll
    for (int k = 0; k < 2; ++k) {
      float e = q0[k].x * ka.x;
      e = fmaf(q0[k].y, ka.y, e);
      e = fmaf(q0[k].z, ka.z, e);
      e = fmaf(q0[k].w, ka.w, e);
      e = fmaf(q1[k].x, kc.x, e);
      e = fmaf(q1[k].y, kc.y, e);
      const float p = __expf(e);
      sm[k] += p;
#pragma unroll
      for (int j = 0; j < NV; ++j) {
        acc[k][4 * j + 0] = fmaf(p, vv[j].x, acc[k][4 * j + 0]);
        acc[k][4 * j + 1] = fmaf(p, vv[j].y, acc[k][4 * j + 1]);
        acc[k][4 * j + 2] = fmaf(p, vv[j].z, acc[k][4 * j + 2]);
        acc[k][4 * j + 3] = fmaf(p, vv[j].w, acc[k][4 * j + 3]);
      }
    }
  }

#pragma unroll
  for (int k = 0; k < 2; ++k) {
    sm[k] += __shfl_xor(sm[k], 16, 64);
    sm[k] += __shfl_xor(sm[k], 32, 64);
#pragma unroll
    for (int c = 0; c < Chp; ++c) {
      acc[k][c] += __shfl_xor(acc[k][c], 16, 64);
      acc[k][c] += __shfl_xor(acc[k][c], 32, 64);
    }
  }

  if (g == 0) {
    float* np_ = num + ((long)(s * 8 + b) * Cp + cg * Chp) * Nr;
    float* dp_ = den + (long)(s * 8 + b) * Nr;
#pragma unroll
    for (int k = 0; k < 2; ++k) {
      const int n = brow + r + 16 * k;
      if (n < N) {
#pragma unroll
        for (int c = 0; c < Chp; ++c) np_[(long)c * Nr + n] = acc[k][c];
        if (cg == 0) dp_[n] = sm[k];
      }
    }
  }
}

// ---------------- attention merge (attn3 small path) ----------------
__global__ __launch_bounds__(256) void k_attnmerge(
    const float* __restrict__ x, const float* __restrict__ num,
    const float* __restrict__ den, const float* __restrict__ gamma_p,
    float* __restrict__ out, int C, int Cp, int N, int Nr, int S) {
  const float g = gamma_p[0];
  const int total = 8 * C * N;
  for (int idx = blockIdx.x * blockDim.x + threadIdx.x; idx < total;
       idx += gridDim.x * blockDim.x) {
    const int n = idx % N;
    const int t = idx / N;
    const int c = t % C;
    const int b = t / C;
    float a = 0.f, d = 0.f;
    for (int s = 0; s < S; ++s) {
      a += num[((long)(s * 8 + b) * Cp + c) * Nr + n];
      d += den[(long)(s * 8 + b) * Nr + n];
    }
    out[((long)b * C + c) * N + n] =
        fmaf(g, a / d, x[((long)b * C + c) * N + n]);
  }
}

// ---------------- batchnorm stats: mean + rsqrt(var+eps) per channel --------
__global__ __launch_bounds__(256) void k_bnstats(const float* __restrict__ x,
                                                 float* __restrict__ stats,
                                                 int Bn, int C, int HW,
                                                 float eps) {
  int c = blockIdx.x;
  int tid = threadIdx.x;
  int cnt = Bn * HW;
  float s = 0.f, s2 = 0.f;
  for (int i = tid; i < cnt; i += blockDim.x) {
    int b = i / HW, r = i % HW;
    float v = x[((long)b * C + c) * HW + r];
    s += v;
    s2 += v * v;
  }
#pragma unroll
  for (int off = 32; off > 0; off >>= 1) {
    s += __shfl_down(s, off);
    s2 += __shfl_down(s2, off);
  }
  __shared__ float as_[4], as2_[4];
  int wid = tid >> 6;
  if ((tid & 63) == 0) { as_[wid] = s; as2_[wid] = s2; }
  __syncthreads();
  if (tid == 0) {
    float S = 0.f, S2 = 0.f;
#pragma unroll
    for (int ww = 0; ww < 4; ++ww) { S += as_[ww]; S2 += as2_[ww]; }
    float mean = S / (float)cnt;
    float var = S2 / (float)cnt - mean * mean;
    stats[c] = mean;
    stats[C + c] = rsqrtf(var + eps);
  }
}

// ---------------- BN apply + selu (+pool) ----------------
template <bool POOL>
__global__ __launch_bounds__(256) void k_bn_selu(
    const float* __restrict__ x, const float* __restrict__ stats,
    const float* __restrict__ g, const float* __restrict__ beta,
    float* __restrict__ out, int Bn, int C, int IH, int IW) {
  int OH = POOL ? (IH >> 1) : IH;
  int OW = POOL ? (IW >> 1) : IW;
  int total = Bn * C * OH * OW;
  for (int idx = blockIdx.x * blockDim.x + threadIdx.x; idx < total;
       idx += gridDim.x * blockDim.x) {
    int px = idx % OW;
    int t = idx / OW;
    int py = t % OH;
    t /= OH;
    int c = t % C;
    int b = t / C;
    float mean = stats[c], istd = stats[C + c];
    float gg = g[c], bb = beta[c];
    const float* ip = x + ((long)b * C + c) * IH * IW;
    float r;
    if (POOL) {
      int iy = py * 2, ix = px * 2;
      float v00 = selu_f((ip[iy * IW + ix] - mean) * istd * gg + bb);
      float v01 = selu_f((ip[iy * IW + ix + 1] - mean) * istd * gg + bb);
      float v10 = selu_f((ip[(iy + 1) * IW + ix] - mean) * istd * gg + bb);
      float v11 = selu_f((ip[(iy + 1) * IW + ix + 1] - mean) * istd * gg + bb);
      r = 0.25f * (v00 + v01 + v10 + v11);
    } else {
      r = selu_f((ip[py * IW + px] - mean) * istd * gg + bb);
    }
    out[((b * C + c) * OH + py) * OW + px] = r;
  }
}

static inline int gs(int total) { return (total + 255) / 256; }
static inline int cdiv(int a, int b) { return (a + b - 1) / b; }

extern "C" void kernel_launch(void* const* d_in, const int* in_sizes, int n_in,
                              void* d_out, int out_size, void* d_ws,
                              size_t ws_size, hipStream_t stream) {
  const float* x      = (const float*)d_in[0];
  const float* enc_w1 = (const float*)d_in[1];
  const float* enc_b1 = (const float*)d_in[2];
  const float* enc_w2 = (const float*)d_in[3];
  const float* enc_b2 = (const float*)d_in[4];
  const float* a1_wq  = (const float*)d_in[5];
  const float* a1_bq  = (const float*)d_in[6];
  const float* a1_wk  = (const float*)d_in[7];
  const float* a1_bk  = (const float*)d_in[8];
  const float* a1_wv  = (const float*)d_in[9];
  const float* a1_bv  = (const float*)d_in[10];
  const float* a1_g   = (const float*)d_in[11];
  const float* c1_w   = (const float*)d_in[12];
  const float* c1_b   = (const float*)d_in[13];
  const float* a2_wq  = (const float*)d_in[14];
  const float* a2_bq  = (const float*)d_in[15];
  const float* a2_wk  = (const float*)d_in[16];
  const float* a2_bk  = (const float*)d_in[17];
  const float* a2_wv  = (const float*)d_in[18];
  const float* a2_bv  = (const float*)d_in[19];
  const float* a2_g   = (const float*)d_in[20];
  const float* c2_w   = (const float*)d_in[21];
  const float* c2_b   = (const float*)d_in[22];
  const float* c3_w   = (const float*)d_in[23];
  const float* c3_g   = (const float*)d_in[24];
  const float* c3_be  = (const float*)d_in[25];
  const float* c4_w   = (const float*)d_in[26];
  const float* c4_g   = (const float*)d_in[27];
  const float* c4_be  = (const float*)d_in[28];
  const float* a3_wq  = (const float*)d_in[29];
  const float* a3_bq  = (const float*)d_in[30];
  const float* a3_wk  = (const float*)d_in[31];
  const float* a3_bk  = (const float*)d_in[32];
  const float* a3_wv  = (const float*)d_in[33];
  const float* a3_bv  = (const float*)d_in[34];
  const float* a3_g   = (const float*)d_in[35];

  float* out = (float*)d_out;
  float* W = (float*)d_ws;

  // ---- workspace plan (float slots; peak 5,056,320 = 20.2 MB, proven) ----
  float* h    = W;                         // [0, 1,920,000)
  float* h1   = W + 1920000;               // [1,920,000, 5,056,320)
  float* h2   = W;                         // [0, 737,280)
  float* xenc = out + 5120;                // (8,40,48,48) direct

  // attn1: Np1=2304, CB=3 (vp bf16 = Np*48 per batch)
  unsigned short* qtb1 = (unsigned short*)(W + 737280);   // 147,456 bf16
  unsigned short* ktb1 = (unsigned short*)(W + 884736);   // 147,456 bf16
  unsigned short* vtb1 = (unsigned short*)(W + 1032192);  // 884,736 bf16
  float* at1 = W + 1474560;                // 737,280 -> ends 2,211,840
  float* c1o = W + 2211840;                // 846,400 -> ends 3,058,240

  // attn2: Np2=2144, CB=4 (vp bf16 = Np*64 per batch)
  unsigned short* qtb2 = (unsigned short*)(W + 3058240);  // 137,216 bf16
  unsigned short* ktb2 = (unsigned short*)(W + 3195456);  // 137,216 bf16
  unsigned short* vtb2 = (unsigned short*)(W + 3332672);  // 1,097,728 bf16
  float* at2 = W + 3881536;                // 846,400 -> ends 4,727,936

  float* c2o  = W;                         // 154,880
  float* c3o  = W + 200000;                // 96,000
  float* st3  = W + 300000;                // 60
  float* c3p  = W + 310000;                // 24,000
  float* c4o  = W + 340000;                // 5,120
  float* st4  = W + 350000;                // 20
  float* c4b  = W + 360000;                // 5,120
  float* q3   = W + 370000;                // 8,192
  float* k3   = W + 380000;                // 8,192
  float* v3   = W + 390000;                // 16,384
  float* num3 = W + 410000;                // 8,192
  float* den3 = W + 420000;                // 512

  const int NOSPLIT = 1 << 30;

  // 1. prep
  {
    int n = 8 * 3 * 200 * 200;
    k_prep<<<gs(n), 256, 0, stream>>>(x, h, n);
  }
  // 2. enc conv1 + selu + pool : (16,3,200,200)->(16,20,99,99), OCB=5
  {
    int tXY = cdiv(99, 16);  // 7
    int blocks = 16 * (20 / 5) * tXY * tXY;  // 3136
    k_conv3x3o<true, true, true, 5><<<blocks, 256, 0, stream>>>(
        h, enc_w1, enc_b1, h1, nullptr, NOSPLIT, 16, 3, 20, 200, 200, tXY,
        tXY);
  }
  // 3. enc conv2 + selu + pool : (16,20,99,99)->(16,40,48,48), OCB=5
  {
    int tXY = cdiv(48, 16);  // 3
    int blocks = 16 * (40 / 5) * tXY * tXY;  // 1152
    k_conv3x3o<true, true, true, 5><<<blocks, 256, 0, stream>>>(
        h1, enc_w2, enc_b2, h2, xenc, 8, 16, 20, 40, 99, 99, tXY, tXY);
  }
  // 4. attn1 qkv : CB=3, Np=2304
  {
    int total = 8 * 2304 * (16 + 48);
    k_qkvA<3><<<gs(total), 256, 0, stream>>>(h2, a1_wq, a1_bq, a1_wk, a1_bk,
                                             a1_wv, a1_bv, qtb1, ktb1, vtb1,
                                             8, 40, 5, 2304, 2304);
  }
  // 5. attn1 (full MFMA, coalesced V) : C=40, CB=3, nqt=144
  {
    k_attnN<40, 3><<<8 * 144, 256, 0, stream>>>(h2, qtb1, ktb1, vtb1, a1_g,
                                                at1, 2304, 2304, 144);
  }
  // 6. c1 conv + selu : (8,40,48,48)->(8,50,46,46), OCB=2
  {
    int tXY = cdiv(46, 32);  // 2
    int blocks = 8 * (50 / 2) * tXY * tXY;  // 800
    k_conv3x3o<false, true, true, 2><<<blocks, 256, 0, stream>>>(
        at1, c1_w, c1_b, c1o, nullptr, NOSPLIT, 8, 40, 50, 48, 48, tXY, tXY);
  }
  // 7. attn2 qkv : CB=4, Np=2144
  {
    int total = 8 * 2144 * (16 + 64);
    k_qkvA<4><<<gs(total), 256, 0, stream>>>(c1o, a2_wq, a2_bq, a2_wk, a2_bk,
                                             a2_wv, a2_bv, qtb2, ktb2, vtb2,
                                             8, 50, 6, 2116, 2144);
  }
  // 8. attn2 (full MFMA, coalesced V) : C=50, CB=4, nqt=133
  {
    k_attnN<50, 4><<<8 * 133, 256, 0, stream>>>(c1o, qtb2, ktb2, vtb2, a2_g,
                                                at2, 2116, 2144, 133);
  }
  // 9. c2 conv + selu + pool : (8,50,46,46)->(8,40,22,22), OCB=2
  {
    int tXY = cdiv(22, 16);  // 2
    int blocks = 8 * (40 / 2) * tXY * tXY;  // 640
    k_conv3x3o<true, true, true, 2><<<blocks, 256, 0, stream>>>(
        at2, c2_w, c2_b, c2o, nullptr, NOSPLIT, 8, 50, 40, 46, 46, tXY, tXY);
  }
  // 10. c3 conv : (8,40,22,22)->(8,30,20,20), OCB=2
  {
    int tXY = cdiv(20, 32);  // 1
    int blocks = 8 * (30 / 2) * tXY * tXY;  // 120
    k_conv3x3o<false, false, false, 2><<<blocks, 256, 0, stream>>>(
        c2o, c3_w, nullptr, c3o, nullptr, NOSPLIT, 8, 40, 30, 22, 22, tXY,
        tXY);
  }
  // 11-12. BN(c3) + selu + pool -> (8,30,10,10)
  k_bnstats<<<30, 256, 0, stream>>>(c3o, st3, 8, 30, 400, 1e-5f);
  {
    int total = 8 * 30 * 10 * 10;
    k_bn_selu<true><<<gs(total), 256, 0, stream>>>(c3o, st3, c3_g, c3_be, c3p,
                                                   8, 30, 20, 20);
  }
  // 13. c4 conv : (8,30,10,10)->(8,10,8,8), OCB=2
  {
    int tXY = cdiv(8, 32);  // 1
    int blocks = 8 * (10 / 2) * tXY * tXY;  // 40
    k_conv3x3o<false, false, false, 2><<<blocks, 256, 0, stream>>>(
        c3p, c4_w, nullptr, c4o, nullptr, NOSPLIT, 8, 30, 10, 10, 10, tXY,
        tXY);
  }
  // 14-15. BN(c4) + selu
  k_bnstats<<<10, 256, 0, stream>>>(c4o, st4, 8, 10, 64, 1e-5f);
  {
    int total = 8 * 10 * 8 * 8;
    k_bn_selu<false><<<gs(total), 256, 0, stream>>>(c4o, st4, c4_g, c4_be, c4b,
                                                    8, 10, 8, 8);
  }
  // 16. attn3 qkv : Cp=16, Np=128
  {
    int total = 8 * 128 * (16 + 16);
    k_qkv3<16><<<gs(total), 256, 0, stream>>>(c4b, a3_wq, a3_bq, a3_wk, a3_bk,
                                              a3_wv, a3_bv, q3, k3, v3, 8, 10,
                                              1, 64, 128);
  }
  // 17. attn3 partials + merge -> out[0..5120)
  {
    int nbr = 2, S = 1, msz = 64;
    k_attn7<10, 8><<<8 * nbr * S, 128, 0, stream>>>(q3, k3, v3, num3, den3, 64,
                                                    nbr, S, msz, 128, 64);
    k_attnmerge<<<gs(8 * 10 * 64), 256, 0, stream>>>(c4b, num3, den3, a3_g,
                                                     out, 10, 16, 64, 64, S);
  }
}

// Round 13
// 390.338 us; speedup vs baseline: 2.4845x; 1.0807x over previous
//
#include <hip/hip_runtime.h>
#include <math.h>

// ClassificationBackbone: conv/attn pipeline.
// R13: direct (no-LDS) conv for the two encoder convs — thread = 2x2 quad x
// OCB ocs, per-ci 8 float2 patch loads straight from global (L1-shared),
// weights via wave-uniform s_load. No barriers. c1..c4 keep LDS conv.
// MFMA attention with pre-permuted V (R12) unchanged.

#define DEVINL __device__ __forceinline__

using bf16x8 = __attribute__((ext_vector_type(8))) short;  // 8 bf16 (4 VGPRs)
using f32x4 = __attribute__((ext_vector_type(4))) float;   // 4 fp32

DEVINL float selu_f(float x) {
  const float scale = 1.0507009873554805f;
  const float alpha = 1.6732632423543772f;
  return scale * (x > 0.f ? x : alpha * (__expf(x) - 1.f));
}

DEVINL short f2bf(float f) {  // RNE fp32 -> bf16
  unsigned int u = __float_as_uint(f);
  u = (u + 0x7FFFu + ((u >> 16) & 1u)) >> 16;
  return (short)u;
}

// ---------------- prep: h = concat([x^0.25/255^0.25, x], batch) -------------
__global__ __launch_bounds__(256) void k_prep(const float* __restrict__ x,
                                              float* __restrict__ h, int n) {
  const float invScale = 0.250244727f;  // 255^-0.25
  for (int i = blockIdx.x * blockDim.x + threadIdx.x; i < n;
       i += gridDim.x * blockDim.x) {
    float v = x[i];
    h[i] = sqrtf(sqrtf(v)) * invScale;
    h[n + i] = v;
  }
}

// ---------- direct conv3x3 (no LDS): 2x2 quad x OCB ocs per thread ----------
// blockIdx = (b, ocg, quad-tile); 256 quads per block, consecutive in (qy,qx)
// row-major -> coalesced loads/stores. Weights wave-uniform -> s_load.
// POOL: quad -> 1 pooled output/oc. NOPOOL: 4 outputs/oc (CH,CW even).
// Patch loads always in-bounds: 2*q+3 <= IW-1 for all shapes used.
template <bool POOL, bool DO_SELU, bool DO_BIAS, int OCB>
__global__ __launch_bounds__(256) void k_conv3x3d(
    const float* __restrict__ in, const float* __restrict__ w,
    const float* __restrict__ bias, float* __restrict__ outA,
    float* __restrict__ outB, int splitB, int Bn, int Cin, int Cout, int IH,
    int IW, int nQB) {
  const int CH = IH - 2, CW = IW - 2;
  const int OH = POOL ? (CH >> 1) : CH;
  const int OW = POOL ? (CW >> 1) : CW;
  const int QY = POOL ? OH : (CH >> 1);
  const int QX = POOL ? OW : (CW >> 1);
  const int nQ = QY * QX;
  const int nOcg = Cout / OCB;

  int bid = blockIdx.x;
  const int qblk = bid % nQB; bid /= nQB;
  const int ocg = bid % nOcg;
  const int b = bid / nOcg;
  const int oc0 = ocg * OCB;

  const int q = qblk * 256 + threadIdx.x;
  if (q >= nQ) return;
  const int qx = q % QX;
  const int qy = q / QX;
  const int iy = 2 * qy, ix = 2 * qx;

  const float* ib = in + ((long)b * Cin * IH + iy) * IW + ix;

  float acc[OCB][2][2];
#pragma unroll
  for (int o = 0; o < OCB; ++o)
#pragma unroll
    for (int r = 0; r < 2; ++r)
#pragma unroll
      for (int c = 0; c < 2; ++c) acc[o][r][c] = 0.f;

  for (int ci = 0; ci < Cin; ++ci) {
    // 4x4 patch via 8 float2 loads (8B aligned: ix even)
    float pr[4][4];
    const float* p = ib + (long)ci * IH * IW;
#pragma unroll
    for (int r = 0; r < 4; ++r) {
      const float2 u0 = *(const float2*)(p + (long)r * IW);
      const float2 u1 = *(const float2*)(p + (long)r * IW + 2);
      pr[r][0] = u0.x; pr[r][1] = u0.y; pr[r][2] = u1.x; pr[r][3] = u1.y;
    }
    const float* wc = w + ((long)oc0 * Cin + ci) * 9;  // wave-uniform
#pragma unroll
    for (int o = 0; o < OCB; ++o) {
      const float* wp = wc + (long)o * Cin * 9;
#pragma unroll
      for (int ky = 0; ky < 3; ++ky)
#pragma unroll
        for (int kx = 0; kx < 3; ++kx) {
          const float ww = wp[ky * 3 + kx];
#pragma unroll
          for (int r = 0; r < 2; ++r)
#pragma unroll
            for (int c = 0; c < 2; ++c)
              acc[o][r][c] = fmaf(ww, pr[r + ky][c + kx], acc[o][r][c]);
        }
    }
  }

  if (POOL) {
#pragma unroll
    for (int o = 0; o < OCB; ++o) {
      const float bb = DO_BIAS ? bias[oc0 + o] : 0.f;
      float s = 0.f;
#pragma unroll
      for (int r = 0; r < 2; ++r)
#pragma unroll
        for (int c = 0; c < 2; ++c) {
          float v = acc[o][r][c] + bb;
          if (DO_SELU) v = selu_f(v);
          s += v;
        }
      const float rv = 0.25f * s;
      const int oc = oc0 + o;
      if (outB != nullptr && b >= splitB)
        outB[(((long)(b - splitB) * Cout + oc) * OH + qy) * OW + qx] = rv;
      else
        outA[(((long)b * Cout + oc) * OH + qy) * OW + qx] = rv;
    }
  } else {
#pragma unroll
    for (int o = 0; o < OCB; ++o) {
      const float bb = DO_BIAS ? bias[oc0 + o] : 0.f;
      const int oc = oc0 + o;
#pragma unroll
      for (int r = 0; r < 2; ++r)
#pragma unroll
        for (int c = 0; c < 2; ++c) {
          const int oy = iy + r, ox = ix + c;
          float v = acc[o][r][c] + bb;
          if (DO_SELU) v = selu_f(v);
          float* dst =
              (outB != nullptr && b >= splitB)
                  ? &outB[(((long)(b - splitB) * Cout + oc) * OH + oy) * OW + ox]
                  : &outA[(((long)b * Cout + oc) * OH + oy) * OW + ox];
          *dst = v;
        }
    }
  }
}

// ------------- LDS conv3x3, OCB ocs/block (c1/c2/c3/c4 path) ----------------
template <bool POOL, bool DO_SELU, bool DO_BIAS, int OCB>
__global__ __launch_bounds__(256, 4) void k_conv3x3o(
    const float* __restrict__ in, const float* __restrict__ w,
    const float* __restrict__ bias, float* __restrict__ outA,
    float* __restrict__ outB, int splitB, int Bn, int Cin, int Cout, int IH,
    int IW, int tilesX, int tilesY) {
  constexpr int CI_CHUNK = 5;
  constexpr int ROWF = 36;
  __shared__ __align__(16) float lds[CI_CHUNK * 34 * ROWF];
  __shared__ __align__(16) float wlds[OCB * CI_CHUNK * 12];

  const int CH = IH - 2, CW = IW - 2;
  const int OH = POOL ? (CH >> 1) : CH;
  const int OW = POOL ? (CW >> 1) : CW;

  int bid = blockIdx.x;
  const int tX = bid % tilesX; bid /= tilesX;
  const int tY = bid % tilesY; bid /= tilesY;
  const int nOcg = Cout / OCB;
  const int ocg = bid % nOcg;
  const int b = bid / nOcg;
  const int oc0 = ocg * OCB;

  const int tid = threadIdx.x;
  const int ty = tid >> 4, tx = tid & 15;
  const int cy = 2 * ty, cx = 2 * tx;
  const int cy0 = tY * 32, cx0 = tX * 32;
  const long inb = (long)b * Cin * IH * IW;

  const bool live = (cy0 + cy < CH) && (cx0 + cx < CW);

  float acc[OCB][2][2];
#pragma unroll
  for (int o = 0; o < OCB; ++o)
#pragma unroll
    for (int r = 0; r < 2; ++r)
#pragma unroll
      for (int c = 0; c < 2; ++c) acc[o][r][c] = 0.f;

  const int f4 = tid & 15;
  const int gx0 = cx0 + 4 * f4;

  for (int ci0 = 0; ci0 < Cin; ci0 += CI_CHUNK) {
    const int nch = min(CI_CHUNK, Cin - ci0);
    __syncthreads();
    for (int j = tid; j < OCB * CI_CHUNK * 9; j += 256) {
      const int o = j / (CI_CHUNK * 9);
      const int rem = j - o * (CI_CHUNK * 9);
      const int cl = rem / 9;
      const int kk = rem - 9 * cl;
      if (cl < nch)
        wlds[(o * CI_CHUNK + cl) * 12 + kk] =
            w[((long)(oc0 + o) * Cin + ci0 + cl) * 9 + kk];
    }
    for (int ra = tid >> 4; ra < nch * 34; ra += 16) {
      const int cl = ra / 34;
      const int r = ra - 34 * cl;
      if (f4 < 9) {
        const int gy = cy0 + r;
        if (gy < IH) {
          const float* gp = in + inb + ((long)(ci0 + cl) * IH + gy) * IW + gx0;
          float4 v;
          if (gx0 + 3 < IW) {
            v = *(const float4*)gp;
          } else {
            v.x = (gx0 < IW) ? gp[0] : 0.f;
            v.y = (gx0 + 1 < IW) ? gp[1] : 0.f;
            v.z = (gx0 + 2 < IW) ? gp[2] : 0.f;
            v.w = 0.f;
          }
          *(float4*)&lds[(cl * 34 + r) * ROWF + 4 * f4] = v;
        }
      }
    }
    __syncthreads();

    if (live) {
      for (int cl = 0; cl < nch; ++cl) {
        float pr[4][4];
        const float* base = &lds[(cl * 34 + cy) * ROWF + cx];
#pragma unroll
        for (int r = 0; r < 4; ++r) {
          float2 u0 = *(const float2*)(base + r * ROWF);
          float2 u1 = *(const float2*)(base + r * ROWF + 2);
          pr[r][0] = u0.x; pr[r][1] = u0.y; pr[r][2] = u1.x; pr[r][3] = u1.y;
        }
#pragma unroll
        for (int o = 0; o < OCB; ++o) {
          const float* wp = &wlds[(o * CI_CHUNK + cl) * 12];
          const float4 wA = *(const float4*)wp;
          const float4 wB = *(const float4*)(wp + 4);
          const float w8 = wp[8];
          const float wv[9] = {wA.x, wA.y, wA.z, wA.w, wB.x, wB.y, wB.z, wB.w,
                               w8};
#pragma unroll
          for (int ky = 0; ky < 3; ++ky)
#pragma unroll
            for (int kx = 0; kx < 3; ++kx) {
              const float ww = wv[ky * 3 + kx];
#pragma unroll
              for (int r = 0; r < 2; ++r)
#pragma unroll
                for (int c = 0; c < 2; ++c)
                  acc[o][r][c] = fmaf(ww, pr[r + ky][c + kx], acc[o][r][c]);
            }
        }
      }
    }
  }

  if (POOL) {
    const int py = tY * 16 + ty, px = tX * 16 + tx;
    if (py < OH && px < OW) {
#pragma unroll
      for (int o = 0; o < OCB; ++o) {
        const float bb = DO_BIAS ? bias[oc0 + o] : 0.f;
        float s = 0.f;
#pragma unroll
        for (int r = 0; r < 2; ++r)
#pragma unroll
          for (int c = 0; c < 2; ++c) {
            float v = acc[o][r][c] + bb;
            if (DO_SELU) v = selu_f(v);
            s += v;
          }
        const float rv = 0.25f * s;
        const int oc = oc0 + o;
        if (outB != nullptr && b >= splitB)
          outB[(((long)(b - splitB) * Cout + oc) * OH + py) * OW + px] = rv;
        else
          outA[(((long)b * Cout + oc) * OH + py) * OW + px] = rv;
      }
    }
  } else {
#pragma unroll
    for (int o = 0; o < OCB; ++o) {
      const float bb = DO_BIAS ? bias[oc0 + o] : 0.f;
      const int oc = oc0 + o;
#pragma unroll
      for (int r = 0; r < 2; ++r)
#pragma unroll
        for (int c = 0; c < 2; ++c) {
          const int oy = cy0 + cy + r, ox = cx0 + cx + c;
          if (oy < OH && ox < OW) {
            float v = acc[o][r][c] + bb;
            if (DO_SELU) v = selu_f(v);
            float* dst =
                (outB != nullptr && b >= splitB)
                    ? &outB[(((long)(b - splitB) * Cout + oc) * OH + oy) * OW + ox]
                    : &outA[(((long)b * Cout + oc) * OH + oy) * OW + ox];
            *dst = v;
          }
        }
    }
  }
}

// -------- qkv for MFMA attention -------------------------------------------
// qtb,ktb bf16 [Np][8]. V written PRE-PERMUTED into PV-fragment order:
// vp[((b*ntile + t)*CB + cb)*512 + lane*8 + i], lane = g*16 + (c&15),
// t = n>>5, mo = n&31, g = (mo&15)>>2, i = ((mo>>4)<<2) | (mo&3), cb = c>>4.
template <int CB>
__global__ __launch_bounds__(256) void k_qkvA(
    const float* __restrict__ x, const float* __restrict__ wq,
    const float* __restrict__ bq, const float* __restrict__ wk,
    const float* __restrict__ bk, const float* __restrict__ wv,
    const float* __restrict__ bv, unsigned short* __restrict__ qtb,
    unsigned short* __restrict__ ktb, unsigned short* __restrict__ vp,
    int Bn, int C, int D, int N, int Np) {
  constexpr int Cpad = CB * 16;
  const int ntile = Np >> 5;
  const int seg1 = Np * 8;
  const int S = 2 * seg1 + Cpad * Np;
  const int total = Bn * S;
  for (int idx = blockIdx.x * blockDim.x + threadIdx.x; idx < total;
       idx += gridDim.x * blockDim.x) {
    const int b = idx / S;
    const int rr = idx % S;
    const float* xb = x + (long)b * C * N;
    if (rr < 2 * seg1) {
      const bool isq = rr < seg1;
      const int t = isq ? rr : rr - seg1;
      const int n = t >> 3, co = t & 7;
      unsigned short val = 0;
      if (co < D && n < N) {
        const float* w = (isq ? wq : wk) + co * C;
        float a = (isq ? bq : bk)[co];
        for (int ci = 0; ci < C; ++ci) a = fmaf(w[ci], xb[(long)ci * N + n], a);
        val = (unsigned short)f2bf(a);
      }
      (isq ? qtb : ktb)[((long)b * Np + n) * 8 + co] = val;
    } else {
      const int t2 = rr - 2 * seg1;
      const int c = t2 / Np, n = t2 % Np;
      unsigned short v = 0;
      if (c < C && n < N) {
        const float* w = wv + c * C;
        float a = bv[c];
        for (int ci = 0; ci < C; ++ci) a = fmaf(w[ci], xb[(long)ci * N + n], a);
        v = (unsigned short)f2bf(a);
      }
      const int tt = n >> 5, mo = n & 31;
      const int g = (mo & 15) >> 2;
      const int i = ((mo >> 4) << 2) | (mo & 3);
      const int lane = g * 16 + (c & 15);
      const int cb = c >> 4;
      vp[(((long)b * ntile + tt) * CB + cb) * 512 + lane * 8 + i] = v;
    }
  }
}

// ---------------- full-MFMA flash attention + residual ----------------
template <int C, int CB>
__global__ __launch_bounds__(256) void k_attnN(
    const float* __restrict__ x, const unsigned short* __restrict__ qtb,
    const unsigned short* __restrict__ ktb,
    const unsigned short* __restrict__ vp,
    const float* __restrict__ gamma_p, float* __restrict__ out, int N, int Np,
    int nqt) {
  __shared__ float pO[4][CB * 256];
  __shared__ float pD[4][16];

  const int bid = blockIdx.x;
  const int b = bid / nqt;
  const int n0 = (bid % nqt) * 16;
  const int tid = threadIdx.x;
  const int wv_ = tid >> 6;
  const int lane = tid & 63;
  const int g = lane >> 4;
  const int qi = lane & 15;

  const int ntile = Np >> 5;
  const unsigned short* qb_ = qtb + (long)b * Np * 8;
  const unsigned short* kb_ = ktb + (long)b * Np * 8;
  const unsigned short* vb_ = vp + (long)b * ntile * CB * 512 + lane * 8;

  bf16x8 qf;
#pragma unroll
  for (int i = 0; i < 8; ++i) qf[i] = 0;
  if (g == 0) qf = *(const bf16x8*)(qb_ + (long)(n0 + qi) * 8);

  f32x4 acc[CB];
#pragma unroll
  for (int cb = 0; cb < CB; ++cb) {
    f32x4 z = {0.f, 0.f, 0.f, 0.f};
    acc[cb] = z;
  }
  float den = 0.f;
  const f32x4 z4 = {0.f, 0.f, 0.f, 0.f};

  for (int t = wv_; t < ntile; t += 4) {
    const int mb = t * 32;
    bf16x8 kf0, kf1;
#pragma unroll
    for (int i = 0; i < 8; ++i) { kf0[i] = 0; kf1[i] = 0; }
    if (g == 0) {
      kf0 = *(const bf16x8*)(kb_ + (long)(mb + qi) * 8);
      kf1 = *(const bf16x8*)(kb_ + (long)(mb + 16 + qi) * 8);
    }
    const f32x4 e0 =
        __builtin_amdgcn_mfma_f32_16x16x32_bf16(kf0, qf, z4, 0, 0, 0);
    const f32x4 e1 =
        __builtin_amdgcn_mfma_f32_16x16x32_bf16(kf1, qf, z4, 0, 0, 0);

    bf16x8 pb;
#pragma unroll
    for (int r = 0; r < 4; ++r) {
      const int ma = mb + 4 * g + r;
      const int mc = ma + 16;
      const float p0 = (ma < N) ? __expf(e0[r]) : 0.f;
      const float p1 = (mc < N) ? __expf(e1[r]) : 0.f;
      den += p0 + p1;
      pb[r] = f2bf(p0);
      pb[4 + r] = f2bf(p1);
    }
    const unsigned short* vt_ = vb_ + (long)t * CB * 512;
#pragma unroll
    for (int cb = 0; cb < CB; ++cb) {
      const bf16x8 va = *(const bf16x8*)(vt_ + cb * 512);
      acc[cb] =
          __builtin_amdgcn_mfma_f32_16x16x32_bf16(va, pb, acc[cb], 0, 0, 0);
    }
  }

  den += __shfl_xor(den, 16, 64);
  den += __shfl_xor(den, 32, 64);

#pragma unroll
  for (int cb = 0; cb < CB; ++cb)
#pragma unroll
    for (int r = 0; r < 4; ++r)
      pO[wv_][cb * 256 + (4 * g + r) * 16 + qi] = acc[cb][r];
  if (g == 0) pD[wv_][qi] = den;
  __syncthreads();

  const float gma = gamma_p[0];
#pragma unroll
  for (int cb = 0; cb < CB; ++cb) {
    const int cell = cb * 256 + tid;
    const int c = cb * 16 + (tid >> 4);
    const int q = tid & 15;
    const int n = n0 + q;
    if (c < C && n < N) {
      const float s = pO[0][cell] + pO[1][cell] + pO[2][cell] + pO[3][cell];
      const float Dn = pD[0][q] + pD[1][q] + pD[2][q] + pD[3][q];
      const long o = ((long)b * C + c) * N + n;
      out[o] = fmaf(gma, s / Dn, x[o]);
    }
  }
}

// ---------------- q/k/v projections (attn3 small path) ----------------
template <int Cp>
__global__ __launch_bounds__(256) void k_qkv3(
    const float* __restrict__ x, const float* __restrict__ wq,
    const float* __restrict__ bq, const float* __restrict__ wk,
    const float* __restrict__ bk, const float* __restrict__ wv,
    const float* __restrict__ bv, float* __restrict__ qt,
    float* __restrict__ kt, float* __restrict__ vt, int Bn, int C, int D,
    int N, int Np) {
  constexpr int KP = 8;
  const int S = Np * (2 * KP + Cp);
  const int total = Bn * S;
  for (int idx = blockIdx.x * blockDim.x + threadIdx.x; idx < total;
       idx += gridDim.x * blockDim.x) {
    const int b = idx / S;
    const int rr = idx % S;
    const float* xb = x + (long)b * C * N;
    const float* w = nullptr;
    const float* bp = nullptr;
    float* dst;
    int n, co, lim;
    if (rr < Np * KP) {
      n = rr / KP; co = rr % KP; lim = D;
      w = wq + co * C; bp = bq;
      dst = qt + ((long)b * Np + n) * KP + co;
    } else if (rr < 2 * Np * KP) {
      const int t = rr - Np * KP;
      n = t / KP; co = t % KP; lim = D;
      w = wk + co * C; bp = bk;
      dst = kt + ((long)b * Np + n) * KP + co;
    } else {
      const int t = rr - 2 * Np * KP;
      n = t / Cp; co = t % Cp; lim = C;
      w = wv + co * C; bp = bv;
      dst = vt + ((long)b * Np + n) * Cp + co;
    }
    if (co < lim && n < N) {
      float a = bp[co];
      for (int ci = 0; ci < C; ++ci) a = fmaf(w[ci], xb[(long)ci * N + n], a);
      *dst = a;
    } else {
      *dst = 0.f;
    }
  }
}

// ---------------- flash attention partials (attn3 small path) ---------------
template <int C, int Chp>
__global__ __launch_bounds__(128) void k_attn7(
    const float* __restrict__ qt, const float* __restrict__ kt,
    const float* __restrict__ vt, float* __restrict__ num,
    float* __restrict__ den, int N, int nbr, int S, int msz, int Np, int Nr) {
  constexpr int KP = 8;
  constexpr int Cp = 2 * Chp;
  constexpr int NV = Chp / 4;
  int bid = blockIdx.x;
  const int s = bid % S; bid /= S;
  const int rb = bid % nbr;
  const int b = bid / nbr;
  const int brow = rb * 32;
  const int tid = threadIdx.x;
  const int lane = tid & 63;
  const int cg = tid >> 6;
  const int g = lane >> 4;
  const int r = lane & 15;

  const float* qb = qt + (long)b * Np * KP;
  const float* kb = kt + (long)b * Np * KP;
  const float* vb = vt + (long)b * Np * Cp;

  float4 q0[2];
  float2 q1[2];
#pragma unroll
  for (int k = 0; k < 2; ++k) {
    const int n = brow + r + 16 * k;
    q0[k] = *(const float4*)(qb + (long)n * KP);
    q1[k] = *(const float2*)(qb + (long)n * KP + 4);
  }

  float acc[2][Chp];
#pragma unroll
  for (int k = 0; k < 2; ++k)
#pragma unroll
    for (int c = 0; c < Chp; ++c) acc[k][c] = 0.f;
  float sm[2] = {0.f, 0.f};

  const int mstart = s * msz;
  const int mlimit = min(mstart + msz, N);
  for (int m0 = mstart; m0 < mlimit; m0 += 4) {
    const int m = m0 + g;
    const float4 ka = *(const float4*)(kb + (long)m * KP);
    const float2 kc = *(const float2*)(kb + (long)m * KP + 4);
    float4 vv[NV];
    const float4* vpp = (const float4*)(vb + (long)m * Cp + cg * Chp);
#pragma unroll
    for (int j = 0; j < NV; ++j) vv[j] = vpp[j];
#pragma unroll
    for (int k = 0; k < 2; ++k) {
      float e = q0[k].x * ka.x;
      e = fmaf(q0[k].y, ka.y, e);
      e = fmaf(q0[k].z, ka.z, e);
      e = fmaf(q0[k].w, ka.w, e);
      e = fmaf(q1[k].x, kc.x, e);
      e = fmaf(q1[k].y, kc.y, e);
      const float p = __expf(e);
      sm[k] += p;
#pragma unroll
      for (int j = 0; j < NV; ++j) {
        acc[k][4 * j + 0] = fmaf(p, vv[j].x, acc[k][4 * j + 0]);
        acc[k][4 * j + 1] = fmaf(p, vv[j].y, acc[k][4 * j + 1]);
        acc[k][4 * j + 2] = fmaf(p, vv[j].z, acc[k][4 * j + 2]);
        acc[k][4 * j + 3] = fmaf(p, vv[j].w, acc[k][4 * j + 3]);
      }
    }
  }

#pragma unroll
  for (int k = 0; k < 2; ++k) {
    sm[k] += __shfl_xor(sm[k], 16, 64);
    sm[k] += __shfl_xor(sm[k], 32, 64);
#pragma unroll
    for (int c = 0; c < Chp; ++c) {
      acc[k][c] += __shfl_xor(acc[k][c], 16, 64);
      acc[k][c] += __shfl_xor(acc[k][c], 32, 64);
    }
  }

  if (g == 0) {
    float* np_ = num + ((long)(s * 8 + b) * Cp + cg * Chp) * Nr;
    float* dp_ = den + (long)(s * 8 + b) * Nr;
#pragma unroll
    for (int k = 0; k < 2; ++k) {
      const int n = brow + r + 16 * k;
      if (n < N) {
#pragma unroll
        for (int c = 0; c < Chp; ++c) np_[(long)c * Nr + n] = acc[k][c];
        if (cg == 0) dp_[n] = sm[k];
      }
    }
  }
}

// ---------------- attention merge (attn3 small path) ----------------
__global__ __launch_bounds__(256) void k_attnmerge(
    const float* __restrict__ x, const float* __restrict__ num,
    const float* __restrict__ den, const float* __restrict__ gamma_p,
    float* __restrict__ out, int C, int Cp, int N, int Nr, int S) {
  const float g = gamma_p[0];
  const int total = 8 * C * N;
  for (int idx = blockIdx.x * blockDim.x + threadIdx.x; idx < total;
       idx += gridDim.x * blockDim.x) {
    const int n = idx % N;
    const int t = idx / N;
    const int c = t % C;
    const int b = t / C;
    float a = 0.f, d = 0.f;
    for (int s = 0; s < S; ++s) {
      a += num[((long)(s * 8 + b) * Cp + c) * Nr + n];
      d += den[(long)(s * 8 + b) * Nr + n];
    }
    out[((long)b * C + c) * N + n] =
        fmaf(g, a / d, x[((long)b * C + c) * N + n]);
  }
}

// ---------------- batchnorm stats: mean + rsqrt(var+eps) per channel --------
__global__ __launch_bounds__(256) void k_bnstats(const float* __restrict__ x,
                                                 float* __restrict__ stats,
                                                 int Bn, int C, int HW,
                                                 float eps) {
  int c = blockIdx.x;
  int tid = threadIdx.x;
  int cnt = Bn * HW;
  float s = 0.f, s2 = 0.f;
  for (int i = tid; i < cnt; i += blockDim.x) {
    int b = i / HW, r = i % HW;
    float v = x[((long)b * C + c) * HW + r];
    s += v;
    s2 += v * v;
  }
#pragma unroll
  for (int off = 32; off > 0; off >>= 1) {
    s += __shfl_down(s, off);
    s2 += __shfl_down(s2, off);
  }
  __shared__ float as_[4], as2_[4];
  int wid = tid >> 6;
  if ((tid & 63) == 0) { as_[wid] = s; as2_[wid] = s2; }
  __syncthreads();
  if (tid == 0) {
    float S = 0.f, S2 = 0.f;
#pragma unroll
    for (int ww = 0; ww < 4; ++ww) { S += as_[ww]; S2 += as2_[ww]; }
    float mean = S / (float)cnt;
    float var = S2 / (float)cnt - mean * mean;
    stats[c] = mean;
    stats[C + c] = rsqrtf(var + eps);
  }
}

// ---------------- BN apply + selu (+pool) ----------------
template <bool POOL>
__global__ __launch_bounds__(256) void k_bn_selu(
    const float* __restrict__ x, const float* __restrict__ stats,
    const float* __restrict__ g, const float* __restrict__ beta,
    float* __restrict__ out, int Bn, int C, int IH, int IW) {
  int OH = POOL ? (IH >> 1) : IH;
  int OW = POOL ? (IW >> 1) : IW;
  int total = Bn * C * OH * OW;
  for (int idx = blockIdx.x * blockDim.x + threadIdx.x; idx < total;
       idx += gridDim.x * blockDim.x) {
    int px = idx % OW;
    int t = idx / OW;
    int py = t % OH;
    t /= OH;
    int c = t % C;
    int b = t / C;
    float mean = stats[c], istd = stats[C + c];
    float gg = g[c], bb = beta[c];
    const float* ip = x + ((long)b * C + c) * IH * IW;
    float r;
    if (POOL) {
      int iy = py * 2, ix = px * 2;
      float v00 = selu_f((ip[iy * IW + ix] - mean) * istd * gg + bb);
      float v01 = selu_f((ip[iy * IW + ix + 1] - mean) * istd * gg + bb);
      float v10 = selu_f((ip[(iy + 1) * IW + ix] - mean) * istd * gg + bb);
      float v11 = selu_f((ip[(iy + 1) * IW + ix + 1] - mean) * istd * gg + bb);
      r = 0.25f * (v00 + v01 + v10 + v11);
    } else {
      r = selu_f((ip[py * IW + px] - mean) * istd * gg + bb);
    }
    out[((b * C + c) * OH + py) * OW + px] = r;
  }
}

static inline int gs(int total) { return (total + 255) / 256; }
static inline int cdiv(int a, int b) { return (a + b - 1) / b; }

extern "C" void kernel_launch(void* const* d_in, const int* in_sizes, int n_in,
                              void* d_out, int out_size, void* d_ws,
                              size_t ws_size, hipStream_t stream) {
  const float* x      = (const float*)d_in[0];
  const float* enc_w1 = (const float*)d_in[1];
  const float* enc_b1 = (const float*)d_in[2];
  const float* enc_w2 = (const float*)d_in[3];
  const float* enc_b2 = (const float*)d_in[4];
  const float* a1_wq  = (const float*)d_in[5];
  const float* a1_bq  = (const float*)d_in[6];
  const float* a1_wk  = (const float*)d_in[7];
  const float* a1_bk  = (const float*)d_in[8];
  const float* a1_wv  = (const float*)d_in[9];
  const float* a1_bv  = (const float*)d_in[10];
  const float* a1_g   = (const float*)d_in[11];
  const float* c1_w   = (const float*)d_in[12];
  const float* c1_b   = (const float*)d_in[13];
  const float* a2_wq  = (const float*)d_in[14];
  const float* a2_bq  = (const float*)d_in[15];
  const float* a2_wk  = (const float*)d_in[16];
  const float* a2_bk  = (const float*)d_in[17];
  const float* a2_wv  = (const float*)d_in[18];
  const float* a2_bv  = (const float*)d_in[19];
  const float* a2_g   = (const float*)d_in[20];
  const float* c2_w   = (const float*)d_in[21];
  const float* c2_b   = (const float*)d_in[22];
  const float* c3_w   = (const float*)d_in[23];
  const float* c3_g   = (const float*)d_in[24];
  const float* c3_be  = (const float*)d_in[25];
  const float* c4_w   = (const float*)d_in[26];
  const float* c4_g   = (const float*)d_in[27];
  const float* c4_be  = (const float*)d_in[28];
  const float* a3_wq  = (const float*)d_in[29];
  const float* a3_bq  = (const float*)d_in[30];
  const float* a3_wk  = (const float*)d_in[31];
  const float* a3_bk  = (const float*)d_in[32];
  const float* a3_wv  = (const float*)d_in[33];
  const float* a3_bv  = (const float*)d_in[34];
  const float* a3_g   = (const float*)d_in[35];

  float* out = (float*)d_out;
  float* W = (float*)d_ws;

  // ---- workspace plan (float slots; peak 5,056,320 = 20.2 MB, proven) ----
  float* h    = W;                         // [0, 1,920,000)
  float* h1   = W + 1920000;               // [1,920,000, 5,056,320)
  float* h2   = W;                         // [0, 737,280)
  float* xenc = out + 5120;                // (8,40,48,48) direct

  // attn1: Np1=2304, CB=3
  unsigned short* qtb1 = (unsigned short*)(W + 737280);   // 147,456 bf16
  unsigned short* ktb1 = (unsigned short*)(W + 884736);   // 147,456 bf16
  unsigned short* vtb1 = (unsigned short*)(W + 1032192);  // 884,736 bf16
  float* at1 = W + 1474560;                // 737,280 -> ends 2,211,840
  float* c1o = W + 2211840;                // 846,400 -> ends 3,058,240

  // attn2: Np2=2144, CB=4
  unsigned short* qtb2 = (unsigned short*)(W + 3058240);  // 137,216 bf16
  unsigned short* ktb2 = (unsigned short*)(W + 3195456);  // 137,216 bf16
  unsigned short* vtb2 = (unsigned short*)(W + 3332672);  // 1,097,728 bf16
  float* at2 = W + 3881536;                // 846,400 -> ends 4,727,936

  float* c2o  = W;                         // 154,880
  float* c3o  = W + 200000;                // 96,000
  float* st3  = W + 300000;                // 60
  float* c3p  = W + 310000;                // 24,000
  float* c4o  = W + 340000;                // 5,120
  float* st4  = W + 350000;                // 20
  float* c4b  = W + 360000;                // 5,120
  float* q3   = W + 370000;                // 8,192
  float* k3   = W + 380000;                // 8,192
  float* v3   = W + 390000;                // 16,384
  float* num3 = W + 410000;                // 8,192
  float* den3 = W + 420000;                // 512

  const int NOSPLIT = 1 << 30;

  // 1. prep
  {
    int n = 8 * 3 * 200 * 200;
    k_prep<<<gs(n), 256, 0, stream>>>(x, h, n);
  }
  // 2. enc conv1 + selu + pool : (16,3,200,200)->(16,20,99,99), direct OCB=5
  {
    int nQ = 99 * 99;                      // pooled outputs per (b,ocg)
    int nQB = cdiv(nQ, 256);               // 39
    int blocks = 16 * (20 / 5) * nQB;      // 2496
    k_conv3x3d<true, true, true, 5><<<blocks, 256, 0, stream>>>(
        h, enc_w1, enc_b1, h1, nullptr, NOSPLIT, 16, 3, 20, 200, 200, nQB);
  }
  // 3. enc conv2 + selu + pool : (16,20,99,99)->(16,40,48,48), direct OCB=5
  {
    int nQ = 48 * 48;
    int nQB = cdiv(nQ, 256);               // 9
    int blocks = 16 * (40 / 5) * nQB;      // 1152
    k_conv3x3d<true, true, true, 5><<<blocks, 256, 0, stream>>>(
        h1, enc_w2, enc_b2, h2, xenc, 8, 16, 20, 40, 99, 99, nQB);
  }
  // 4. attn1 qkv : CB=3, Np=2304
  {
    int total = 8 * 2304 * (16 + 48);
    k_qkvA<3><<<gs(total), 256, 0, stream>>>(h2, a1_wq, a1_bq, a1_wk, a1_bk,
                                             a1_wv, a1_bv, qtb1, ktb1, vtb1,
                                             8, 40, 5, 2304, 2304);
  }
  // 5. attn1 (full MFMA, coalesced V) : C=40, CB=3, nqt=144
  {
    k_attnN<40, 3><<<8 * 144, 256, 0, stream>>>(h2, qtb1, ktb1, vtb1, a1_g,
                                                at1, 2304, 2304, 144);
  }
  // 6. c1 conv + selu : (8,40,48,48)->(8,50,46,46), LDS OCB=2
  {
    int tXY = cdiv(46, 32);  // 2
    int blocks = 8 * (50 / 2) * tXY * tXY;  // 800
    k_conv3x3o<false, true, true, 2><<<blocks, 256, 0, stream>>>(
        at1, c1_w, c1_b, c1o, nullptr, NOSPLIT, 8, 40, 50, 48, 48, tXY, tXY);
  }
  // 7. attn2 qkv : CB=4, Np=2144
  {
    int total = 8 * 2144 * (16 + 64);
    k_qkvA<4><<<gs(total), 256, 0, stream>>>(c1o, a2_wq, a2_bq, a2_wk, a2_bk,
                                             a2_wv, a2_bv, qtb2, ktb2, vtb2,
                                             8, 50, 6, 2116, 2144);
  }
  // 8. attn2 (full MFMA, coalesced V) : C=50, CB=4, nqt=133
  {
    k_attnN<50, 4><<<8 * 133, 256, 0, stream>>>(c1o, qtb2, ktb2, vtb2, a2_g,
                                                at2, 2116, 2144, 133);
  }
  // 9. c2 conv + selu + pool : (8,50,46,46)->(8,40,22,22), LDS OCB=2
  {
    int tXY = cdiv(22, 16);  // 2
    int blocks = 8 * (40 / 2) * tXY * tXY;  // 640
    k_conv3x3o<true, true, true, 2><<<blocks, 256, 0, stream>>>(
        at2, c2_w, c2_b, c2o, nullptr, NOSPLIT, 8, 50, 40, 46, 46, tXY, tXY);
  }
  // 10. c3 conv : (8,40,22,22)->(8,30,20,20), LDS OCB=2
  {
    int tXY = cdiv(20, 32);  // 1
    int blocks = 8 * (30 / 2) * tXY * tXY;  // 120
    k_conv3x3o<false, false, false, 2><<<blocks, 256, 0, stream>>>(
        c2o, c3_w, nullptr, c3o, nullptr, NOSPLIT, 8, 40, 30, 22, 22, tXY,
        tXY);
  }
  // 11-12. BN(c3) + selu + pool -> (8,30,10,10)
  k_bnstats<<<30, 256, 0, stream>>>(c3o, st3, 8, 30, 400, 1e-5f);
  {
    int total = 8 * 30 * 10 * 10;
    k_bn_selu<true><<<gs(total), 256, 0, stream>>>(c3o, st3, c3_g, c3_be, c3p,
                                                   8, 30, 20, 20);
  }
  // 13. c4 conv : (8,30,10,10)->(8,10,8,8), LDS OCB=2
  {
    int tXY = cdiv(8, 32);  // 1
    int blocks = 8 * (10 / 2) * tXY * tXY;  // 40
    k_conv3x3o<false, false, false, 2><<<blocks, 256, 0, stream>>>(
        c3p, c4_w, nullptr, c4o, nullptr, NOSPLIT, 8, 30, 10, 10, 10, tXY,
        tXY);
  }
  // 14-15. BN(c4) + selu
  k_bnstats<<<10, 256, 0, stream>>>(c4o, st4, 8, 10, 64, 1e-5f);
  {
    int total = 8 * 10 * 8 * 8;
    k_bn_selu<false><<<gs(total), 256, 0, stream>>>(c4o, st4, c4_g, c4_be, c4b,
                                                    8, 10, 8, 8);
  }
  // 16. attn3 qkv : Cp=16, Np=128
  {
    int total = 8 * 128 * (16 + 16);
    k_qkv3<16><<<gs(total), 256, 0, stream>>>(c4b, a3_wq, a3_bq, a3_wk, a3_bk,
                                              a3_wv, a3_bv, q3, k3, v3, 8, 10,
                                              1, 64, 128);
  }
  // 17. attn3 partials + merge -> out[0..5120)
  {
    int nbr = 2, S = 1, msz = 64;
    k_attn7<10, 8><<<8 * nbr * S, 128, 0, stream>>>(q3, k3, v3, num3, den3, 64,
                                                    nbr, S, msz, 128, 64);
    k_attnmerge<<<gs(8 * 10 * 64), 256, 0, stream>>>(c4b, num3, den3, a3_g,
                                                     out, 10, 16, 64, 64, S);
  }
}

// Round 14
// 315.894 us; speedup vs baseline: 3.0700x; 1.2357x over previous
//
#include <hip/hip_runtime.h>
#include <math.h>

// ClassificationBackbone: conv/attn pipeline.
// R14: ALL convs now use the direct (no-LDS, no-barrier) kernel k_conv3x3d —
// thread = 2x2 conv quad x OCB ocs, 8 float2 patch loads/ci (L1-shared,
// 50% overlap between neighbors), weights via wave-uniform s_load.
// MFMA attention with pre-permuted V (R12) unchanged.

#define DEVINL __device__ __forceinline__

using bf16x8 = __attribute__((ext_vector_type(8))) short;  // 8 bf16 (4 VGPRs)
using f32x4 = __attribute__((ext_vector_type(4))) float;   // 4 fp32

DEVINL float selu_f(float x) {
  const float scale = 1.0507009873554805f;
  const float alpha = 1.6732632423543772f;
  return scale * (x > 0.f ? x : alpha * (__expf(x) - 1.f));
}

DEVINL short f2bf(float f) {  // RNE fp32 -> bf16
  unsigned int u = __float_as_uint(f);
  u = (u + 0x7FFFu + ((u >> 16) & 1u)) >> 16;
  return (short)u;
}

// ---------------- prep: h = concat([x^0.25/255^0.25, x], batch) -------------
__global__ __launch_bounds__(256) void k_prep(const float* __restrict__ x,
                                              float* __restrict__ h, int n) {
  const float invScale = 0.250244727f;  // 255^-0.25
  for (int i = blockIdx.x * blockDim.x + threadIdx.x; i < n;
       i += gridDim.x * blockDim.x) {
    float v = x[i];
    h[i] = sqrtf(sqrtf(v)) * invScale;
    h[n + i] = v;
  }
}

// ---------- direct conv3x3 (no LDS): 2x2 quad x OCB ocs per thread ----------
// blockIdx = (b, ocg, quad-tile); 256 quads per block, consecutive in (qy,qx)
// row-major -> coalesced loads/stores. Weights wave-uniform -> s_load.
// POOL: quad -> 1 pooled output/oc. NOPOOL: 4 outputs/oc (CH,CW even).
// Patch loads always in-bounds (2*qmax+3 <= IW-1 for all shapes used);
// all float2 addresses 8B-aligned (even strides/bases).
template <bool POOL, bool DO_SELU, bool DO_BIAS, int OCB>
__global__ __launch_bounds__(256) void k_conv3x3d(
    const float* __restrict__ in, const float* __restrict__ w,
    const float* __restrict__ bias, float* __restrict__ outA,
    float* __restrict__ outB, int splitB, int Bn, int Cin, int Cout, int IH,
    int IW, int nQB) {
  const int CH = IH - 2, CW = IW - 2;
  const int OH = POOL ? (CH >> 1) : CH;
  const int OW = POOL ? (CW >> 1) : CW;
  const int QY = POOL ? OH : (CH >> 1);
  const int QX = POOL ? OW : (CW >> 1);
  const int nQ = QY * QX;
  const int nOcg = Cout / OCB;

  int bid = blockIdx.x;
  const int qblk = bid % nQB; bid /= nQB;
  const int ocg = bid % nOcg;
  const int b = bid / nOcg;
  const int oc0 = ocg * OCB;

  const int q = qblk * 256 + threadIdx.x;
  if (q >= nQ) return;
  const int qx = q % QX;
  const int qy = q / QX;
  const int iy = 2 * qy, ix = 2 * qx;

  const float* ib = in + ((long)b * Cin * IH + iy) * IW + ix;

  float acc[OCB][2][2];
#pragma unroll
  for (int o = 0; o < OCB; ++o)
#pragma unroll
    for (int r = 0; r < 2; ++r)
#pragma unroll
      for (int c = 0; c < 2; ++c) acc[o][r][c] = 0.f;

  for (int ci = 0; ci < Cin; ++ci) {
    float pr[4][4];
    const float* p = ib + (long)ci * IH * IW;
#pragma unroll
    for (int r = 0; r < 4; ++r) {
      const float2 u0 = *(const float2*)(p + (long)r * IW);
      const float2 u1 = *(const float2*)(p + (long)r * IW + 2);
      pr[r][0] = u0.x; pr[r][1] = u0.y; pr[r][2] = u1.x; pr[r][3] = u1.y;
    }
    const float* wc = w + ((long)oc0 * Cin + ci) * 9;  // wave-uniform
#pragma unroll
    for (int o = 0; o < OCB; ++o) {
      const float* wp = wc + (long)o * Cin * 9;
#pragma unroll
      for (int ky = 0; ky < 3; ++ky)
#pragma unroll
        for (int kx = 0; kx < 3; ++kx) {
          const float ww = wp[ky * 3 + kx];
#pragma unroll
          for (int r = 0; r < 2; ++r)
#pragma unroll
            for (int c = 0; c < 2; ++c)
              acc[o][r][c] = fmaf(ww, pr[r + ky][c + kx], acc[o][r][c]);
        }
    }
  }

  if (POOL) {
#pragma unroll
    for (int o = 0; o < OCB; ++o) {
      const float bb = DO_BIAS ? bias[oc0 + o] : 0.f;
      float s = 0.f;
#pragma unroll
      for (int r = 0; r < 2; ++r)
#pragma unroll
        for (int c = 0; c < 2; ++c) {
          float v = acc[o][r][c] + bb;
          if (DO_SELU) v = selu_f(v);
          s += v;
        }
      const float rv = 0.25f * s;
      const int oc = oc0 + o;
      if (outB != nullptr && b >= splitB)
        outB[(((long)(b - splitB) * Cout + oc) * OH + qy) * OW + qx] = rv;
      else
        outA[(((long)b * Cout + oc) * OH + qy) * OW + qx] = rv;
    }
  } else {
#pragma unroll
    for (int o = 0; o < OCB; ++o) {
      const float bb = DO_BIAS ? bias[oc0 + o] : 0.f;
      const int oc = oc0 + o;
#pragma unroll
      for (int r = 0; r < 2; ++r)
#pragma unroll
        for (int c = 0; c < 2; ++c) {
          const int oy = iy + r, ox = ix + c;
          float v = acc[o][r][c] + bb;
          if (DO_SELU) v = selu_f(v);
          float* dst =
              (outB != nullptr && b >= splitB)
                  ? &outB[(((long)(b - splitB) * Cout + oc) * OH + oy) * OW + ox]
                  : &outA[(((long)b * Cout + oc) * OH + oy) * OW + ox];
          *dst = v;
        }
    }
  }
}

// -------- qkv for MFMA attention -------------------------------------------
// qtb,ktb bf16 [Np][8]. V written PRE-PERMUTED into PV-fragment order:
// vp[((b*ntile + t)*CB + cb)*512 + lane*8 + i], lane = g*16 + (c&15),
// t = n>>5, mo = n&31, g = (mo&15)>>2, i = ((mo>>4)<<2) | (mo&3), cb = c>>4.
template <int CB>
__global__ __launch_bounds__(256) void k_qkvA(
    const float* __restrict__ x, const float* __restrict__ wq,
    const float* __restrict__ bq, const float* __restrict__ wk,
    const float* __restrict__ bk, const float* __restrict__ wv,
    const float* __restrict__ bv, unsigned short* __restrict__ qtb,
    unsigned short* __restrict__ ktb, unsigned short* __restrict__ vp,
    int Bn, int C, int D, int N, int Np) {
  constexpr int Cpad = CB * 16;
  const int ntile = Np >> 5;
  const int seg1 = Np * 8;
  const int S = 2 * seg1 + Cpad * Np;
  const int total = Bn * S;
  for (int idx = blockIdx.x * blockDim.x + threadIdx.x; idx < total;
       idx += gridDim.x * blockDim.x) {
    const int b = idx / S;
    const int rr = idx % S;
    const float* xb = x + (long)b * C * N;
    if (rr < 2 * seg1) {
      const bool isq = rr < seg1;
      const int t = isq ? rr : rr - seg1;
      const int n = t >> 3, co = t & 7;
      unsigned short val = 0;
      if (co < D && n < N) {
        const float* w = (isq ? wq : wk) + co * C;
        float a = (isq ? bq : bk)[co];
        for (int ci = 0; ci < C; ++ci) a = fmaf(w[ci], xb[(long)ci * N + n], a);
        val = (unsigned short)f2bf(a);
      }
      (isq ? qtb : ktb)[((long)b * Np + n) * 8 + co] = val;
    } else {
      const int t2 = rr - 2 * seg1;
      const int c = t2 / Np, n = t2 % Np;
      unsigned short v = 0;
      if (c < C && n < N) {
        const float* w = wv + c * C;
        float a = bv[c];
        for (int ci = 0; ci < C; ++ci) a = fmaf(w[ci], xb[(long)ci * N + n], a);
        v = (unsigned short)f2bf(a);
      }
      const int tt = n >> 5, mo = n & 31;
      const int g = (mo & 15) >> 2;
      const int i = ((mo >> 4) << 2) | (mo & 3);
      const int lane = g * 16 + (c & 15);
      const int cb = c >> 4;
      vp[(((long)b * ntile + tt) * CB + cb) * 512 + lane * 8 + i] = v;
    }
  }
}

// ---------------- full-MFMA flash attention + residual ----------------
template <int C, int CB>
__global__ __launch_bounds__(256) void k_attnN(
    const float* __restrict__ x, const unsigned short* __restrict__ qtb,
    const unsigned short* __restrict__ ktb,
    const unsigned short* __restrict__ vp,
    const float* __restrict__ gamma_p, float* __restrict__ out, int N, int Np,
    int nqt) {
  __shared__ float pO[4][CB * 256];
  __shared__ float pD[4][16];

  const int bid = blockIdx.x;
  const int b = bid / nqt;
  const int n0 = (bid % nqt) * 16;
  const int tid = threadIdx.x;
  const int wv_ = tid >> 6;
  const int lane = tid & 63;
  const int g = lane >> 4;
  const int qi = lane & 15;

  const int ntile = Np >> 5;
  const unsigned short* qb_ = qtb + (long)b * Np * 8;
  const unsigned short* kb_ = ktb + (long)b * Np * 8;
  const unsigned short* vb_ = vp + (long)b * ntile * CB * 512 + lane * 8;

  bf16x8 qf;
#pragma unroll
  for (int i = 0; i < 8; ++i) qf[i] = 0;
  if (g == 0) qf = *(const bf16x8*)(qb_ + (long)(n0 + qi) * 8);

  f32x4 acc[CB];
#pragma unroll
  for (int cb = 0; cb < CB; ++cb) {
    f32x4 z = {0.f, 0.f, 0.f, 0.f};
    acc[cb] = z;
  }
  float den = 0.f;
  const f32x4 z4 = {0.f, 0.f, 0.f, 0.f};

  for (int t = wv_; t < ntile; t += 4) {
    const int mb = t * 32;
    bf16x8 kf0, kf1;
#pragma unroll
    for (int i = 0; i < 8; ++i) { kf0[i] = 0; kf1[i] = 0; }
    if (g == 0) {
      kf0 = *(const bf16x8*)(kb_ + (long)(mb + qi) * 8);
      kf1 = *(const bf16x8*)(kb_ + (long)(mb + 16 + qi) * 8);
    }
    const f32x4 e0 =
        __builtin_amdgcn_mfma_f32_16x16x32_bf16(kf0, qf, z4, 0, 0, 0);
    const f32x4 e1 =
        __builtin_amdgcn_mfma_f32_16x16x32_bf16(kf1, qf, z4, 0, 0, 0);

    bf16x8 pb;
#pragma unroll
    for (int r = 0; r < 4; ++r) {
      const int ma = mb + 4 * g + r;
      const int mc = ma + 16;
      const float p0 = (ma < N) ? __expf(e0[r]) : 0.f;
      const float p1 = (mc < N) ? __expf(e1[r]) : 0.f;
      den += p0 + p1;
      pb[r] = f2bf(p0);
      pb[4 + r] = f2bf(p1);
    }
    const unsigned short* vt_ = vb_ + (long)t * CB * 512;
#pragma unroll
    for (int cb = 0; cb < CB; ++cb) {
      const bf16x8 va = *(const bf16x8*)(vt_ + cb * 512);
      acc[cb] =
          __builtin_amdgcn_mfma_f32_16x16x32_bf16(va, pb, acc[cb], 0, 0, 0);
    }
  }

  den += __shfl_xor(den, 16, 64);
  den += __shfl_xor(den, 32, 64);

#pragma unroll
  for (int cb = 0; cb < CB; ++cb)
#pragma unroll
    for (int r = 0; r < 4; ++r)
      pO[wv_][cb * 256 + (4 * g + r) * 16 + qi] = acc[cb][r];
  if (g == 0) pD[wv_][qi] = den;
  __syncthreads();

  const float gma = gamma_p[0];
#pragma unroll
  for (int cb = 0; cb < CB; ++cb) {
    const int cell = cb * 256 + tid;
    const int c = cb * 16 + (tid >> 4);
    const int q = tid & 15;
    const int n = n0 + q;
    if (c < C && n < N) {
      const float s = pO[0][cell] + pO[1][cell] + pO[2][cell] + pO[3][cell];
      const float Dn = pD[0][q] + pD[1][q] + pD[2][q] + pD[3][q];
      const long o = ((long)b * C + c) * N + n;
      out[o] = fmaf(gma, s / Dn, x[o]);
    }
  }
}

// ---------------- q/k/v projections (attn3 small path) ----------------
template <int Cp>
__global__ __launch_bounds__(256) void k_qkv3(
    const float* __restrict__ x, const float* __restrict__ wq,
    const float* __restrict__ bq, const float* __restrict__ wk,
    const float* __restrict__ bk, const float* __restrict__ wv,
    const float* __restrict__ bv, float* __restrict__ qt,
    float* __restrict__ kt, float* __restrict__ vt, int Bn, int C, int D,
    int N, int Np) {
  constexpr int KP = 8;
  const int S = Np * (2 * KP + Cp);
  const int total = Bn * S;
  for (int idx = blockIdx.x * blockDim.x + threadIdx.x; idx < total;
       idx += gridDim.x * blockDim.x) {
    const int b = idx / S;
    const int rr = idx % S;
    const float* xb = x + (long)b * C * N;
    const float* w = nullptr;
    const float* bp = nullptr;
    float* dst;
    int n, co, lim;
    if (rr < Np * KP) {
      n = rr / KP; co = rr % KP; lim = D;
      w = wq + co * C; bp = bq;
      dst = qt + ((long)b * Np + n) * KP + co;
    } else if (rr < 2 * Np * KP) {
      const int t = rr - Np * KP;
      n = t / KP; co = t % KP; lim = D;
      w = wk + co * C; bp = bk;
      dst = kt + ((long)b * Np + n) * KP + co;
    } else {
      const int t = rr - 2 * Np * KP;
      n = t / Cp; co = t % Cp; lim = C;
      w = wv + co * C; bp = bv;
      dst = vt + ((long)b * Np + n) * Cp + co;
    }
    if (co < lim && n < N) {
      float a = bp[co];
      for (int ci = 0; ci < C; ++ci) a = fmaf(w[ci], xb[(long)ci * N + n], a);
      *dst = a;
    } else {
      *dst = 0.f;
    }
  }
}

// ---------------- flash attention partials (attn3 small path) ---------------
template <int C, int Chp>
__global__ __launch_bounds__(128) void k_attn7(
    const float* __restrict__ qt, const float* __restrict__ kt,
    const float* __restrict__ vt, float* __restrict__ num,
    float* __restrict__ den, int N, int nbr, int S, int msz, int Np, int Nr) {
  constexpr int KP = 8;
  constexpr int Cp = 2 * Chp;
  constexpr int NV = Chp / 4;
  int bid = blockIdx.x;
  const int s = bid % S; bid /= S;
  const int rb = bid % nbr;
  const int b = bid / nbr;
  const int brow = rb * 32;
  const int tid = threadIdx.x;
  const int lane = tid & 63;
  const int cg = tid >> 6;
  const int g = lane >> 4;
  const int r = lane & 15;

  const float* qb = qt + (long)b * Np * KP;
  const float* kb = kt + (long)b * Np * KP;
  const float* vb = vt + (long)b * Np * Cp;

  float4 q0[2];
  float2 q1[2];
#pragma unroll
  for (int k = 0; k < 2; ++k) {
    const int n = brow + r + 16 * k;
    q0[k] = *(const float4*)(qb + (long)n * KP);
    q1[k] = *(const float2*)(qb + (long)n * KP + 4);
  }

  float acc[2][Chp];
#pragma unroll
  for (int k = 0; k < 2; ++k)
#pragma unroll
    for (int c = 0; c < Chp; ++c) acc[k][c] = 0.f;
  float sm[2] = {0.f, 0.f};

  const int mstart = s * msz;
  const int mlimit = min(mstart + msz, N);
  for (int m0 = mstart; m0 < mlimit; m0 += 4) {
    const int m = m0 + g;
    const float4 ka = *(const float4*)(kb + (long)m * KP);
    const float2 kc = *(const float2*)(kb + (long)m * KP + 4);
    float4 vv[NV];
    const float4* vpp = (const float4*)(vb + (long)m * Cp + cg * Chp);
#pragma unroll
    for (int j = 0; j < NV; ++j) vv[j] = vpp[j];
#pragma unroll
    for (int k = 0; k < 2; ++k) {
      float e = q0[k].x * ka.x;
      e = fmaf(q0[k].y, ka.y, e);
      e = fmaf(q0[k].z, ka.z, e);
      e = fmaf(q0[k].w, ka.w, e);
      e = fmaf(q1[k].x, kc.x, e);
      e = fmaf(q1[k].y, kc.y, e);
      const float p = __expf(e);
      sm[k] += p;
#pragma unroll
      for (int j = 0; j < NV; ++j) {
        acc[k][4 * j + 0] = fmaf(p, vv[j].x, acc[k][4 * j + 0]);
        acc[k][4 * j + 1] = fmaf(p, vv[j].y, acc[k][4 * j + 1]);
        acc[k][4 * j + 2] = fmaf(p, vv[j].z, acc[k][4 * j + 2]);
        acc[k][4 * j + 3] = fmaf(p, vv[j].w, acc[k][4 * j + 3]);
      }
    }
  }

#pragma unroll
  for (int k = 0; k < 2; ++k) {
    sm[k] += __shfl_xor(sm[k], 16, 64);
    sm[k] += __shfl_xor(sm[k], 32, 64);
#pragma unroll
    for (int c = 0; c < Chp; ++c) {
      acc[k][c] += __shfl_xor(acc[k][c], 16, 64);
      acc[k][c] += __shfl_xor(acc[k][c], 32, 64);
    }
  }

  if (g == 0) {
    float* np_ = num + ((long)(s * 8 + b) * Cp + cg * Chp) * Nr;
    float* dp_ = den + (long)(s * 8 + b) * Nr;
#pragma unroll
    for (int k = 0; k < 2; ++k) {
      const int n = brow + r + 16 * k;
      if (n < N) {
#pragma unroll
        for (int c = 0; c < Chp; ++c) np_[(long)c * Nr + n] = acc[k][c];
        if (cg == 0) dp_[n] = sm[k];
      }
    }
  }
}

// ---------------- attention merge (attn3 small path) ----------------
__global__ __launch_bounds__(256) void k_attnmerge(
    const float* __restrict__ x, const float* __restrict__ num,
    const float* __restrict__ den, const float* __restrict__ gamma_p,
    float* __restrict__ out, int C, int Cp, int N, int Nr, int S) {
  const float g = gamma_p[0];
  const int total = 8 * C * N;
  for (int idx = blockIdx.x * blockDim.x + threadIdx.x; idx < total;
       idx += gridDim.x * blockDim.x) {
    const int n = idx % N;
    const int t = idx / N;
    const int c = t % C;
    const int b = t / C;
    float a = 0.f, d = 0.f;
    for (int s = 0; s < S; ++s) {
      a += num[((long)(s * 8 + b) * Cp + c) * Nr + n];
      d += den[(long)(s * 8 + b) * Nr + n];
    }
    out[((long)b * C + c) * N + n] =
        fmaf(g, a / d, x[((long)b * C + c) * N + n]);
  }
}

// ---------------- batchnorm stats: mean + rsqrt(var+eps) per channel --------
__global__ __launch_bounds__(256) void k_bnstats(const float* __restrict__ x,
                                                 float* __restrict__ stats,
                                                 int Bn, int C, int HW,
                                                 float eps) {
  int c = blockIdx.x;
  int tid = threadIdx.x;
  int cnt = Bn * HW;
  float s = 0.f, s2 = 0.f;
  for (int i = tid; i < cnt; i += blockDim.x) {
    int b = i / HW, r = i % HW;
    float v = x[((long)b * C + c) * HW + r];
    s += v;
    s2 += v * v;
  }
#pragma unroll
  for (int off = 32; off > 0; off >>= 1) {
    s += __shfl_down(s, off);
    s2 += __shfl_down(s2, off);
  }
  __shared__ float as_[4], as2_[4];
  int wid = tid >> 6;
  if ((tid & 63) == 0) { as_[wid] = s; as2_[wid] = s2; }
  __syncthreads();
  if (tid == 0) {
    float S = 0.f, S2 = 0.f;
#pragma unroll
    for (int ww = 0; ww < 4; ++ww) { S += as_[ww]; S2 += as2_[ww]; }
    float mean = S / (float)cnt;
    float var = S2 / (float)cnt - mean * mean;
    stats[c] = mean;
    stats[C + c] = rsqrtf(var + eps);
  }
}

// ---------------- BN apply + selu (+pool) ----------------
template <bool POOL>
__global__ __launch_bounds__(256) void k_bn_selu(
    const float* __restrict__ x, const float* __restrict__ stats,
    const float* __restrict__ g, const float* __restrict__ beta,
    float* __restrict__ out, int Bn, int C, int IH, int IW) {
  int OH = POOL ? (IH >> 1) : IH;
  int OW = POOL ? (IW >> 1) : IW;
  int total = Bn * C * OH * OW;
  for (int idx = blockIdx.x * blockDim.x + threadIdx.x; idx < total;
       idx += gridDim.x * blockDim.x) {
    int px = idx % OW;
    int t = idx / OW;
    int py = t % OH;
    t /= OH;
    int c = t % C;
    int b = t / C;
    float mean = stats[c], istd = stats[C + c];
    float gg = g[c], bb = beta[c];
    const float* ip = x + ((long)b * C + c) * IH * IW;
    float r;
    if (POOL) {
      int iy = py * 2, ix = px * 2;
      float v00 = selu_f((ip[iy * IW + ix] - mean) * istd * gg + bb);
      float v01 = selu_f((ip[iy * IW + ix + 1] - mean) * istd * gg + bb);
      float v10 = selu_f((ip[(iy + 1) * IW + ix] - mean) * istd * gg + bb);
      float v11 = selu_f((ip[(iy + 1) * IW + ix + 1] - mean) * istd * gg + bb);
      r = 0.25f * (v00 + v01 + v10 + v11);
    } else {
      r = selu_f((ip[py * IW + px] - mean) * istd * gg + bb);
    }
    out[((b * C + c) * OH + py) * OW + px] = r;
  }
}

static inline int gs(int total) { return (total + 255) / 256; }
static inline int cdiv(int a, int b) { return (a + b - 1) / b; }

extern "C" void kernel_launch(void* const* d_in, const int* in_sizes, int n_in,
                              void* d_out, int out_size, void* d_ws,
                              size_t ws_size, hipStream_t stream) {
  const float* x      = (const float*)d_in[0];
  const float* enc_w1 = (const float*)d_in[1];
  const float* enc_b1 = (const float*)d_in[2];
  const float* enc_w2 = (const float*)d_in[3];
  const float* enc_b2 = (const float*)d_in[4];
  const float* a1_wq  = (const float*)d_in[5];
  const float* a1_bq  = (const float*)d_in[6];
  const float* a1_wk  = (const float*)d_in[7];
  const float* a1_bk  = (const float*)d_in[8];
  const float* a1_wv  = (const float*)d_in[9];
  const float* a1_bv  = (const float*)d_in[10];
  const float* a1_g   = (const float*)d_in[11];
  const float* c1_w   = (const float*)d_in[12];
  const float* c1_b   = (const float*)d_in[13];
  const float* a2_wq  = (const float*)d_in[14];
  const float* a2_bq  = (const float*)d_in[15];
  const float* a2_wk  = (const float*)d_in[16];
  const float* a2_bk  = (const float*)d_in[17];
  const float* a2_wv  = (const float*)d_in[18];
  const float* a2_bv  = (const float*)d_in[19];
  const float* a2_g   = (const float*)d_in[20];
  const float* c2_w   = (const float*)d_in[21];
  const float* c2_b   = (const float*)d_in[22];
  const float* c3_w   = (const float*)d_in[23];
  const float* c3_g   = (const float*)d_in[24];
  const float* c3_be  = (const float*)d_in[25];
  const float* c4_w   = (const float*)d_in[26];
  const float* c4_g   = (const float*)d_in[27];
  const float* c4_be  = (const float*)d_in[28];
  const float* a3_wq  = (const float*)d_in[29];
  const float* a3_bq  = (const float*)d_in[30];
  const float* a3_wk  = (const float*)d_in[31];
  const float* a3_bk  = (const float*)d_in[32];
  const float* a3_wv  = (const float*)d_in[33];
  const float* a3_bv  = (const float*)d_in[34];
  const float* a3_g   = (const float*)d_in[35];

  float* out = (float*)d_out;
  float* W = (float*)d_ws;

  // ---- workspace plan (float slots; peak 5,056,320 = 20.2 MB, proven) ----
  float* h    = W;                         // [0, 1,920,000)
  float* h1   = W + 1920000;               // [1,920,000, 5,056,320)
  float* h2   = W;                         // [0, 737,280)
  float* xenc = out + 5120;                // (8,40,48,48) direct

  // attn1: Np1=2304, CB=3
  unsigned short* qtb1 = (unsigned short*)(W + 737280);   // 147,456 bf16
  unsigned short* ktb1 = (unsigned short*)(W + 884736);   // 147,456 bf16
  unsigned short* vtb1 = (unsigned short*)(W + 1032192);  // 884,736 bf16
  float* at1 = W + 1474560;                // 737,280 -> ends 2,211,840
  float* c1o = W + 2211840;                // 846,400 -> ends 3,058,240

  // attn2: Np2=2144, CB=4
  unsigned short* qtb2 = (unsigned short*)(W + 3058240);  // 137,216 bf16
  unsigned short* ktb2 = (unsigned short*)(W + 3195456);  // 137,216 bf16
  unsigned short* vtb2 = (unsigned short*)(W + 3332672);  // 1,097,728 bf16
  float* at2 = W + 3881536;                // 846,400 -> ends 4,727,936

  float* c2o  = W;                         // 154,880
  float* c3o  = W + 200000;                // 96,000
  float* st3  = W + 300000;                // 60
  float* c3p  = W + 310000;                // 24,000
  float* c4o  = W + 340000;                // 5,120
  float* st4  = W + 350000;                // 20
  float* c4b  = W + 360000;                // 5,120
  float* q3   = W + 370000;                // 8,192
  float* k3   = W + 380000;                // 8,192
  float* v3   = W + 390000;                // 16,384
  float* num3 = W + 410000;                // 8,192
  float* den3 = W + 420000;                // 512

  const int NOSPLIT = 1 << 30;

  // 1. prep
  {
    int n = 8 * 3 * 200 * 200;
    k_prep<<<gs(n), 256, 0, stream>>>(x, h, n);
  }
  // 2. enc conv1 + selu + pool : (16,3,200,200)->(16,20,99,99), direct OCB=5
  {
    int nQ = 99 * 99;
    int nQB = cdiv(nQ, 256);               // 39
    int blocks = 16 * (20 / 5) * nQB;      // 2496
    k_conv3x3d<true, true, true, 5><<<blocks, 256, 0, stream>>>(
        h, enc_w1, enc_b1, h1, nullptr, NOSPLIT, 16, 3, 20, 200, 200, nQB);
  }
  // 3. enc conv2 + selu + pool : (16,20,99,99)->(16,40,48,48), direct OCB=5
  {
    int nQ = 48 * 48;
    int nQB = cdiv(nQ, 256);               // 9
    int blocks = 16 * (40 / 5) * nQB;      // 1152
    k_conv3x3d<true, true, true, 5><<<blocks, 256, 0, stream>>>(
        h1, enc_w2, enc_b2, h2, xenc, 8, 16, 20, 40, 99, 99, nQB);
  }
  // 4. attn1 qkv : CB=3, Np=2304
  {
    int total = 8 * 2304 * (16 + 48);
    k_qkvA<3><<<gs(total), 256, 0, stream>>>(h2, a1_wq, a1_bq, a1_wk, a1_bk,
                                             a1_wv, a1_bv, qtb1, ktb1, vtb1,
                                             8, 40, 5, 2304, 2304);
  }
  // 5. attn1 (full MFMA, coalesced V) : C=40, CB=3, nqt=144
  {
    k_attnN<40, 3><<<8 * 144, 256, 0, stream>>>(h2, qtb1, ktb1, vtb1, a1_g,
                                                at1, 2304, 2304, 144);
  }
  // 6. c1 conv + selu : (8,40,48,48)->(8,50,46,46), direct OCB=2
  {
    int nQ = 23 * 23;                      // quads over 46x46
    int nQB = cdiv(nQ, 256);               // 3
    int blocks = 8 * (50 / 2) * nQB;       // 600
    k_conv3x3d<false, true, true, 2><<<blocks, 256, 0, stream>>>(
        at1, c1_w, c1_b, c1o, nullptr, NOSPLIT, 8, 40, 50, 48, 48, nQB);
  }
  // 7. attn2 qkv : CB=4, Np=2144
  {
    int total = 8 * 2144 * (16 + 64);
    k_qkvA<4><<<gs(total), 256, 0, stream>>>(c1o, a2_wq, a2_bq, a2_wk, a2_bk,
                                             a2_wv, a2_bv, qtb2, ktb2, vtb2,
                                             8, 50, 6, 2116, 2144);
  }
  // 8. attn2 (full MFMA, coalesced V) : C=50, CB=4, nqt=133
  {
    k_attnN<50, 4><<<8 * 133, 256, 0, stream>>>(c1o, qtb2, ktb2, vtb2, a2_g,
                                                at2, 2116, 2144, 133);
  }
  // 9. c2 conv + selu + pool : (8,50,46,46)->(8,40,22,22), direct OCB=2
  {
    int nQ = 22 * 22;                      // pooled outputs
    int nQB = cdiv(nQ, 256);               // 2
    int blocks = 8 * (40 / 2) * nQB;       // 320
    k_conv3x3d<true, true, true, 2><<<blocks, 256, 0, stream>>>(
        at2, c2_w, c2_b, c2o, nullptr, NOSPLIT, 8, 50, 40, 46, 46, nQB);
  }
  // 10. c3 conv : (8,40,22,22)->(8,30,20,20), direct OCB=2
  {
    int nQ = 10 * 10;
    int nQB = cdiv(nQ, 256);               // 1
    int blocks = 8 * (30 / 2) * nQB;       // 120
    k_conv3x3d<false, false, false, 2><<<blocks, 256, 0, stream>>>(
        c2o, c3_w, nullptr, c3o, nullptr, NOSPLIT, 8, 40, 30, 22, 22, nQB);
  }
  // 11-12. BN(c3) + selu + pool -> (8,30,10,10)
  k_bnstats<<<30, 256, 0, stream>>>(c3o, st3, 8, 30, 400, 1e-5f);
  {
    int total = 8 * 30 * 10 * 10;
    k_bn_selu<true><<<gs(total), 256, 0, stream>>>(c3o, st3, c3_g, c3_be, c3p,
                                                   8, 30, 20, 20);
  }
  // 13. c4 conv : (8,30,10,10)->(8,10,8,8), direct OCB=2
  {
    int nQ = 4 * 4;
    int nQB = cdiv(nQ, 256);               // 1
    int blocks = 8 * (10 / 2) * nQB;       // 40
    k_conv3x3d<false, false, false, 2><<<blocks, 256, 0, stream>>>(
        c3p, c4_w, nullptr, c4o, nullptr, NOSPLIT, 8, 30, 10, 10, 10, nQB);
  }
  // 14-15. BN(c4) + selu
  k_bnstats<<<10, 256, 0, stream>>>(c4o, st4, 8, 10, 64, 1e-5f);
  {
    int total = 8 * 10 * 8 * 8;
    k_bn_selu<false><<<gs(total), 256, 0, stream>>>(c4o, st4, c4_g, c4_be, c4b,
                                                    8, 10, 8, 8);
  }
  // 16. attn3 qkv : Cp=16, Np=128
  {
    int total = 8 * 128 * (16 + 16);
    k_qkv3<16><<<gs(total), 256, 0, stream>>>(c4b, a3_wq, a3_bq, a3_wk, a3_bk,
                                              a3_wv, a3_bv, q3, k3, v3, 8, 10,
                                              1, 64, 128);
  }
  // 17. attn3 partials + merge -> out[0..5120)
  {
    int nbr = 2, S = 1, msz = 64;
    k_attn7<10, 8><<<8 * nbr * S, 128, 0, stream>>>(q3, k3, v3, num3, den3, 64,
                                                    nbr, S, msz, 128, 64);
    k_attnmerge<<<gs(8 * 10 * 64), 256, 0, stream>>>(c4b, num3, den3, a3_g,
                                                     out, 10, 16, 64, 64, S);
  }
}